// Round 3
// baseline (14725.410 us; speedup 1.0000x reference)
//
#include <hip/hip_runtime.h>
#include <cstdint>
#include <cstddef>

// ---------------- model constants ----------------
#define BSZ   64
#define L_IN  168      // input / predict length
#define S1    222      // encoder sequence after pyramid (168+42+10+2)
#define SKV   390      // decoder kv length (222+168)
#define DM    512
#define HD    768      // 6 heads * 128
#define NHD   6
#define DK    128

typedef unsigned short u16;

// ---------------- bf16 helpers ----------------
__device__ inline float b2f(u16 u){
  union { unsigned int i; float f; } v; v.i = ((unsigned int)u) << 16; return v.f;
}
__device__ inline u16 f2b(float f){
  union { float f; unsigned int i; } v; v.f = f;
  unsigned int x = v.i;
  return (u16)((x + 0x7fffu + ((x >> 16) & 1u)) >> 16);
}
// dual-dtype input loads: f32flag chooses float32 vs bf16 interpretation of d_in
__device__ inline float ldv(const void* p, long long i, bool f32){
  return f32 ? ((const float*)p)[i] : b2f(((const u16*)p)[i]);
}
__device__ inline float4 ldv4(const void* p, long long i, bool f32){
  if (f32) return *(const float4*)((const float*)p + i);
  ushort4 w = *(const ushort4*)((const u16*)p + i);
  return make_float4(b2f(w.x), b2f(w.y), b2f(w.z), b2f(w.w));
}
__device__ inline bool is_f32(const u16* det){ return det[0] != 0x3F80; }

// ---------------- workspace layout (float-equivalent offsets) ----------------
constexpr size_t OFF_ENCX = 0;
constexpr size_t OFF_DECX = OFF_ENCX + (size_t)BSZ*S1*DM;
constexpr size_t OFF_QB   = OFF_DECX + (size_t)BSZ*L_IN*DM;
constexpr size_t OFF_KB   = OFF_QB   + (size_t)BSZ*S1*HD/2;
constexpr size_t OFF_VB   = OFF_KB   + (size_t)BSZ*SKV*HD/2;
constexpr size_t OFF_MASK = OFF_VB   + (size_t)BSZ*SKV*HD/2;   // ~149.6 MB total + mask

// ---------------- PAM mask build ----------------
__device__ inline int scale_of(int i, int& ii){
  if (i < 168){ ii = i;       return 0; }
  if (i < 210){ ii = i - 168; return 1; }
  if (i < 220){ ii = i - 210; return 2; }
  ii = i - 220; return 3;
}

__global__ void build_mask_kernel(unsigned char* __restrict__ m){
  int idx = blockIdx.x * 256 + threadIdx.x;
  if (idx >= S1*S1) return;
  int i = idx / S1, j = idx % S1;
  int ii, jj;
  int li = scale_of(i, ii);
  int lj = scale_of(j, jj);
  const int n[4] = {168, 42, 10, 2};
  bool ok = false;
  if (li == lj){
    int d = ii - jj; ok = (d <= 1 && d >= -1);
  } else if (li == lj + 1){
    int lo = ii*4, hi = (ii == n[li]-1) ? n[lj] : ii*4+4;
    ok = (jj >= lo && jj < hi);
  } else if (lj == li + 1){
    int lo = jj*4, hi = (jj == n[lj]-1) ? n[li] : jj*4+4;
    ok = (ii >= lo && ii < hi);
  }
  m[idx] = ok ? 1 : 0;
}

// ---------------- embedding: circular conv1d(k=3) + pos emb + time linear ----------------
__global__ void embed_kernel(const void* __restrict__ x,   // [B,168,7]
                             const void* __restrict__ t,   // [B,168,4]
                             const void* __restrict__ cw,  // [512,7,3]
                             const void* __restrict__ tw,  // [4,512]
                             const void* __restrict__ tb,  // [512]
                             const u16* __restrict__ det,
                             float* __restrict__ out)      // [B,168,512]
{
  bool f32 = is_f32(det);
  int idx = blockIdx.x * 256 + threadIdx.x;
  if (idx >= BSZ*L_IN*DM) return;
  int d = idx & (DM-1);
  int l = (idx >> 9) % L_IN;
  int b = idx / (DM*L_IN);
  float acc = 0.f;
  #pragma unroll
  for (int tt = 0; tt < 3; ++tt){
    int ls = l + tt - 1;
    ls = (ls < 0) ? ls + L_IN : (ls >= L_IN ? ls - L_IN : ls);
    long long xo = ((long long)(b*L_IN + ls))*7;
    #pragma unroll
    for (int c = 0; c < 7; ++c)
      acc += ldv(x, xo + c, f32) * ldv(cw, d*21 + c*3 + tt, f32);
  }
  int d2 = d & ~1;
  float dv  = expf(-(float)d2 * (9.210340371976184f/512.f)); // ln(10000)/512
  float ang = (float)l * dv;
  acc += (d & 1) ? cosf(ang) : sinf(ang);
  long long to = ((long long)(b*L_IN + l))*4;
  #pragma unroll
  for (int f = 0; f < 4; ++f) acc += ldv(t, to + f, f32) * ldv(tw, f*DM + d, f32);
  acc += ldv(tb, d, f32);
  out[idx] = acc;
}

// ---------------- tiled GEMM: C = A[M,K] @ W[K,N] (+bias, epi) ----------------
// ABF: A is bf16 ws buffer (else f32 ws buffer). CBF: C is bf16 (else f32).
// W/bias come from d_in: dual-dtype via det. Element offsets wOff/bOff.
// Row mapping: global row r -> b = r/La, l = r%La; C row = b*Lc + off + l.
// EPI: 0 = bias, 1 = bias+GELU(exact), 2 = bias+residual R (f32, C-indexed)
#define BM 64
#define BN 64
#define BK 16
template<int EPI, int ABF, int CBF>
__global__ __launch_bounds__(256)
void gemm_k(const void* __restrict__ Av, const void* __restrict__ W, long long wOff,
            const void* __restrict__ bias, long long bOff, const float* __restrict__ R,
            void* __restrict__ Cv, const u16* __restrict__ det,
            int K, int N, int La, int Lc, int off)
{
  __shared__ float As[BK][BM+4];
  __shared__ float Bs[BK][BN+4];
  bool f32 = is_f32(det);
  int tid = threadIdx.x;
  int row0 = blockIdx.y * BM, col0 = blockIdx.x * BN;
  int ty = tid >> 4, tx = tid & 15;
  int lr = tid >> 2, lc4 = (tid & 3) << 2;   // A tile load: row, 4-col group
  int wr = tid >> 4, wc4 = (tid & 15) << 2;  // W tile load: k-row, 4-col group
  float acc[4][4] = {};
  for (int k0 = 0; k0 < K; k0 += BK){
    if (ABF){
      const u16* A = (const u16*)Av;
      ushort4 av = *(const ushort4*)(A + (size_t)(row0 + lr)*K + k0 + lc4);
      As[lc4+0][lr] = b2f(av.x); As[lc4+1][lr] = b2f(av.y);
      As[lc4+2][lr] = b2f(av.z); As[lc4+3][lr] = b2f(av.w);
    } else {
      const float* A = (const float*)Av;
      float4 av = *(const float4*)(A + (size_t)(row0 + lr)*K + k0 + lc4);
      As[lc4+0][lr] = av.x; As[lc4+1][lr] = av.y;
      As[lc4+2][lr] = av.z; As[lc4+3][lr] = av.w;
    }
    float4 wv = ldv4(W, wOff + (long long)(k0 + wr)*N + col0 + wc4, f32);
    *(float4*)&Bs[wr][wc4] = wv;
    __syncthreads();
    #pragma unroll
    for (int kk = 0; kk < BK; ++kk){
      float4 a  = *(const float4*)&As[kk][ty << 2];
      float4 bb = *(const float4*)&Bs[kk][tx << 2];
      acc[0][0] += a.x*bb.x; acc[0][1] += a.x*bb.y; acc[0][2] += a.x*bb.z; acc[0][3] += a.x*bb.w;
      acc[1][0] += a.y*bb.x; acc[1][1] += a.y*bb.y; acc[1][2] += a.y*bb.z; acc[1][3] += a.y*bb.w;
      acc[2][0] += a.z*bb.x; acc[2][1] += a.z*bb.y; acc[2][2] += a.z*bb.z; acc[2][3] += a.z*bb.w;
      acc[3][0] += a.w*bb.x; acc[3][1] += a.w*bb.y; acc[3][2] += a.w*bb.z; acc[3][3] += a.w*bb.w;
    }
    __syncthreads();
  }
  #pragma unroll
  for (int i = 0; i < 4; ++i){
    int r = row0 + (ty << 2) + i;
    int bb = r / La, l = r - bb*La;
    size_t crow = ((size_t)bb*Lc + off + l)*(size_t)N;
    #pragma unroll
    for (int j = 0; j < 4; ++j){
      int c = col0 + (tx << 2) + j;
      float vv = acc[i][j] + ldv(bias, bOff + c, f32);
      if (EPI == 1) vv = 0.5f*vv*(1.f + erff(vv*0.70710678118654752f));
      if (EPI == 2) vv += R[crow + c];
      if (CBF) ((u16*)Cv)[crow + c] = f2b(vv);
      else     ((float*)Cv)[crow + c] = vv;
    }
  }
}

// ---------------- bottleneck strided conv (k=4, s=4) + BN(eval) + ELU ----------------
__global__ void conv_bn_elu_kernel(const float* __restrict__ in, int inStride, int inOff,
                                   float* __restrict__ out, int outStride, int outOff, int Lout,
                                   const void* __restrict__ w,   // [3,128,128,4]
                                   const void* __restrict__ cb,  // [3,128]
                                   const void* __restrict__ bg,
                                   const void* __restrict__ bb,
                                   const void* __restrict__ bm,
                                   const void* __restrict__ bv,
                                   const u16* __restrict__ det, int lay)
{
  bool f32 = is_f32(det);
  int idx = blockIdx.x * 256 + threadIdx.x;
  int total = BSZ * Lout * 128;
  if (idx >= total) return;
  int co = idx & 127;
  int j  = (idx >> 7) % Lout;
  int b  = idx / (128 * Lout);
  const float* ir = in + ((size_t)(b*inStride + inOff + j*4))*128;
  long long wo = (long long)lay*65536 + (long long)co*512;
  float acc = 0.f;
  for (int ci = 0; ci < 128; ++ci){
    #pragma unroll
    for (int tt = 0; tt < 4; ++tt)
      acc += ir[tt*128 + ci] * ldv(w, wo + ci*4 + tt, f32);
  }
  long long po = (long long)lay*128 + co;
  acc += ldv(cb, po, f32);
  acc = (acc - ldv(bm, po, f32)) * rsqrtf(ldv(bv, po, f32) + 1e-5f) * ldv(bg, po, f32) + ldv(bb, po, f32);
  acc = acc > 0.f ? acc : (__expf(acc) - 1.f);
  out[((size_t)(b*outStride + outOff + j))*128 + co] = acc;
}

// ---------------- LayerNorm (one wave per 512-row), f32 in -> f32 out ----------------
__global__ __launch_bounds__(64)
void ln_kernel(const float* __restrict__ X, const void* __restrict__ g, long long gOff,
               const void* __restrict__ bt, long long bOff, float eps,
               float* __restrict__ Out, const u16* __restrict__ det)
{
  bool f32 = is_f32(det);
  int row = blockIdx.x, lane = threadIdx.x;
  const float* xr = X + (size_t)row*DM;
  float v[8]; float s = 0.f;
  #pragma unroll
  for (int i = 0; i < 8; ++i){ v[i] = xr[lane + i*64]; s += v[i]; }
  #pragma unroll
  for (int o = 32; o > 0; o >>= 1) s += __shfl_xor(s, o);
  float mean = s * (1.f/512.f);
  float q = 0.f;
  #pragma unroll
  for (int i = 0; i < 8; ++i){ float d = v[i]-mean; q += d*d; }
  #pragma unroll
  for (int o = 32; o > 0; o >>= 1) q += __shfl_xor(q, o);
  float inv = rsqrtf(q*(1.f/512.f) + eps);
  float* orow = Out + (size_t)row*DM;
  #pragma unroll
  for (int i = 0; i < 8; ++i){
    int c = lane + i*64;
    orow[c] = (v[i]-mean)*inv*ldv(g, gOff + c, f32) + ldv(bt, bOff + c, f32);
  }
}

// ---------------- concat(embed[168], up[54]) + LayerNorm(1e-5) ----------------
__global__ __launch_bounds__(64)
void concat_ln_kernel(const float* __restrict__ emb, const float* __restrict__ up,
                      const void* __restrict__ g, const void* __restrict__ bt,
                      float* __restrict__ Out, const u16* __restrict__ det)
{
  bool f32 = is_f32(det);
  int row = blockIdx.x, lane = threadIdx.x;
  int b = row / S1, l = row - b*S1;
  const float* xr = (l < L_IN) ? emb + ((size_t)(b*L_IN + l))*DM
                               : up  + ((size_t)(b*54 + (l - L_IN)))*DM;
  float v[8]; float s = 0.f;
  #pragma unroll
  for (int i = 0; i < 8; ++i){ v[i] = xr[lane + i*64]; s += v[i]; }
  #pragma unroll
  for (int o = 32; o > 0; o >>= 1) s += __shfl_xor(s, o);
  float mean = s * (1.f/512.f);
  float q = 0.f;
  #pragma unroll
  for (int i = 0; i < 8; ++i){ float d = v[i]-mean; q += d*d; }
  #pragma unroll
  for (int o = 32; o > 0; o >>= 1) q += __shfl_xor(q, o);
  float inv = rsqrtf(q*(1.f/512.f) + 1e-5f);
  float* orow = Out + (size_t)row*DM;
  #pragma unroll
  for (int i = 0; i < 8; ++i){
    int c = lane + i*64;
    orow[c] = (v[i]-mean)*inv*ldv(g, c, f32) + ldv(bt, c, f32);
  }
}

// ---------------- attention: bf16 q/k/v (ws-internal), two-pass softmax ----------------
#define QT 16
#define KTL 32
#define SW 416
__global__ __launch_bounds__(256)
void attn_kernel(u16* __restrict__ q, const u16* __restrict__ k,
                 const u16* __restrict__ v, const unsigned char* __restrict__ mask,
                 int Lq, int Lk, int decmode)
{
  __shared__ float Qs[QT][132];
  __shared__ float KVs[KTL][132];
  __shared__ float Ss[QT][SW];
  __shared__ float red[QT][17];
  int b = blockIdx.z, h = blockIdx.y;
  int qt0 = blockIdx.x * QT;
  int tid = threadIdx.x;
  for (int i = tid; i < QT*128; i += 256){
    int qi = i >> 7, d = i & 127;
    int qg = qt0 + qi;
    Qs[qi][d] = (qg < Lq) ? b2f(q[((size_t)b*Lq + qg)*HD + h*DK + d]) : 0.f;
  }
  __syncthreads();
  const float scale = 0.088388347648318447f;  // 1/sqrt(128)
  int kj = tid & 31, qw = tid >> 5;
  for (int kt0 = 0; kt0 < Lk; kt0 += KTL){
    for (int i = tid; i < KTL*128; i += 256){
      int kk = i >> 7, d = i & 127;
      int kg = kt0 + kk;
      KVs[kk][d] = (kg < Lk) ? b2f(k[((size_t)b*Lk + kg)*HD + h*DK + d]) : 0.f;
    }
    __syncthreads();
    int kg = kt0 + kj;
    #pragma unroll
    for (int qq = 0; qq < 2; ++qq){
      int qi = qw + qq*8;
      const float4* qr = (const float4*)&Qs[qi][0];
      const float4* kr = (const float4*)&KVs[kj][0];
      float acc = 0.f;
      #pragma unroll 8
      for (int d4 = 0; d4 < 32; ++d4){
        float4 a = qr[d4], c = kr[d4];
        acc += a.x*c.x + a.y*c.y + a.z*c.z + a.w*c.w;
      }
      int qg2 = qt0 + qi;
      float s = acc * scale;
      bool ok = (qg2 < Lq) && (kg < Lk);
      if (ok) ok = decmode ? (kg <= S1 + qg2) : (mask[qg2*S1 + kg] != 0);
      Ss[qi][kt0 + kj] = ok ? s : -1e30f;
    }
    __syncthreads();
  }
  int g = tid >> 4, lg = tid & 15;
  float mx = -1e30f;
  for (int j = lg; j < Lk; j += 16) mx = fmaxf(mx, Ss[g][j]);
  red[g][lg] = mx;
  __syncthreads();
  if (lg == 0){
    float m2 = -1e30f;
    #pragma unroll
    for (int t2 = 0; t2 < 16; ++t2) m2 = fmaxf(m2, red[g][t2]);
    red[g][16] = m2;
  }
  __syncthreads();
  mx = red[g][16];
  float ps = 0.f;
  for (int j = lg; j < Lk; j += 16){
    float p = __expf(Ss[g][j] - mx);
    Ss[g][j] = p; ps += p;
  }
  __syncthreads();
  red[g][lg] = ps;
  __syncthreads();
  if (lg == 0){
    float s2 = 0.f;
    #pragma unroll
    for (int t2 = 0; t2 < 16; ++t2) s2 += red[g][t2];
    red[g][16] = s2;
  }
  __syncthreads();
  float inv = 1.f / red[g][16];
  for (int j = lg; j < Lk; j += 16) Ss[g][j] *= inv;
  float acc[8];
  #pragma unroll
  for (int i = 0; i < 8; ++i) acc[i] = 0.f;
  int d = tid & 127, qh = tid >> 7;
  for (int kt0 = 0; kt0 < Lk; kt0 += KTL){
    __syncthreads();
    for (int i = tid; i < KTL*128; i += 256){
      int kk = i >> 7, dd = i & 127;
      int kg = kt0 + kk;
      KVs[kk][dd] = (kg < Lk) ? b2f(v[((size_t)b*Lk + kg)*HD + h*DK + dd]) : 0.f;
    }
    __syncthreads();
    int kmax = min(KTL, Lk - kt0);
    for (int kk4 = 0; kk4 < kmax; kk4 += 4){
      float v0 = KVs[kk4+0][d], v1 = KVs[kk4+1][d];
      float v2 = KVs[kk4+2][d], v3 = KVs[kk4+3][d];
      #pragma unroll
      for (int qq = 0; qq < 8; ++qq){
        float4 p = *(const float4*)&Ss[qh + qq*2][kt0 + kk4];
        acc[qq] += p.x*v0 + p.y*v1 + p.z*v2 + p.w*v3;
      }
    }
  }
  #pragma unroll
  for (int qq = 0; qq < 8; ++qq){
    int qi = qh + qq*2, qg = qt0 + qi;
    if (qg < Lq) q[((size_t)b*Lq + qg)*HD + h*DK + d] = f2b(acc[qq]);
  }
}

// ---------------- prediction head: [*,512] @ [512,7] -> out (dtype per det) ----------------
__global__ void pred_kernel(const float* __restrict__ X, const void* __restrict__ w,
                            void* __restrict__ out, const u16* __restrict__ det)
{
  bool f32 = is_f32(det);
  int idx = blockIdx.x * 256 + threadIdx.x;
  if (idx >= BSZ*L_IN*7) return;
  int c  = idx % 7;
  int rl = idx / 7;
  const float* xr = X + (size_t)rl*DM;
  float acc = 0.f;
  for (int kk = 0; kk < DM; ++kk) acc += xr[kk] * ldv(w, kk*7 + c, f32);
  if (f32) ((float*)out)[idx] = acc;
  else     ((u16*)out)[idx] = f2b(acc);
}

// ---------------- launch ----------------
extern "C" void kernel_launch(void* const* d_in, const int* in_sizes, int n_in,
                              void* d_out, int out_size, void* d_ws, size_t ws_size,
                              hipStream_t stream)
{
  (void)in_sizes; (void)n_in; (void)out_size; (void)ws_size;
  #define IN(i) ((const void*)d_in[i])
  const u16* det = (const u16*)d_in[20];   // bc_ln_g = ones -> dtype detector
  float* ws   = (float*)d_ws;
  float* encx = ws + OFF_ENCX;
  float* decx = ws + OFF_DECX;
  u16*   qb   = (u16*)(ws + OFF_QB);
  u16*   kb   = (u16*)(ws + OFF_KB);
  u16*   vb   = (u16*)(ws + OFF_VB);
  unsigned char* maskp = (unsigned char*)(ws + OFF_MASK);
  // phase-disjoint aliases
  float* tmp1  = ws + OFF_KB;               // f32 [64,222,512] pre-LN sum (K dead)
  u16*   tmph  = (u16*)(ws + OFF_VB);       // bf16 [64,222,512] ffn hidden (V dead)
  float* embE  = ws + OFF_VB;               // f32 [64,168,512] enc embed (pre-encoder)
  float* bdown = ws + OFF_KB;               // f32 [64,168,128]
  float* bconv = bdown + (size_t)BSZ*L_IN*128;   // f32 [64,54,128]
  float* bup   = bconv + (size_t)BSZ*54*128;     // f32 [64,54,512]

  build_mask_kernel<<<(S1*S1 + 255)/256, 256, 0, stream>>>(maskp);

  embed_kernel<<<(BSZ*L_IN*DM)/256, 256, 0, stream>>>(IN(0), IN(1), IN(4), IN(5), IN(6), det, embE);
  embed_kernel<<<(BSZ*L_IN*DM)/256, 256, 0, stream>>>(IN(2), IN(3), IN(7), IN(8), IN(9), det, decx);

  // bottleneck
  gemm_k<0,0,0><<<dim3(128/BN, (BSZ*L_IN)/BM), 256, 0, stream>>>(
      embE, IN(10), 0, IN(11), 0, nullptr, bdown, det, 512, 128, L_IN, L_IN, 0);
  conv_bn_elu_kernel<<<(BSZ*42*128)/256, 256, 0, stream>>>(
      bdown, L_IN, 0, bconv, 54, 0, 42,
      IN(12), IN(13), IN(14), IN(15), IN(16), IN(17), det, 0);
  conv_bn_elu_kernel<<<(BSZ*10*128)/256, 256, 0, stream>>>(
      bconv, 54, 0, bconv, 54, 42, 10,
      IN(12), IN(13), IN(14), IN(15), IN(16), IN(17), det, 1);
  conv_bn_elu_kernel<<<(BSZ*2*128)/256, 256, 0, stream>>>(
      bconv, 54, 42, bconv, 54, 52, 2,
      IN(12), IN(13), IN(14), IN(15), IN(16), IN(17), det, 2);
  gemm_k<0,0,0><<<dim3(512/BN, (BSZ*54)/BM), 256, 0, stream>>>(
      bconv, IN(18), 0, IN(19), 0, nullptr, bup, det, 128, 512, 54, 54, 0);
  concat_ln_kernel<<<BSZ*S1, 64, 0, stream>>>(embE, bup, IN(20), IN(21), encx, det);

  // encoder layers
  for (int i = 0; i < 6; ++i){
    long long wO = (long long)i*512*768, oO = (long long)i*768*512;
    long long bO = (long long)i*768, dO = (long long)i*512;
    long long fO = (long long)i*512*512;
    gemm_k<0,0,1><<<dim3(768/BN, (BSZ*S1)/BM), 256, 0, stream>>>(
        encx, IN(22), wO, IN(23), bO, nullptr, qb, det, 512, 768, S1, S1, 0);
    gemm_k<0,0,1><<<dim3(768/BN, (BSZ*S1)/BM), 256, 0, stream>>>(
        encx, IN(24), wO, IN(25), bO, nullptr, kb, det, 512, 768, S1, S1, 0);
    gemm_k<0,0,1><<<dim3(768/BN, (BSZ*S1)/BM), 256, 0, stream>>>(
        encx, IN(26), wO, IN(27), bO, nullptr, vb, det, 512, 768, S1, S1, 0);
    attn_kernel<<<dim3((S1+QT-1)/QT, NHD, BSZ), 256, 0, stream>>>(
        qb, kb, vb, maskp, S1, S1, 0);
    gemm_k<2,1,0><<<dim3(512/BN, (BSZ*S1)/BM), 256, 0, stream>>>(
        qb, IN(28), oO, IN(29), dO, encx, tmp1, det, 768, 512, S1, S1, 0);
    ln_kernel<<<BSZ*S1, 64, 0, stream>>>(tmp1, IN(30), dO, IN(31), dO, 1e-6f, encx, det);
    gemm_k<1,0,1><<<dim3(512/BN, (BSZ*S1)/BM), 256, 0, stream>>>(
        encx, IN(32), fO, IN(33), dO, nullptr, tmph, det, 512, 512, S1, S1, 0);
    gemm_k<2,1,0><<<dim3(512/BN, (BSZ*S1)/BM), 256, 0, stream>>>(
        tmph, IN(34), fO, IN(35), dO, encx, tmp1, det, 512, 512, S1, S1, 0);
    ln_kernel<<<BSZ*S1, 64, 0, stream>>>(tmp1, IN(36), dO, IN(37), dO, 1e-6f, encx, det);
  }

  // decoder layers (kv = concat(encx, decx) via row-remapped K/V GEMMs)
  for (int i = 0; i < 2; ++i){
    long long wO = (long long)i*512*768, oO = (long long)i*768*512;
    long long bO = (long long)i*768, dO = (long long)i*512;
    long long fO = (long long)i*512*512;
    gemm_k<0,0,1><<<dim3(768/BN, (BSZ*L_IN)/BM), 256, 0, stream>>>(
        decx, IN(38), wO, IN(39), bO, nullptr, qb, det, 512, 768, L_IN, L_IN, 0);
    gemm_k<0,0,1><<<dim3(768/BN, (BSZ*S1)/BM), 256, 0, stream>>>(
        encx, IN(40), wO, IN(41), bO, nullptr, kb, det, 512, 768, S1, SKV, 0);
    gemm_k<0,0,1><<<dim3(768/BN, (BSZ*L_IN)/BM), 256, 0, stream>>>(
        decx, IN(40), wO, IN(41), bO, nullptr, kb, det, 512, 768, L_IN, SKV, S1);
    gemm_k<0,0,1><<<dim3(768/BN, (BSZ*S1)/BM), 256, 0, stream>>>(
        encx, IN(42), wO, IN(43), bO, nullptr, vb, det, 512, 768, S1, SKV, 0);
    gemm_k<0,0,1><<<dim3(768/BN, (BSZ*L_IN)/BM), 256, 0, stream>>>(
        decx, IN(42), wO, IN(43), bO, nullptr, vb, det, 512, 768, L_IN, SKV, S1);
    attn_kernel<<<dim3((L_IN+QT-1)/QT, NHD, BSZ), 256, 0, stream>>>(
        qb, kb, vb, nullptr, L_IN, SKV, 1);
    gemm_k<2,1,0><<<dim3(512/BN, (BSZ*L_IN)/BM), 256, 0, stream>>>(
        qb, IN(44), oO, IN(45), dO, decx, tmp1, det, 768, 512, L_IN, L_IN, 0);
    ln_kernel<<<BSZ*L_IN, 64, 0, stream>>>(tmp1, IN(46), dO, IN(47), dO, 1e-6f, decx, det);
    gemm_k<1,0,1><<<dim3(512/BN, (BSZ*L_IN)/BM), 256, 0, stream>>>(
        decx, IN(48), fO, IN(49), dO, nullptr, tmph, det, 512, 512, L_IN, L_IN, 0);
    gemm_k<2,1,0><<<dim3(512/BN, (BSZ*L_IN)/BM), 256, 0, stream>>>(
        tmph, IN(50), fO, IN(51), dO, decx, tmp1, det, 512, 512, L_IN, L_IN, 0);
    ln_kernel<<<BSZ*L_IN, 64, 0, stream>>>(tmp1, IN(52), dO, IN(53), dO, 1e-6f, decx, det);
  }

  pred_kernel<<<(BSZ*L_IN*7 + 255)/256, 256, 0, stream>>>(decx, IN(54), d_out, det);
  #undef IN
}

// Round 4
// 11014.613 us; speedup vs baseline: 1.3369x; 1.3369x over previous
//
#include <hip/hip_runtime.h>
#include <cstdint>
#include <cstddef>

// ---------------- model constants ----------------
#define BSZ   64
#define L_IN  168      // input / predict length
#define S1    222      // encoder sequence after pyramid (168+42+10+2)
#define SKV   390      // decoder kv length (222+168)
#define DM    512
#define HD    768      // 6 heads * 128
#define NHD   6
#define DK    128

typedef unsigned short u16;

// ---------------- bf16 helpers ----------------
__device__ inline float b2f(u16 u){
  union { unsigned int i; float f; } v; v.i = ((unsigned int)u) << 16; return v.f;
}
__device__ inline u16 f2b(float f){
  union { float f; unsigned int i; } v; v.f = f;
  unsigned int x = v.i;
  return (u16)((x + 0x7fffu + ((x >> 16) & 1u)) >> 16);
}
// dual-dtype input loads: f32 flag chooses float32 vs bf16 interpretation of d_in
__device__ inline float ldv(const void* p, long long i, bool f32){
  return f32 ? ((const float*)p)[i] : b2f(((const u16*)p)[i]);
}
__device__ inline float4 ldv4(const void* p, long long i, bool f32){
  if (f32) return *(const float4*)((const float*)p + i);
  ushort4 w = *(const ushort4*)((const u16*)p + i);
  return make_float4(b2f(w.x), b2f(w.y), b2f(w.z), b2f(w.w));
}
__device__ inline bool is_f32(const u16* det){ return det[0] != 0x3F80; }

// ---------------- workspace layout (float-equivalent offsets) ----------------
constexpr size_t OFF_ENCX = 0;
constexpr size_t OFF_DECX = OFF_ENCX + (size_t)BSZ*S1*DM;
constexpr size_t OFF_QB   = OFF_DECX + (size_t)BSZ*L_IN*DM;
constexpr size_t OFF_KB   = OFF_QB   + (size_t)BSZ*S1*HD/2;
constexpr size_t OFF_VB   = OFF_KB   + (size_t)BSZ*SKV*HD/2;
constexpr size_t OFF_NBR  = OFF_VB   + (size_t)BSZ*SKV*HD/2;   // int[222*12]

// ---------------- PAM sparsity: per-query neighbor list ----------------
__device__ inline int scale_of(int i, int& ii){
  if (i < 168){ ii = i;       return 0; }
  if (i < 210){ ii = i - 168; return 1; }
  if (i < 220){ ii = i - 210; return 2; }
  ii = i - 220; return 3;
}
__device__ inline bool pam_ok(int i, int j){
  int ii, jj;
  int li = scale_of(i, ii);
  int lj = scale_of(j, jj);
  const int n[4] = {168, 42, 10, 2};
  if (li == lj){ int d = ii - jj; return (d <= 1 && d >= -1); }
  if (li == lj + 1){ int lo = ii*4, hi = (ii == n[li]-1) ? n[lj] : ii*4+4; return (jj >= lo && jj < hi); }
  if (lj == li + 1){ int lo = jj*4, hi = (jj == n[lj]-1) ? n[li] : jj*4+4; return (ii >= lo && ii < hi); }
  return false;
}
// max neighbor count is 9 (scale2 last node: 2 intra + 6 children + 1 parent); pad to 12
__global__ void build_nbr_kernel(int* __restrict__ nbr){
  int q = blockIdx.x * 256 + threadIdx.x;
  if (q >= S1) return;
  int cnt = 0;
  int list[12];
  for (int j = 0; j < S1; ++j)
    if (pam_ok(q, j) && cnt < 12) list[cnt++] = j;
  #pragma unroll
  for (int t = 0; t < 12; ++t) nbr[q*12 + t] = (t < cnt) ? list[t] : -1;
}

// ---------------- embedding: circular conv1d(k=3) + pos emb + time linear ----------------
__global__ void embed_kernel(const void* __restrict__ x,   // [B,168,7]
                             const void* __restrict__ t,   // [B,168,4]
                             const void* __restrict__ cw,  // [512,7,3]
                             const void* __restrict__ tw,  // [4,512]
                             const void* __restrict__ tb,  // [512]
                             const u16* __restrict__ det,
                             float* __restrict__ out)      // [B,168,512]
{
  bool f32 = is_f32(det);
  int idx = blockIdx.x * 256 + threadIdx.x;
  if (idx >= BSZ*L_IN*DM) return;
  int d = idx & (DM-1);
  int l = (idx >> 9) % L_IN;
  int b = idx / (DM*L_IN);
  float acc = 0.f;
  #pragma unroll
  for (int tt = 0; tt < 3; ++tt){
    int ls = l + tt - 1;
    ls = (ls < 0) ? ls + L_IN : (ls >= L_IN ? ls - L_IN : ls);
    long long xo = ((long long)(b*L_IN + ls))*7;
    #pragma unroll
    for (int c = 0; c < 7; ++c)
      acc += ldv(x, xo + c, f32) * ldv(cw, d*21 + c*3 + tt, f32);
  }
  int d2 = d & ~1;
  float dv  = expf(-(float)d2 * (9.210340371976184f/512.f)); // ln(10000)/512
  float ang = (float)l * dv;
  acc += (d & 1) ? cosf(ang) : sinf(ang);
  long long to = ((long long)(b*L_IN + l))*4;
  #pragma unroll
  for (int f = 0; f < 4; ++f) acc += ldv(t, to + f, f32) * ldv(tw, f*DM + d, f32);
  acc += ldv(tb, d, f32);
  out[idx] = acc;
}

// ---------------- tiled GEMM: C = A[M,K] @ W[K,N] (+bias, epi) ----------------
#define BM 64
#define BN 64
#define BK 16
template<int EPI, int ABF, int CBF>
__global__ __launch_bounds__(256)
void gemm_k(const void* __restrict__ Av, const void* __restrict__ W, long long wOff,
            const void* __restrict__ bias, long long bOff, const float* __restrict__ R,
            void* __restrict__ Cv, const u16* __restrict__ det,
            int K, int N, int La, int Lc, int off)
{
  __shared__ float As[BK][BM+4];
  __shared__ float Bs[BK][BN+4];
  bool f32 = is_f32(det);
  int tid = threadIdx.x;
  int row0 = blockIdx.y * BM, col0 = blockIdx.x * BN;
  int ty = tid >> 4, tx = tid & 15;
  int lr = tid >> 2, lc4 = (tid & 3) << 2;
  int wr = tid >> 4, wc4 = (tid & 15) << 2;
  float acc[4][4] = {};
  for (int k0 = 0; k0 < K; k0 += BK){
    if (ABF){
      const u16* A = (const u16*)Av;
      ushort4 av = *(const ushort4*)(A + (size_t)(row0 + lr)*K + k0 + lc4);
      As[lc4+0][lr] = b2f(av.x); As[lc4+1][lr] = b2f(av.y);
      As[lc4+2][lr] = b2f(av.z); As[lc4+3][lr] = b2f(av.w);
    } else {
      const float* A = (const float*)Av;
      float4 av = *(const float4*)(A + (size_t)(row0 + lr)*K + k0 + lc4);
      As[lc4+0][lr] = av.x; As[lc4+1][lr] = av.y;
      As[lc4+2][lr] = av.z; As[lc4+3][lr] = av.w;
    }
    float4 wv = ldv4(W, wOff + (long long)(k0 + wr)*N + col0 + wc4, f32);
    *(float4*)&Bs[wr][wc4] = wv;
    __syncthreads();
    #pragma unroll
    for (int kk = 0; kk < BK; ++kk){
      float4 a  = *(const float4*)&As[kk][ty << 2];
      float4 bb = *(const float4*)&Bs[kk][tx << 2];
      acc[0][0] += a.x*bb.x; acc[0][1] += a.x*bb.y; acc[0][2] += a.x*bb.z; acc[0][3] += a.x*bb.w;
      acc[1][0] += a.y*bb.x; acc[1][1] += a.y*bb.y; acc[1][2] += a.y*bb.z; acc[1][3] += a.y*bb.w;
      acc[2][0] += a.z*bb.x; acc[2][1] += a.z*bb.y; acc[2][2] += a.z*bb.z; acc[2][3] += a.z*bb.w;
      acc[3][0] += a.w*bb.x; acc[3][1] += a.w*bb.y; acc[3][2] += a.w*bb.z; acc[3][3] += a.w*bb.w;
    }
    __syncthreads();
  }
  #pragma unroll
  for (int i = 0; i < 4; ++i){
    int r = row0 + (ty << 2) + i;
    int bb = r / La, l = r - bb*La;
    size_t crow = ((size_t)bb*Lc + off + l)*(size_t)N;
    #pragma unroll
    for (int j = 0; j < 4; ++j){
      int c = col0 + (tx << 2) + j;
      float vv = acc[i][j] + ldv(bias, bOff + c, f32);
      if (EPI == 1) vv = 0.5f*vv*(1.f + erff(vv*0.70710678118654752f));
      if (EPI == 2) vv += R[crow + c];
      if (CBF) ((u16*)Cv)[crow + c] = f2b(vv);
      else     ((float*)Cv)[crow + c] = vv;
    }
  }
}

// ---------------- bottleneck strided conv (k=4, s=4) + BN(eval) + ELU ----------------
__global__ void conv_bn_elu_kernel(const float* __restrict__ in, int inStride, int inOff,
                                   float* __restrict__ out, int outStride, int outOff, int Lout,
                                   const void* __restrict__ w,
                                   const void* __restrict__ cb,
                                   const void* __restrict__ bg,
                                   const void* __restrict__ bb,
                                   const void* __restrict__ bm,
                                   const void* __restrict__ bv,
                                   const u16* __restrict__ det, int lay)
{
  bool f32 = is_f32(det);
  int idx = blockIdx.x * 256 + threadIdx.x;
  int total = BSZ * Lout * 128;
  if (idx >= total) return;
  int co = idx & 127;
  int j  = (idx >> 7) % Lout;
  int b  = idx / (128 * Lout);
  const float* ir = in + ((size_t)(b*inStride + inOff + j*4))*128;
  long long wo = (long long)lay*65536 + (long long)co*512;
  float acc = 0.f;
  for (int ci = 0; ci < 128; ++ci){
    #pragma unroll
    for (int tt = 0; tt < 4; ++tt)
      acc += ir[tt*128 + ci] * ldv(w, wo + ci*4 + tt, f32);
  }
  long long po = (long long)lay*128 + co;
  acc += ldv(cb, po, f32);
  acc = (acc - ldv(bm, po, f32)) * rsqrtf(ldv(bv, po, f32) + 1e-5f) * ldv(bg, po, f32) + ldv(bb, po, f32);
  acc = acc > 0.f ? acc : (__expf(acc) - 1.f);
  out[((size_t)(b*outStride + outOff + j))*128 + co] = acc;
}

// ---------------- LayerNorm (one wave per 512-row) ----------------
__global__ __launch_bounds__(64)
void ln_kernel(const float* __restrict__ X, const void* __restrict__ g, long long gOff,
               const void* __restrict__ bt, long long bOff, float eps,
               float* __restrict__ Out, const u16* __restrict__ det)
{
  bool f32 = is_f32(det);
  int row = blockIdx.x, lane = threadIdx.x;
  const float* xr = X + (size_t)row*DM;
  float v[8]; float s = 0.f;
  #pragma unroll
  for (int i = 0; i < 8; ++i){ v[i] = xr[lane + i*64]; s += v[i]; }
  #pragma unroll
  for (int o = 32; o > 0; o >>= 1) s += __shfl_xor(s, o);
  float mean = s * (1.f/512.f);
  float q = 0.f;
  #pragma unroll
  for (int i = 0; i < 8; ++i){ float d = v[i]-mean; q += d*d; }
  #pragma unroll
  for (int o = 32; o > 0; o >>= 1) q += __shfl_xor(q, o);
  float inv = rsqrtf(q*(1.f/512.f) + eps);
  float* orow = Out + (size_t)row*DM;
  #pragma unroll
  for (int i = 0; i < 8; ++i){
    int c = lane + i*64;
    orow[c] = (v[i]-mean)*inv*ldv(g, gOff + c, f32) + ldv(bt, bOff + c, f32);
  }
}

// ---------------- concat(embed[168], up[54]) + LayerNorm(1e-5) ----------------
__global__ __launch_bounds__(64)
void concat_ln_kernel(const float* __restrict__ emb, const float* __restrict__ up,
                      const void* __restrict__ g, const void* __restrict__ bt,
                      float* __restrict__ Out, const u16* __restrict__ det)
{
  bool f32 = is_f32(det);
  int row = blockIdx.x, lane = threadIdx.x;
  int b = row / S1, l = row - b*S1;
  const float* xr = (l < L_IN) ? emb + ((size_t)(b*L_IN + l))*DM
                               : up  + ((size_t)(b*54 + (l - L_IN)))*DM;
  float v[8]; float s = 0.f;
  #pragma unroll
  for (int i = 0; i < 8; ++i){ v[i] = xr[lane + i*64]; s += v[i]; }
  #pragma unroll
  for (int o = 32; o > 0; o >>= 1) s += __shfl_xor(s, o);
  float mean = s * (1.f/512.f);
  float q = 0.f;
  #pragma unroll
  for (int i = 0; i < 8; ++i){ float d = v[i]-mean; q += d*d; }
  #pragma unroll
  for (int o = 32; o > 0; o >>= 1) q += __shfl_xor(q, o);
  float inv = rsqrtf(q*(1.f/512.f) + 1e-5f);
  float* orow = Out + (size_t)row*DM;
  #pragma unroll
  for (int i = 0; i < 8; ++i){
    int c = lane + i*64;
    orow[c] = (v[i]-mean)*inv*ldv(g, c, f32) + ldv(bt, c, f32);
  }
}

// ---------------- encoder attention: PAM-sparse, one wave per (b,q,h) ----------------
// softmax over <=12 neighbor keys is exactly the reference masked softmax
// (exp(-1e9 - m) underflows to 0). Output in-place into q.
__global__ __launch_bounds__(384)
void attn_enc_sparse(u16* __restrict__ q, const u16* __restrict__ k,
                     const u16* __restrict__ v, const int* __restrict__ nbr)
{
  __shared__ int nb[12];
  int blk = blockIdx.x;
  int b = blk / S1, qr = blk - b*S1;
  if (threadIdx.x < 12) nb[threadIdx.x] = nbr[qr*12 + threadIdx.x];
  __syncthreads();
  int h = threadIdx.x >> 6;      // 0..5 (one wave per head)
  int lane = threadIdx.x & 63;   // lane owns dims 2*lane, 2*lane+1
  const float scale = 0.088388347648318447f;  // 1/sqrt(128)
  size_t rowoff = ((size_t)b*S1 + qr)*HD + h*DK;
  unsigned int qw = ((const unsigned int*)(q + rowoff))[lane];
  float q0 = b2f((u16)(qw & 0xffff)), q1 = b2f((u16)(qw >> 16));
  float pj[12];
  #pragma unroll
  for (int j = 0; j < 12; ++j){
    int kg = nb[j];
    float p = 0.f;
    if (kg >= 0){  // wave-uniform branch
      unsigned int kw = ((const unsigned int*)(k + ((size_t)b*S1 + kg)*HD + h*DK))[lane];
      p = q0*b2f((u16)(kw & 0xffff)) + q1*b2f((u16)(kw >> 16));
    }
    #pragma unroll
    for (int o = 32; o > 0; o >>= 1) p += __shfl_xor(p, o);
    pj[j] = (kg >= 0) ? p*scale : -1e30f;
  }
  float m = -1e30f;
  #pragma unroll
  for (int j = 0; j < 12; ++j) m = fmaxf(m, pj[j]);
  float s = 0.f;
  #pragma unroll
  for (int j = 0; j < 12; ++j){
    pj[j] = (nb[j] >= 0) ? __expf(pj[j]-m) : 0.f;
    s += pj[j];
  }
  float inv = 1.f / s;
  float o0 = 0.f, o1 = 0.f;
  #pragma unroll
  for (int j = 0; j < 12; ++j){
    int kg = nb[j];
    if (kg >= 0){
      unsigned int vw = ((const unsigned int*)(v + ((size_t)b*S1 + kg)*HD + h*DK))[lane];
      o0 += pj[j]*b2f((u16)(vw & 0xffff));
      o1 += pj[j]*b2f((u16)(vw >> 16));
    }
  }
  unsigned int ow = ((unsigned int)f2b(o1*inv) << 16) | (unsigned int)f2b(o0*inv);
  ((unsigned int*)(q + rowoff))[lane] = ow;
}

// ---------------- decoder attention: dense causal, one block per (b,h) ----------------
// loops q-tiles internally so K/V stay L2-resident; causal k-range clamp
#define DQT 16
#define DKT 48
#define DSW 396
__global__ __launch_bounds__(256)
void attn_dec_kernel(u16* __restrict__ q, const u16* __restrict__ k,
                     const u16* __restrict__ v)
{
  __shared__ float Qs[DQT][132];
  __shared__ float KVs[DKT][132];
  __shared__ float Ss[DQT][DSW];
  __shared__ float red[DQT][17];
  int b = blockIdx.x, h = blockIdx.y;
  int tid = threadIdx.x;
  const float scale = 0.088388347648318447f;
  const size_t qb0 = (size_t)b*L_IN*HD + (size_t)h*DK;
  const size_t kb0 = (size_t)b*SKV*HD + (size_t)h*DK;
  for (int qt0 = 0; qt0 < L_IN; qt0 += DQT){
    __syncthreads();   // LDS reuse guard across q-tile iterations
    for (int i = tid*4; i < DQT*128; i += 1024){
      int qi = i >> 7, d = i & 127;
      int qg = qt0 + qi;
      if (qg < L_IN){
        ushort4 w = *(const ushort4*)(q + qb0 + (size_t)qg*HD + d);
        Qs[qi][d] = b2f(w.x); Qs[qi][d+1] = b2f(w.y); Qs[qi][d+2] = b2f(w.z); Qs[qi][d+3] = b2f(w.w);
      } else {
        Qs[qi][d] = 0.f; Qs[qi][d+1] = 0.f; Qs[qi][d+2] = 0.f; Qs[qi][d+3] = 0.f;
      }
    }
    int kEnd = S1 + qt0 + DQT; if (kEnd > SKV) kEnd = SKV;  // causal upper bound for this tile
    // ---- scores: micro-tile 1q x 3k ----
    int kx = tid & 15, qy = tid >> 4;
    for (int kt0 = 0; kt0 < kEnd; kt0 += DKT){
      for (int i = tid*4; i < DKT*128; i += 1024){
        int kk = i >> 7, d = i & 127;
        int kg = kt0 + kk;
        if (kg < SKV){
          ushort4 w = *(const ushort4*)(k + kb0 + (size_t)kg*HD + d);
          KVs[kk][d] = b2f(w.x); KVs[kk][d+1] = b2f(w.y); KVs[kk][d+2] = b2f(w.z); KVs[kk][d+3] = b2f(w.w);
        } else {
          KVs[kk][d] = 0.f; KVs[kk][d+1] = 0.f; KVs[kk][d+2] = 0.f; KVs[kk][d+3] = 0.f;
        }
      }
      __syncthreads();
      float s0 = 0.f, s1 = 0.f, s2 = 0.f;
      const float4* qr = (const float4*)&Qs[qy][0];
      const float4* k0 = (const float4*)&KVs[3*kx+0][0];
      const float4* k1 = (const float4*)&KVs[3*kx+1][0];
      const float4* k2 = (const float4*)&KVs[3*kx+2][0];
      #pragma unroll 8
      for (int d4 = 0; d4 < 32; ++d4){
        float4 a = qr[d4];
        float4 x0 = k0[d4], x1 = k1[d4], x2 = k2[d4];
        s0 += a.x*x0.x + a.y*x0.y + a.z*x0.z + a.w*x0.w;
        s1 += a.x*x1.x + a.y*x1.y + a.z*x1.z + a.w*x1.w;
        s2 += a.x*x2.x + a.y*x2.y + a.z*x2.z + a.w*x2.w;
      }
      int qg = qt0 + qy;
      float sv0 = s0, sv1 = s1, sv2 = s2;
      #pragma unroll
      for (int t = 0; t < 3; ++t){
        float sc = (t == 0) ? sv0 : (t == 1) ? sv1 : sv2;
        int col = kt0 + 3*kx + t;
        if (col < kEnd){
          bool ok = (qg < L_IN) && (col <= S1 + qg);
          Ss[qy][col] = ok ? sc*scale : -1e30f;
        } else if (col < DSW){
          Ss[qy][col] = 0.f;    // pad read by PV float4 tail -> contributes 0
        }
      }
      __syncthreads();
    }
    // ---- softmax: 16 lanes per query row ----
    int g = tid >> 4, lg = tid & 15;
    float mx = -1e30f;
    for (int j = lg; j < kEnd; j += 16) mx = fmaxf(mx, Ss[g][j]);
    red[g][lg] = mx;
    __syncthreads();
    if (lg == 0){
      float m2 = -1e30f;
      #pragma unroll
      for (int t2 = 0; t2 < 16; ++t2) m2 = fmaxf(m2, red[g][t2]);
      red[g][16] = m2;
    }
    __syncthreads();
    mx = red[g][16];
    float ps = 0.f;
    for (int j = lg; j < kEnd; j += 16){
      float p = __expf(Ss[g][j] - mx);
      Ss[g][j] = p; ps += p;
    }
    __syncthreads();
    red[g][lg] = ps;
    __syncthreads();
    if (lg == 0){
      float s2 = 0.f;
      #pragma unroll
      for (int t2 = 0; t2 < 16; ++t2) s2 += red[g][t2];
      red[g][16] = s2;
    }
    __syncthreads();
    float inv = 1.f / red[g][16];
    for (int j = lg; j < kEnd; j += 16) Ss[g][j] *= inv;
    // ---- PV: thread owns dim d, 8 query rows ----
    float acc[8];
    #pragma unroll
    for (int i = 0; i < 8; ++i) acc[i] = 0.f;
    int d = tid & 127, qh = tid >> 7;
    for (int kt0 = 0; kt0 < kEnd; kt0 += DKT){
      __syncthreads();
      for (int i = tid*4; i < DKT*128; i += 1024){
        int kk = i >> 7, dd = i & 127;
        int kg = kt0 + kk;
        if (kg < SKV){
          ushort4 w = *(const ushort4*)(v + kb0 + (size_t)kg*HD + dd);
          KVs[kk][dd] = b2f(w.x); KVs[kk][dd+1] = b2f(w.y); KVs[kk][dd+2] = b2f(w.z); KVs[kk][dd+3] = b2f(w.w);
        } else {
          KVs[kk][dd] = 0.f; KVs[kk][dd+1] = 0.f; KVs[kk][dd+2] = 0.f; KVs[kk][dd+3] = 0.f;
        }
      }
      __syncthreads();
      int kmax = kEnd - kt0; if (kmax > DKT) kmax = DKT;
      for (int kk4 = 0; kk4 < kmax; kk4 += 4){
        float v0 = KVs[kk4+0][d], v1 = KVs[kk4+1][d];
        float v2 = KVs[kk4+2][d], v3 = KVs[kk4+3][d];
        #pragma unroll
        for (int qq = 0; qq < 8; ++qq){
          float4 p = *(const float4*)&Ss[qh + qq*2][kt0 + kk4];
          acc[qq] += p.x*v0 + p.y*v1 + p.z*v2 + p.w*v3;
        }
      }
    }
    #pragma unroll
    for (int qq = 0; qq < 8; ++qq){
      int qi = qh + qq*2, qg = qt0 + qi;
      if (qg < L_IN) q[qb0 + (size_t)qg*HD + d] = f2b(acc[qq]);
    }
  }
}

// ---------------- prediction head ----------------
__global__ void pred_kernel(const float* __restrict__ X, const void* __restrict__ w,
                            void* __restrict__ out, const u16* __restrict__ det)
{
  bool f32 = is_f32(det);
  int idx = blockIdx.x * 256 + threadIdx.x;
  if (idx >= BSZ*L_IN*7) return;
  int c  = idx % 7;
  int rl = idx / 7;
  const float* xr = X + (size_t)rl*DM;
  float acc = 0.f;
  for (int kk = 0; kk < DM; ++kk) acc += xr[kk] * ldv(w, kk*7 + c, f32);
  if (f32) ((float*)out)[idx] = acc;
  else     ((u16*)out)[idx] = f2b(acc);
}

// ---------------- launch ----------------
extern "C" void kernel_launch(void* const* d_in, const int* in_sizes, int n_in,
                              void* d_out, int out_size, void* d_ws, size_t ws_size,
                              hipStream_t stream)
{
  (void)in_sizes; (void)n_in; (void)out_size; (void)ws_size;
  #define IN(i) ((const void*)d_in[i])
  const u16* det = (const u16*)d_in[20];   // bc_ln_g = ones -> dtype detector
  float* ws   = (float*)d_ws;
  float* encx = ws + OFF_ENCX;
  float* decx = ws + OFF_DECX;
  u16*   qb   = (u16*)(ws + OFF_QB);
  u16*   kb   = (u16*)(ws + OFF_KB);
  u16*   vb   = (u16*)(ws + OFF_VB);
  int*   nbr  = (int*)(ws + OFF_NBR);
  // phase-disjoint aliases
  float* tmp1  = ws + OFF_KB;               // f32 [64,222,512] pre-LN sum (K dead)
  u16*   tmph  = (u16*)(ws + OFF_VB);       // bf16 [64,222,512] ffn hidden (V dead)
  float* embE  = ws + OFF_VB;               // f32 [64,168,512] enc embed (pre-encoder)
  float* bdown = ws + OFF_KB;               // f32 [64,168,128]
  float* bconv = bdown + (size_t)BSZ*L_IN*128;   // f32 [64,54,128]
  float* bup   = bconv + (size_t)BSZ*54*128;     // f32 [64,54,512]

  build_nbr_kernel<<<1, 256, 0, stream>>>(nbr);

  embed_kernel<<<(BSZ*L_IN*DM)/256, 256, 0, stream>>>(IN(0), IN(1), IN(4), IN(5), IN(6), det, embE);
  embed_kernel<<<(BSZ*L_IN*DM)/256, 256, 0, stream>>>(IN(2), IN(3), IN(7), IN(8), IN(9), det, decx);

  // bottleneck
  gemm_k<0,0,0><<<dim3(128/BN, (BSZ*L_IN)/BM), 256, 0, stream>>>(
      embE, IN(10), 0, IN(11), 0, nullptr, bdown, det, 512, 128, L_IN, L_IN, 0);
  conv_bn_elu_kernel<<<(BSZ*42*128)/256, 256, 0, stream>>>(
      bdown, L_IN, 0, bconv, 54, 0, 42,
      IN(12), IN(13), IN(14), IN(15), IN(16), IN(17), det, 0);
  conv_bn_elu_kernel<<<(BSZ*10*128)/256, 256, 0, stream>>>(
      bconv, 54, 0, bconv, 54, 42, 10,
      IN(12), IN(13), IN(14), IN(15), IN(16), IN(17), det, 1);
  conv_bn_elu_kernel<<<(BSZ*2*128)/256, 256, 0, stream>>>(
      bconv, 54, 42, bconv, 54, 52, 2,
      IN(12), IN(13), IN(14), IN(15), IN(16), IN(17), det, 2);
  gemm_k<0,0,0><<<dim3(512/BN, (BSZ*54)/BM), 256, 0, stream>>>(
      bconv, IN(18), 0, IN(19), 0, nullptr, bup, det, 128, 512, 54, 54, 0);
  concat_ln_kernel<<<BSZ*S1, 64, 0, stream>>>(embE, bup, IN(20), IN(21), encx, det);

  // encoder layers
  for (int i = 0; i < 6; ++i){
    long long wO = (long long)i*512*768, oO = (long long)i*768*512;
    long long bO = (long long)i*768, dO = (long long)i*512;
    long long fO = (long long)i*512*512;
    gemm_k<0,0,1><<<dim3(768/BN, (BSZ*S1)/BM), 256, 0, stream>>>(
        encx, IN(22), wO, IN(23), bO, nullptr, qb, det, 512, 768, S1, S1, 0);
    gemm_k<0,0,1><<<dim3(768/BN, (BSZ*S1)/BM), 256, 0, stream>>>(
        encx, IN(24), wO, IN(25), bO, nullptr, kb, det, 512, 768, S1, S1, 0);
    gemm_k<0,0,1><<<dim3(768/BN, (BSZ*S1)/BM), 256, 0, stream>>>(
        encx, IN(26), wO, IN(27), bO, nullptr, vb, det, 512, 768, S1, S1, 0);
    attn_enc_sparse<<<dim3(BSZ*S1), 384, 0, stream>>>(qb, kb, vb, nbr);
    gemm_k<2,1,0><<<dim3(512/BN, (BSZ*S1)/BM), 256, 0, stream>>>(
        qb, IN(28), oO, IN(29), dO, encx, tmp1, det, 768, 512, S1, S1, 0);
    ln_kernel<<<BSZ*S1, 64, 0, stream>>>(tmp1, IN(30), dO, IN(31), dO, 1e-6f, encx, det);
    gemm_k<1,0,1><<<dim3(512/BN, (BSZ*S1)/BM), 256, 0, stream>>>(
        encx, IN(32), fO, IN(33), dO, nullptr, tmph, det, 512, 512, S1, S1, 0);
    gemm_k<2,1,0><<<dim3(512/BN, (BSZ*S1)/BM), 256, 0, stream>>>(
        tmph, IN(34), fO, IN(35), dO, encx, tmp1, det, 512, 512, S1, S1, 0);
    ln_kernel<<<BSZ*S1, 64, 0, stream>>>(tmp1, IN(36), dO, IN(37), dO, 1e-6f, encx, det);
  }

  // decoder layers (kv = concat(encx, decx) via row-remapped K/V GEMMs)
  for (int i = 0; i < 2; ++i){
    long long wO = (long long)i*512*768, oO = (long long)i*768*512;
    long long bO = (long long)i*768, dO = (long long)i*512;
    long long fO = (long long)i*512*512;
    gemm_k<0,0,1><<<dim3(768/BN, (BSZ*L_IN)/BM), 256, 0, stream>>>(
        decx, IN(38), wO, IN(39), bO, nullptr, qb, det, 512, 768, L_IN, L_IN, 0);
    gemm_k<0,0,1><<<dim3(768/BN, (BSZ*S1)/BM), 256, 0, stream>>>(
        encx, IN(40), wO, IN(41), bO, nullptr, kb, det, 512, 768, S1, SKV, 0);
    gemm_k<0,0,1><<<dim3(768/BN, (BSZ*L_IN)/BM), 256, 0, stream>>>(
        decx, IN(40), wO, IN(41), bO, nullptr, kb, det, 512, 768, L_IN, SKV, S1);
    gemm_k<0,0,1><<<dim3(768/BN, (BSZ*S1)/BM), 256, 0, stream>>>(
        encx, IN(42), wO, IN(43), bO, nullptr, vb, det, 512, 768, S1, SKV, 0);
    gemm_k<0,0,1><<<dim3(768/BN, (BSZ*L_IN)/BM), 256, 0, stream>>>(
        decx, IN(42), wO, IN(43), bO, nullptr, vb, det, 512, 768, L_IN, SKV, S1);
    attn_dec_kernel<<<dim3(BSZ, NHD), 256, 0, stream>>>(qb, kb, vb);
    gemm_k<2,1,0><<<dim3(512/BN, (BSZ*L_IN)/BM), 256, 0, stream>>>(
        qb, IN(44), oO, IN(45), dO, decx, tmp1, det, 768, 512, L_IN, L_IN, 0);
    ln_kernel<<<BSZ*L_IN, 64, 0, stream>>>(tmp1, IN(46), dO, IN(47), dO, 1e-6f, decx, det);
    gemm_k<1,0,1><<<dim3(512/BN, (BSZ*L_IN)/BM), 256, 0, stream>>>(
        decx, IN(48), fO, IN(49), dO, nullptr, tmph, det, 512, 512, L_IN, L_IN, 0);
    gemm_k<2,1,0><<<dim3(512/BN, (BSZ*L_IN)/BM), 256, 0, stream>>>(
        tmph, IN(50), fO, IN(51), dO, decx, tmp1, det, 512, 512, L_IN, L_IN, 0);
    ln_kernel<<<BSZ*L_IN, 64, 0, stream>>>(tmp1, IN(52), dO, IN(53), dO, 1e-6f, decx, det);
  }

  pred_kernel<<<(BSZ*L_IN*7 + 255)/256, 256, 0, stream>>>(decx, IN(54), d_out, det);
  #undef IN
}

// Round 5
// 5798.271 us; speedup vs baseline: 2.5396x; 1.8996x over previous
//
#include <hip/hip_runtime.h>
#include <cstdint>
#include <cstddef>

// ---------------- model constants ----------------
#define BSZ   64
#define L_IN  168      // input / predict length
#define S1    222      // encoder sequence after pyramid (168+42+10+2)
#define SKV   390      // decoder kv length (222+168)
#define DM    512
#define HD    768      // 6 heads * 128
#define NHD   6
#define DK    128

typedef unsigned short u16;
typedef __attribute__((ext_vector_type(8))) short bf16x8;
typedef __attribute__((ext_vector_type(4))) float f32x4v;

// ---------------- bf16 helpers ----------------
__device__ inline float b2f(u16 u){
  union { unsigned int i; float f; } v; v.i = ((unsigned int)u) << 16; return v.f;
}
__device__ inline u16 f2b(float f){
  union { float f; unsigned int i; } v; v.f = f;
  unsigned int x = v.i;
  return (u16)((x + 0x7fffu + ((x >> 16) & 1u)) >> 16);
}
__device__ inline unsigned int pk2(float a, float b){
  return ((unsigned int)f2b(b) << 16) | (unsigned int)f2b(a);
}
// dual-dtype input loads: f32 flag chooses float32 vs bf16 interpretation of d_in
__device__ inline float ldv(const void* p, long long i, bool f32){
  return f32 ? ((const float*)p)[i] : b2f(((const u16*)p)[i]);
}
__device__ inline float4 ldv4(const void* p, long long i, bool f32){
  if (f32) return *(const float4*)((const float*)p + i);
  ushort4 w = *(const ushort4*)((const u16*)p + i);
  return make_float4(b2f(w.x), b2f(w.y), b2f(w.z), b2f(w.w));
}
__device__ inline bool is_f32(const u16* det){ return det[0] != 0x3F80; }

// ---------------- workspace layout (float-equivalent offsets), total ~149.6 MB ----------------
constexpr size_t OFF_ENCX = 0;                                  // f32 [64,222,512]
constexpr size_t OFF_DECX = OFF_ENCX + (size_t)BSZ*S1*DM;       // f32 [64,168,512]
constexpr size_t OFF_QB   = OFF_DECX + (size_t)BSZ*L_IN*DM;     // bf16 [64,222,768]
constexpr size_t OFF_KB   = OFF_QB   + (size_t)BSZ*S1*HD/2;     // bf16 [64,390,768]
constexpr size_t OFF_VB   = OFF_KB   + (size_t)BSZ*SKV*HD/2;    // bf16 [64,390,768]
constexpr size_t OFF_NBR  = OFF_VB   + (size_t)BSZ*SKV*HD/2;    // int[222*12]
// aliases:
//  tmp1 (f32 pre-LN)  -> vb base   (V dead by then)         needs <= 7,274,496 f
//  WtE (enc Wt bf16)  -> vb + 7,274,496 f (disjoint from V data AND tmp1)
//  WtD (dec Wt bf16)  -> qb + 4,128,768 f (beyond dec-q footprint)
//  tmph (bf16 hidden) -> kb base   (K dead by then)
//  embE (f32)         -> vb base   (pre-encoder only)
//  bottleneck scratch -> kb base

// ---------------- PAM sparsity: per-query neighbor list ----------------
__device__ inline int scale_of(int i, int& ii){
  if (i < 168){ ii = i;       return 0; }
  if (i < 210){ ii = i - 168; return 1; }
  if (i < 220){ ii = i - 210; return 2; }
  ii = i - 220; return 3;
}
__device__ inline bool pam_ok(int i, int j){
  int ii, jj;
  int li = scale_of(i, ii);
  int lj = scale_of(j, jj);
  const int n[4] = {168, 42, 10, 2};
  if (li == lj){ int d = ii - jj; return (d <= 1 && d >= -1); }
  if (li == lj + 1){ int lo = ii*4, hi = (ii == n[li]-1) ? n[lj] : ii*4+4; return (jj >= lo && jj < hi); }
  if (lj == li + 1){ int lo = jj*4, hi = (jj == n[lj]-1) ? n[li] : jj*4+4; return (ii >= lo && ii < hi); }
  return false;
}
__global__ void build_nbr_kernel(int* __restrict__ nbr){
  int q = blockIdx.x * 256 + threadIdx.x;
  if (q >= S1) return;
  int cnt = 0;
  int list[12];
  for (int j = 0; j < S1; ++j)
    if (pam_ok(q, j) && cnt < 12) list[cnt++] = j;
  #pragma unroll
  for (int t = 0; t < 12; ++t) nbr[q*12 + t] = (t < cnt) ? list[t] : -1;
}

// ---------------- embedding ----------------
__global__ void embed_kernel(const void* __restrict__ x, const void* __restrict__ t,
                             const void* __restrict__ cw, const void* __restrict__ tw,
                             const void* __restrict__ tb, const u16* __restrict__ det,
                             float* __restrict__ out)
{
  bool f32 = is_f32(det);
  int idx = blockIdx.x * 256 + threadIdx.x;
  if (idx >= BSZ*L_IN*DM) return;
  int d = idx & (DM-1);
  int l = (idx >> 9) % L_IN;
  int b = idx / (DM*L_IN);
  float acc = 0.f;
  #pragma unroll
  for (int tt = 0; tt < 3; ++tt){
    int ls = l + tt - 1;
    ls = (ls < 0) ? ls + L_IN : (ls >= L_IN ? ls - L_IN : ls);
    long long xo = ((long long)(b*L_IN + ls))*7;
    #pragma unroll
    for (int c = 0; c < 7; ++c)
      acc += ldv(x, xo + c, f32) * ldv(cw, d*21 + c*3 + tt, f32);
  }
  int d2 = d & ~1;
  float dv  = expf(-(float)d2 * (9.210340371976184f/512.f));
  float ang = (float)l * dv;
  acc += (d & 1) ? cosf(ang) : sinf(ang);
  long long to = ((long long)(b*L_IN + l))*4;
  #pragma unroll
  for (int f = 0; f < 4; ++f) acc += ldv(t, to + f, f32) * ldv(tw, f*DM + d, f32);
  acc += ldv(tb, d, f32);
  out[idx] = acc;
}

// ---------------- weight transpose: W[K,N] (d_in dtype) -> Wt bf16 [N,K] ----------------
__global__ __launch_bounds__(256)
void wt_kernel(const void* __restrict__ W, long long wOff, u16* __restrict__ Wt,
               int K, int N, const u16* __restrict__ det)
{
  bool f32 = is_f32(det);
  __shared__ float t[32][33];
  int k0 = blockIdx.y*32, n0 = blockIdx.x*32;
  int c = threadIdx.x & 31, r0 = threadIdx.x >> 5;  // 8 rows per pass
  #pragma unroll
  for (int rr = 0; rr < 32; rr += 8)
    t[r0+rr][c] = ldv(W, wOff + (long long)(k0+r0+rr)*N + n0 + c, f32);
  __syncthreads();
  #pragma unroll
  for (int rr = 0; rr < 32; rr += 8)
    Wt[(size_t)(n0+r0+rr)*K + k0 + c] = f2b(t[c][r0+rr]);
}

// ---------------- MFMA GEMM: C = A[M,K] @ W[K,N] via Wt bf16 [N,K] ----------------
// ABF: A bf16 (else f32, converted during staging). CBF: C bf16 (else f32).
// EPI: 0 bias, 1 bias+GELU, 2 bias+residual R (f32). Row remap r->(b=r/La, l): C row b*Lc+off+l.
template<int EPI, int ABF, int CBF>
__global__ __launch_bounds__(256)
void gemm_mfma(const void* __restrict__ Av, const u16* __restrict__ Wt,
               const void* __restrict__ bias, long long bOff, const float* __restrict__ R,
               void* __restrict__ Cv, const u16* __restrict__ det,
               int K, int N, int La, int Lc, int off)
{
  __shared__ u16 As[128][64];
  __shared__ u16 Bs[128][64];
  bool f32 = is_f32(det);
  int tid = threadIdx.x;
  int row0 = blockIdx.y*128, col0 = blockIdx.x*128;
  int wave = tid >> 6, lane = tid & 63;
  int wm = (wave >> 1)*64, wn = (wave & 1)*64;
  int lm = lane & 15, quad = lane >> 4;
  int sr = tid >> 1;             // staging row 0..127
  int sh = (tid & 1) * 32;       // k-half
  int swzS = (sr & 7) * 8;
  f32x4v acc[4][4];
  #pragma unroll
  for (int i = 0; i < 4; ++i)
    #pragma unroll
    for (int j = 0; j < 4; ++j) acc[i][j] = (f32x4v){0.f,0.f,0.f,0.f};

  for (int k0 = 0; k0 < K; k0 += 64){
    // ---- stage A tile [128][64] ----
    if (ABF){
      const u16* src = (const u16*)Av + (size_t)(row0+sr)*K + k0 + sh;
      uint4 v0 = *(const uint4*)(src+0);
      uint4 v1 = *(const uint4*)(src+8);
      uint4 v2 = *(const uint4*)(src+16);
      uint4 v3 = *(const uint4*)(src+24);
      *(uint4*)&As[sr][(sh+0)^swzS]  = v0;
      *(uint4*)&As[sr][(sh+8)^swzS]  = v1;
      *(uint4*)&As[sr][(sh+16)^swzS] = v2;
      *(uint4*)&As[sr][(sh+24)^swzS] = v3;
    } else {
      const float* src = (const float*)Av + (size_t)(row0+sr)*K + k0 + sh;
      #pragma unroll
      for (int j = 0; j < 4; ++j){
        float4 f0 = *(const float4*)(src + 8*j);
        float4 f1 = *(const float4*)(src + 8*j + 4);
        uint4 o;
        o.x = pk2(f0.x, f0.y); o.y = pk2(f0.z, f0.w);
        o.z = pk2(f1.x, f1.y); o.w = pk2(f1.z, f1.w);
        *(uint4*)&As[sr][(sh + 8*j)^swzS] = o;
      }
    }
    // ---- stage B tile: Wt rows col0..col0+127 ----
    {
      const u16* src = Wt + (size_t)(col0+sr)*K + k0 + sh;
      uint4 v0 = *(const uint4*)(src+0);
      uint4 v1 = *(const uint4*)(src+8);
      uint4 v2 = *(const uint4*)(src+16);
      uint4 v3 = *(const uint4*)(src+24);
      *(uint4*)&Bs[sr][(sh+0)^swzS]  = v0;
      *(uint4*)&Bs[sr][(sh+8)^swzS]  = v1;
      *(uint4*)&Bs[sr][(sh+16)^swzS] = v2;
      *(uint4*)&Bs[sr][(sh+24)^swzS] = v3;
    }
    __syncthreads();
    // ---- fragments + MFMA ----
    bf16x8 af[4][2], bfr[4][2];
    #pragma unroll
    for (int mi = 0; mi < 4; ++mi){
      int m = wm + mi*16 + lm;
      int sz = (m & 7)*8;
      af[mi][0] = *(const bf16x8*)&As[m][(quad*8) ^ sz];
      af[mi][1] = *(const bf16x8*)&As[m][(32 + quad*8) ^ sz];
    }
    #pragma unroll
    for (int ni = 0; ni < 4; ++ni){
      int n = wn + ni*16 + lm;
      int sz = (n & 7)*8;
      bfr[ni][0] = *(const bf16x8*)&Bs[n][(quad*8) ^ sz];
      bfr[ni][1] = *(const bf16x8*)&Bs[n][(32 + quad*8) ^ sz];
    }
    #pragma unroll
    for (int mi = 0; mi < 4; ++mi)
      #pragma unroll
      for (int ni = 0; ni < 4; ++ni){
        acc[mi][ni] = __builtin_amdgcn_mfma_f32_16x16x32_bf16(af[mi][0], bfr[ni][0], acc[mi][ni], 0, 0, 0);
        acc[mi][ni] = __builtin_amdgcn_mfma_f32_16x16x32_bf16(af[mi][1], bfr[ni][1], acc[mi][ni], 0, 0, 0);
      }
    __syncthreads();
  }
  // ---- epilogue: C/D layout col=lane&15, row=quad*4+reg ----
  #pragma unroll
  for (int mi = 0; mi < 4; ++mi){
    #pragma unroll
    for (int r = 0; r < 4; ++r){
      int row = row0 + wm + mi*16 + quad*4 + r;
      int bb = row / La, l = row - bb*La;
      size_t crow = ((size_t)bb*Lc + off + l)*(size_t)N;
      #pragma unroll
      for (int ni = 0; ni < 4; ++ni){
        int col = col0 + wn + ni*16 + lm;
        float vv = acc[mi][ni][r] + ldv(bias, bOff + col, f32);
        if (EPI == 1) vv = 0.5f*vv*(1.f + erff(vv*0.70710678118654752f));
        if (EPI == 2) vv += R[crow + col];
        if (CBF) ((u16*)Cv)[crow + col] = f2b(vv);
        else     ((float*)Cv)[crow + col] = vv;
      }
    }
  }
}

// ---------------- SIMT GEMM (bottleneck only) ----------------
#define BM 64
#define BN 64
#define BK 16
__global__ __launch_bounds__(256)
void gemm_k(const float* __restrict__ A, const void* __restrict__ W, long long wOff,
            const void* __restrict__ bias, long long bOff,
            float* __restrict__ C, const u16* __restrict__ det, int K, int N)
{
  __shared__ float As2[BK][BM+4];
  __shared__ float Bs2[BK][BN+4];
  bool f32 = is_f32(det);
  int tid = threadIdx.x;
  int row0 = blockIdx.y * BM, col0 = blockIdx.x * BN;
  int ty = tid >> 4, tx = tid & 15;
  int lr = tid >> 2, lc4 = (tid & 3) << 2;
  int wr = tid >> 4, wc4 = (tid & 15) << 2;
  float acc[4][4] = {};
  for (int k0 = 0; k0 < K; k0 += BK){
    float4 av = *(const float4*)(A + (size_t)(row0 + lr)*K + k0 + lc4);
    As2[lc4+0][lr] = av.x; As2[lc4+1][lr] = av.y;
    As2[lc4+2][lr] = av.z; As2[lc4+3][lr] = av.w;
    float4 wv = ldv4(W, wOff + (long long)(k0 + wr)*N + col0 + wc4, f32);
    *(float4*)&Bs2[wr][wc4] = wv;
    __syncthreads();
    #pragma unroll
    for (int kk = 0; kk < BK; ++kk){
      float4 a  = *(const float4*)&As2[kk][ty << 2];
      float4 bb = *(const float4*)&Bs2[kk][tx << 2];
      acc[0][0] += a.x*bb.x; acc[0][1] += a.x*bb.y; acc[0][2] += a.x*bb.z; acc[0][3] += a.x*bb.w;
      acc[1][0] += a.y*bb.x; acc[1][1] += a.y*bb.y; acc[1][2] += a.y*bb.z; acc[1][3] += a.y*bb.w;
      acc[2][0] += a.z*bb.x; acc[2][1] += a.z*bb.y; acc[2][2] += a.z*bb.z; acc[2][3] += a.z*bb.w;
      acc[3][0] += a.w*bb.x; acc[3][1] += a.w*bb.y; acc[3][2] += a.w*bb.z; acc[3][3] += a.w*bb.w;
    }
    __syncthreads();
  }
  #pragma unroll
  for (int i = 0; i < 4; ++i){
    int r = row0 + (ty << 2) + i;
    size_t crow = (size_t)r*(size_t)N;
    #pragma unroll
    for (int j = 0; j < 4; ++j){
      int c = col0 + (tx << 2) + j;
      C[crow + c] = acc[i][j] + ldv(bias, bOff + c, f32);
    }
  }
}

// ---------------- bottleneck strided conv (k=4, s=4) + BN(eval) + ELU ----------------
__global__ void conv_bn_elu_kernel(const float* __restrict__ in, int inStride, int inOff,
                                   float* __restrict__ out, int outStride, int outOff, int Lout,
                                   const void* __restrict__ w, const void* __restrict__ cb,
                                   const void* __restrict__ bg, const void* __restrict__ bb,
                                   const void* __restrict__ bm, const void* __restrict__ bv,
                                   const u16* __restrict__ det, int lay)
{
  bool f32 = is_f32(det);
  int idx = blockIdx.x * 256 + threadIdx.x;
  int total = BSZ * Lout * 128;
  if (idx >= total) return;
  int co = idx & 127;
  int j  = (idx >> 7) % Lout;
  int b  = idx / (128 * Lout);
  const float* ir = in + ((size_t)(b*inStride + inOff + j*4))*128;
  long long wo = (long long)lay*65536 + (long long)co*512;
  float acc = 0.f;
  for (int ci = 0; ci < 128; ++ci){
    #pragma unroll
    for (int tt = 0; tt < 4; ++tt)
      acc += ir[tt*128 + ci] * ldv(w, wo + ci*4 + tt, f32);
  }
  long long po = (long long)lay*128 + co;
  acc += ldv(cb, po, f32);
  acc = (acc - ldv(bm, po, f32)) * rsqrtf(ldv(bv, po, f32) + 1e-5f) * ldv(bg, po, f32) + ldv(bb, po, f32);
  acc = acc > 0.f ? acc : (__expf(acc) - 1.f);
  out[((size_t)(b*outStride + outOff + j))*128 + co] = acc;
}

// ---------------- LayerNorm ----------------
__global__ __launch_bounds__(64)
void ln_kernel(const float* __restrict__ X, const void* __restrict__ g, long long gOff,
               const void* __restrict__ bt, long long bOff, float eps,
               float* __restrict__ Out, const u16* __restrict__ det)
{
  bool f32 = is_f32(det);
  int row = blockIdx.x, lane = threadIdx.x;
  const float* xr = X + (size_t)row*DM;
  float v[8]; float s = 0.f;
  #pragma unroll
  for (int i = 0; i < 8; ++i){ v[i] = xr[lane + i*64]; s += v[i]; }
  #pragma unroll
  for (int o = 32; o > 0; o >>= 1) s += __shfl_xor(s, o);
  float mean = s * (1.f/512.f);
  float q = 0.f;
  #pragma unroll
  for (int i = 0; i < 8; ++i){ float d = v[i]-mean; q += d*d; }
  #pragma unroll
  for (int o = 32; o > 0; o >>= 1) q += __shfl_xor(q, o);
  float inv = rsqrtf(q*(1.f/512.f) + eps);
  float* orow = Out + (size_t)row*DM;
  #pragma unroll
  for (int i = 0; i < 8; ++i){
    int c = lane + i*64;
    orow[c] = (v[i]-mean)*inv*ldv(g, gOff + c, f32) + ldv(bt, bOff + c, f32);
  }
}

// ---------------- concat(embed[168], up[54]) + LayerNorm(1e-5) ----------------
__global__ __launch_bounds__(64)
void concat_ln_kernel(const float* __restrict__ emb, const float* __restrict__ up,
                      const void* __restrict__ g, const void* __restrict__ bt,
                      float* __restrict__ Out, const u16* __restrict__ det)
{
  bool f32 = is_f32(det);
  int row = blockIdx.x, lane = threadIdx.x;
  int b = row / S1, l = row - b*S1;
  const float* xr = (l < L_IN) ? emb + ((size_t)(b*L_IN + l))*DM
                               : up  + ((size_t)(b*54 + (l - L_IN)))*DM;
  float v[8]; float s = 0.f;
  #pragma unroll
  for (int i = 0; i < 8; ++i){ v[i] = xr[lane + i*64]; s += v[i]; }
  #pragma unroll
  for (int o = 32; o > 0; o >>= 1) s += __shfl_xor(s, o);
  float mean = s * (1.f/512.f);
  float q = 0.f;
  #pragma unroll
  for (int i = 0; i < 8; ++i){ float d = v[i]-mean; q += d*d; }
  #pragma unroll
  for (int o = 32; o > 0; o >>= 1) q += __shfl_xor(q, o);
  float inv = rsqrtf(q*(1.f/512.f) + 1e-5f);
  float* orow = Out + (size_t)row*DM;
  #pragma unroll
  for (int i = 0; i < 8; ++i){
    int c = lane + i*64;
    orow[c] = (v[i]-mean)*inv*ldv(g, c, f32) + ldv(bt, c, f32);
  }
}

// ---------------- encoder attention: PAM-sparse, one wave per (b,q,h) ----------------
__global__ __launch_bounds__(384)
void attn_enc_sparse(u16* __restrict__ q, const u16* __restrict__ k,
                     const u16* __restrict__ v, const int* __restrict__ nbr)
{
  __shared__ int nb[12];
  int blk = blockIdx.x;
  int b = blk / S1, qr = blk - b*S1;
  if (threadIdx.x < 12) nb[threadIdx.x] = nbr[qr*12 + threadIdx.x];
  __syncthreads();
  int h = threadIdx.x >> 6;
  int lane = threadIdx.x & 63;
  const float scale = 0.088388347648318447f;
  size_t rowoff = ((size_t)b*S1 + qr)*HD + h*DK;
  unsigned int qw = ((const unsigned int*)(q + rowoff))[lane];
  float q0 = b2f((u16)(qw & 0xffff)), q1 = b2f((u16)(qw >> 16));
  float pj[12];
  #pragma unroll
  for (int j = 0; j < 12; ++j){
    int kg = nb[j];
    float p = 0.f;
    if (kg >= 0){
      unsigned int kw = ((const unsigned int*)(k + ((size_t)b*S1 + kg)*HD + h*DK))[lane];
      p = q0*b2f((u16)(kw & 0xffff)) + q1*b2f((u16)(kw >> 16));
    }
    #pragma unroll
    for (int o = 32; o > 0; o >>= 1) p += __shfl_xor(p, o);
    pj[j] = (kg >= 0) ? p*scale : -1e30f;
  }
  float m = -1e30f;
  #pragma unroll
  for (int j = 0; j < 12; ++j) m = fmaxf(m, pj[j]);
  float s = 0.f;
  #pragma unroll
  for (int j = 0; j < 12; ++j){
    pj[j] = (nb[j] >= 0) ? __expf(pj[j]-m) : 0.f;
    s += pj[j];
  }
  float inv = 1.f / s;
  float o0 = 0.f, o1 = 0.f;
  #pragma unroll
  for (int j = 0; j < 12; ++j){
    int kg = nb[j];
    if (kg >= 0){
      unsigned int vw = ((const unsigned int*)(v + ((size_t)b*S1 + kg)*HD + h*DK))[lane];
      o0 += pj[j]*b2f((u16)(vw & 0xffff));
      o1 += pj[j]*b2f((u16)(vw >> 16));
    }
  }
  unsigned int ow = ((unsigned int)f2b(o1*inv) << 16) | (unsigned int)f2b(o0*inv);
  ((unsigned int*)(q + rowoff))[lane] = ow;
}

// ---------------- decoder attention: one block per (b, q-tile, h), causal clamp ----------------
#define DQT 16
#define DKT 32
#define DSW 396
__global__ __launch_bounds__(256)
void attn_dec_kernel(u16* __restrict__ q, const u16* __restrict__ k,
                     const u16* __restrict__ v)
{
  __shared__ float Qs[DQT][132];
  __shared__ float KVs[DKT][132];
  __shared__ float Ss[DQT][DSW];
  __shared__ float red[DQT][17];
  int b = blockIdx.z, h = blockIdx.y;
  int qt0 = blockIdx.x * DQT;
  int tid = threadIdx.x;
  const float scale = 0.088388347648318447f;
  const size_t qb0 = (size_t)b*L_IN*HD + (size_t)h*DK;
  const size_t kb0 = (size_t)b*SKV*HD + (size_t)h*DK;
  for (int i = tid*4; i < DQT*128; i += 1024){
    int qi = i >> 7, d = i & 127;
    int qg = qt0 + qi;
    if (qg < L_IN){
      ushort4 w = *(const ushort4*)(q + qb0 + (size_t)qg*HD + d);
      Qs[qi][d] = b2f(w.x); Qs[qi][d+1] = b2f(w.y); Qs[qi][d+2] = b2f(w.z); Qs[qi][d+3] = b2f(w.w);
    } else {
      Qs[qi][d] = 0.f; Qs[qi][d+1] = 0.f; Qs[qi][d+2] = 0.f; Qs[qi][d+3] = 0.f;
    }
  }
  int kEnd = S1 + qt0 + DQT; if (kEnd > SKV) kEnd = SKV;
  int kj = tid & 31, qw = tid >> 5;
  for (int kt0 = 0; kt0 < kEnd; kt0 += DKT){
    for (int i = tid*4; i < DKT*128; i += 1024){
      int kk = i >> 7, d = i & 127;
      int kg = kt0 + kk;
      if (kg < SKV){
        ushort4 w = *(const ushort4*)(k + kb0 + (size_t)kg*HD + d);
        KVs[kk][d] = b2f(w.x); KVs[kk][d+1] = b2f(w.y); KVs[kk][d+2] = b2f(w.z); KVs[kk][d+3] = b2f(w.w);
      } else {
        KVs[kk][d] = 0.f; KVs[kk][d+1] = 0.f; KVs[kk][d+2] = 0.f; KVs[kk][d+3] = 0.f;
      }
    }
    __syncthreads();
    int col = kt0 + kj;
    #pragma unroll
    for (int qq = 0; qq < 2; ++qq){
      int qi = qw + qq*8;
      const float4* qr = (const float4*)&Qs[qi][0];
      const float4* kr = (const float4*)&KVs[kj][0];
      float acc = 0.f;
      #pragma unroll 8
      for (int d4 = 0; d4 < 32; ++d4){
        float4 a = qr[d4], c = kr[d4];
        acc += a.x*c.x + a.y*c.y + a.z*c.z + a.w*c.w;
      }
      int qg = qt0 + qi;
      if (col < kEnd){
        bool ok = (qg < L_IN) && (col <= S1 + qg);
        Ss[qi][col] = ok ? acc*scale : -1e30f;
      } else if (col < DSW){
        Ss[qi][col] = 0.f;
      }
    }
    __syncthreads();
  }
  int g = tid >> 4, lg = tid & 15;
  float mx = -1e30f;
  for (int j = lg; j < kEnd; j += 16) mx = fmaxf(mx, Ss[g][j]);
  red[g][lg] = mx;
  __syncthreads();
  if (lg == 0){
    float m2 = -1e30f;
    #pragma unroll
    for (int t2 = 0; t2 < 16; ++t2) m2 = fmaxf(m2, red[g][t2]);
    red[g][16] = m2;
  }
  __syncthreads();
  mx = red[g][16];
  float ps = 0.f;
  for (int j = lg; j < kEnd; j += 16){
    float p = __expf(Ss[g][j] - mx);
    Ss[g][j] = p; ps += p;
  }
  __syncthreads();
  red[g][lg] = ps;
  __syncthreads();
  if (lg == 0){
    float s2 = 0.f;
    #pragma unroll
    for (int t2 = 0; t2 < 16; ++t2) s2 += red[g][t2];
    red[g][16] = s2;
  }
  __syncthreads();
  float inv = 1.f / red[g][16];
  for (int j = lg; j < kEnd; j += 16) Ss[g][j] *= inv;
  float acc[8];
  #pragma unroll
  for (int i = 0; i < 8; ++i) acc[i] = 0.f;
  int d = tid & 127, qh = tid >> 7;
  for (int kt0 = 0; kt0 < kEnd; kt0 += DKT){
    __syncthreads();
    for (int i = tid*4; i < DKT*128; i += 1024){
      int kk = i >> 7, dd = i & 127;
      int kg = kt0 + kk;
      if (kg < SKV){
        ushort4 w = *(const ushort4*)(v + kb0 + (size_t)kg*HD + dd);
        KVs[kk][dd] = b2f(w.x); KVs[kk][dd+1] = b2f(w.y); KVs[kk][dd+2] = b2f(w.z); KVs[kk][dd+3] = b2f(w.w);
      } else {
        KVs[kk][dd] = 0.f; KVs[kk][dd+1] = 0.f; KVs[kk][dd+2] = 0.f; KVs[kk][dd+3] = 0.f;
      }
    }
    __syncthreads();
    int kmax = kEnd - kt0; if (kmax > DKT) kmax = DKT;
    for (int kk4 = 0; kk4 < kmax; kk4 += 4){
      float v0 = KVs[kk4+0][d], v1 = KVs[kk4+1][d];
      float v2 = KVs[kk4+2][d], v3 = KVs[kk4+3][d];
      #pragma unroll
      for (int qq = 0; qq < 8; ++qq){
        float4 p = *(const float4*)&Ss[qh + qq*2][kt0 + kk4];
        acc[qq] += p.x*v0 + p.y*v1 + p.z*v2 + p.w*v3;
      }
    }
  }
  #pragma unroll
  for (int qq = 0; qq < 8; ++qq){
    int qi = qh + qq*2, qg = qt0 + qi;
    if (qg < L_IN) q[qb0 + (size_t)qg*HD + d] = f2b(acc[qq]);
  }
}

// ---------------- prediction head ----------------
__global__ void pred_kernel(const float* __restrict__ X, const void* __restrict__ w,
                            void* __restrict__ out, const u16* __restrict__ det)
{
  bool f32 = is_f32(det);
  int idx = blockIdx.x * 256 + threadIdx.x;
  if (idx >= BSZ*L_IN*7) return;
  int c  = idx % 7;
  int rl = idx / 7;
  const float* xr = X + (size_t)rl*DM;
  float acc = 0.f;
  for (int kk = 0; kk < DM; ++kk) acc += xr[kk] * ldv(w, kk*7 + c, f32);
  if (f32) ((float*)out)[idx] = acc;
  else     ((u16*)out)[idx] = f2b(acc);
}

// ---------------- launch ----------------
extern "C" void kernel_launch(void* const* d_in, const int* in_sizes, int n_in,
                              void* d_out, int out_size, void* d_ws, size_t ws_size,
                              hipStream_t stream)
{
  (void)in_sizes; (void)n_in; (void)out_size; (void)ws_size;
  #define IN(i) ((const void*)d_in[i])
  const u16* det = (const u16*)d_in[20];
  float* ws   = (float*)d_ws;
  float* encx = ws + OFF_ENCX;
  float* decx = ws + OFF_DECX;
  u16*   qb   = (u16*)(ws + OFF_QB);
  u16*   kb   = (u16*)(ws + OFF_KB);
  u16*   vb   = (u16*)(ws + OFF_VB);
  int*   nbr  = (int*)(ws + OFF_NBR);
  // phase-disjoint aliases
  float* tmp1  = ws + OFF_VB;                              // f32 pre-LN sums (V dead)
  u16*   WtE   = (u16*)(ws + OFF_VB + (size_t)BSZ*S1*DM);  // enc Wt scratch (beyond V data & tmp1)
  u16*   WtD   = (u16*)(ws + OFF_QB + (size_t)BSZ*L_IN*HD/2); // dec Wt scratch (beyond dec-q)
  u16*   tmph  = (u16*)(ws + OFF_KB);                      // bf16 ffn hidden (K dead)
  float* embE  = ws + OFF_VB;                              // f32 enc embed (pre-encoder)
  float* bdown = ws + OFF_KB;
  float* bconv = bdown + (size_t)BSZ*L_IN*128;
  float* bup   = bconv + (size_t)BSZ*54*128;

  build_nbr_kernel<<<1, 256, 0, stream>>>(nbr);

  embed_kernel<<<(BSZ*L_IN*DM)/256, 256, 0, stream>>>(IN(0), IN(1), IN(4), IN(5), IN(6), det, embE);
  embed_kernel<<<(BSZ*L_IN*DM)/256, 256, 0, stream>>>(IN(2), IN(3), IN(7), IN(8), IN(9), det, decx);

  // bottleneck (SIMT GEMMs — small)
  gemm_k<<<dim3(128/BN, (BSZ*L_IN)/BM), 256, 0, stream>>>(
      embE, IN(10), 0, IN(11), 0, bdown, det, 512, 128);
  conv_bn_elu_kernel<<<(BSZ*42*128)/256, 256, 0, stream>>>(
      bdown, L_IN, 0, bconv, 54, 0, 42, IN(12), IN(13), IN(14), IN(15), IN(16), IN(17), det, 0);
  conv_bn_elu_kernel<<<(BSZ*10*128)/256, 256, 0, stream>>>(
      bconv, 54, 0, bconv, 54, 42, 10, IN(12), IN(13), IN(14), IN(15), IN(16), IN(17), det, 1);
  conv_bn_elu_kernel<<<(BSZ*2*128)/256, 256, 0, stream>>>(
      bconv, 54, 42, bconv, 54, 52, 2, IN(12), IN(13), IN(14), IN(15), IN(16), IN(17), det, 2);
  gemm_k<<<dim3(512/BN, (BSZ*54)/BM), 256, 0, stream>>>(
      bconv, IN(18), 0, IN(19), 0, bup, det, 128, 512);
  concat_ln_kernel<<<BSZ*S1, 64, 0, stream>>>(embE, bup, IN(20), IN(21), encx, det);

  // encoder layers
  for (int i = 0; i < 6; ++i){
    long long wO = (long long)i*512*768, oO = (long long)i*768*512;
    long long bO = (long long)i*768, dO = (long long)i*512;
    long long fO = (long long)i*512*512;
    wt_kernel<<<dim3(768/32, 512/32), 256, 0, stream>>>(IN(22), wO, WtE, 512, 768, det);
    gemm_mfma<0,0,1><<<dim3(6, 111), 256, 0, stream>>>(
        encx, WtE, IN(23), bO, nullptr, qb, det, 512, 768, S1, S1, 0);
    wt_kernel<<<dim3(768/32, 512/32), 256, 0, stream>>>(IN(24), wO, WtE, 512, 768, det);
    gemm_mfma<0,0,1><<<dim3(6, 111), 256, 0, stream>>>(
        encx, WtE, IN(25), bO, nullptr, kb, det, 512, 768, S1, S1, 0);
    wt_kernel<<<dim3(768/32, 512/32), 256, 0, stream>>>(IN(26), wO, WtE, 512, 768, det);
    gemm_mfma<0,0,1><<<dim3(6, 111), 256, 0, stream>>>(
        encx, WtE, IN(27), bO, nullptr, vb, det, 512, 768, S1, S1, 0);
    attn_enc_sparse<<<dim3(BSZ*S1), 384, 0, stream>>>(qb, kb, vb, nbr);
    wt_kernel<<<dim3(512/32, 768/32), 256, 0, stream>>>(IN(28), oO, WtE, 768, 512, det);
    gemm_mfma<2,1,0><<<dim3(4, 111), 256, 0, stream>>>(
        qb, WtE, IN(29), dO, encx, tmp1, det, 768, 512, S1, S1, 0);
    ln_kernel<<<BSZ*S1, 64, 0, stream>>>(tmp1, IN(30), dO, IN(31), dO, 1e-6f, encx, det);
    wt_kernel<<<dim3(512/32, 512/32), 256, 0, stream>>>(IN(32), fO, WtE, 512, 512, det);
    gemm_mfma<1,0,1><<<dim3(4, 111), 256, 0, stream>>>(
        encx, WtE, IN(33), dO, nullptr, tmph, det, 512, 512, S1, S1, 0);
    wt_kernel<<<dim3(512/32, 512/32), 256, 0, stream>>>(IN(34), fO, WtE, 512, 512, det);
    gemm_mfma<2,1,0><<<dim3(4, 111), 256, 0, stream>>>(
        tmph, WtE, IN(35), dO, encx, tmp1, det, 512, 512, S1, S1, 0);
    ln_kernel<<<BSZ*S1, 64, 0, stream>>>(tmp1, IN(36), dO, IN(37), dO, 1e-6f, encx, det);
  }

  // decoder layers
  for (int i = 0; i < 2; ++i){
    long long wO = (long long)i*512*768, oO = (long long)i*768*512;
    long long bO = (long long)i*768, dO = (long long)i*512;
    long long fO = (long long)i*512*512;
    wt_kernel<<<dim3(768/32, 512/32), 256, 0, stream>>>(IN(38), wO, WtD, 512, 768, det);
    gemm_mfma<0,0,1><<<dim3(6, 84), 256, 0, stream>>>(
        decx, WtD, IN(39), bO, nullptr, qb, det, 512, 768, L_IN, L_IN, 0);
    wt_kernel<<<dim3(768/32, 512/32), 256, 0, stream>>>(IN(40), wO, WtD, 512, 768, det);
    gemm_mfma<0,0,1><<<dim3(6, 111), 256, 0, stream>>>(
        encx, WtD, IN(41), bO, nullptr, kb, det, 512, 768, S1, SKV, 0);
    gemm_mfma<0,0,1><<<dim3(6, 84), 256, 0, stream>>>(
        decx, WtD, IN(41), bO, nullptr, kb, det, 512, 768, L_IN, SKV, S1);
    wt_kernel<<<dim3(768/32, 512/32), 256, 0, stream>>>(IN(42), wO, WtD, 512, 768, det);
    gemm_mfma<0,0,1><<<dim3(6, 111), 256, 0, stream>>>(
        encx, WtD, IN(43), bO, nullptr, vb, det, 512, 768, S1, SKV, 0);
    gemm_mfma<0,0,1><<<dim3(6, 84), 256, 0, stream>>>(
        decx, WtD, IN(43), bO, nullptr, vb, det, 512, 768, L_IN, SKV, S1);
    attn_dec_kernel<<<dim3((L_IN+DQT-1)/DQT, NHD, BSZ), 256, 0, stream>>>(qb, kb, vb);
    wt_kernel<<<dim3(512/32, 768/32), 256, 0, stream>>>(IN(44), oO, WtD, 768, 512, det);
    gemm_mfma<2,1,0><<<dim3(4, 84), 256, 0, stream>>>(
        qb, WtD, IN(45), dO, decx, tmp1, det, 768, 512, L_IN, L_IN, 0);
    ln_kernel<<<BSZ*L_IN, 64, 0, stream>>>(tmp1, IN(46), dO, IN(47), dO, 1e-6f, decx, det);
    wt_kernel<<<dim3(512/32, 512/32), 256, 0, stream>>>(IN(48), fO, WtD, 512, 512, det);
    gemm_mfma<1,0,1><<<dim3(4, 84), 256, 0, stream>>>(
        decx, WtD, IN(49), dO, nullptr, tmph, det, 512, 512, L_IN, L_IN, 0);
    wt_kernel<<<dim3(512/32, 512/32), 256, 0, stream>>>(IN(50), fO, WtD, 512, 512, det);
    gemm_mfma<2,1,0><<<dim3(4, 84), 256, 0, stream>>>(
        tmph, WtD, IN(51), dO, decx, tmp1, det, 512, 512, L_IN, L_IN, 0);
    ln_kernel<<<BSZ*L_IN, 64, 0, stream>>>(tmp1, IN(52), dO, IN(53), dO, 1e-6f, decx, det);
  }

  pred_kernel<<<(BSZ*L_IN*7 + 255)/256, 256, 0, stream>>>(decx, IN(54), d_out, det);
  #undef IN
}

// Round 6
// 4553.783 us; speedup vs baseline: 3.2337x; 1.2733x over previous
//
#include <hip/hip_runtime.h>
#include <cstdint>
#include <cstddef>

// ---------------- model constants ----------------
#define BSZ   64
#define L_IN  168
#define S1    222
#define SKV   390
#define DM    512
#define HD    768
#define NHD   6
#define DK    128

typedef unsigned short u16;
typedef unsigned int u32;
typedef __attribute__((ext_vector_type(8))) short bf16x8;
typedef __attribute__((ext_vector_type(4))) float f32x4v;

// ---------------- bf16 helpers ----------------
__device__ inline float b2f(u16 u){
  union { u32 i; float f; } v; v.i = ((u32)u) << 16; return v.f;
}
__device__ inline u16 f2b(float f){
  union { float f; u32 i; } v; v.f = f;
  u32 x = v.i;
  return (u16)((x + 0x7fffu + ((x >> 16) & 1u)) >> 16);
}
__device__ inline u32 pk2(float a, float b){
  return ((u32)f2b(b) << 16) | (u32)f2b(a);
}
__device__ inline float ldv(const void* p, long long i, bool f32){
  return f32 ? ((const float*)p)[i] : b2f(((const u16*)p)[i]);
}
__device__ inline float4 ldv4(const void* p, long long i, bool f32){
  if (f32) return *(const float4*)((const float*)p + i);
  ushort4 w = *(const ushort4*)((const u16*)p + i);
  return make_float4(b2f(w.x), b2f(w.y), b2f(w.z), b2f(w.w));
}
__device__ inline bool is_f32(const u16* det){ return det[0] != 0x3F80; }

// ---------------- workspace layout (float-equivalent offsets) ----------------
constexpr size_t OFF_ENCX = 0;
constexpr size_t OFF_DECX = OFF_ENCX + (size_t)BSZ*S1*DM;
constexpr size_t OFF_QB   = OFF_DECX + (size_t)BSZ*L_IN*DM;
constexpr size_t OFF_KB   = OFF_QB   + (size_t)BSZ*S1*HD/2;
constexpr size_t OFF_VB   = OFF_KB   + (size_t)BSZ*SKV*HD/2;
constexpr size_t OFF_NBR  = OFF_VB   + (size_t)BSZ*SKV*HD/2;

// ---------------- PAM sparsity ----------------
__device__ inline int scale_of(int i, int& ii){
  if (i < 168){ ii = i;       return 0; }
  if (i < 210){ ii = i - 168; return 1; }
  if (i < 220){ ii = i - 210; return 2; }
  ii = i - 220; return 3;
}
__device__ inline bool pam_ok(int i, int j){
  int ii, jj;
  int li = scale_of(i, ii);
  int lj = scale_of(j, jj);
  const int n[4] = {168, 42, 10, 2};
  if (li == lj){ int d = ii - jj; return (d <= 1 && d >= -1); }
  if (li == lj + 1){ int lo = ii*4, hi = (ii == n[li]-1) ? n[lj] : ii*4+4; return (jj >= lo && jj < hi); }
  if (lj == li + 1){ int lo = jj*4, hi = (jj == n[lj]-1) ? n[li] : jj*4+4; return (ii >= lo && ii < hi); }
  return false;
}
__global__ void build_nbr_kernel(int* __restrict__ nbr){
  int q = blockIdx.x * 256 + threadIdx.x;
  if (q >= S1) return;
  int cnt = 0;
  int list[12];
  for (int j = 0; j < S1; ++j)
    if (pam_ok(q, j) && cnt < 12) list[cnt++] = j;
  #pragma unroll
  for (int t = 0; t < 12; ++t) nbr[q*12 + t] = (t < cnt) ? list[t] : -1;
}

// ---------------- embedding ----------------
__global__ void embed_kernel(const void* __restrict__ x, const void* __restrict__ t,
                             const void* __restrict__ cw, const void* __restrict__ tw,
                             const void* __restrict__ tb, const u16* __restrict__ det,
                             float* __restrict__ out)
{
  bool f32 = is_f32(det);
  int idx = blockIdx.x * 256 + threadIdx.x;
  if (idx >= BSZ*L_IN*DM) return;
  int d = idx & (DM-1);
  int l = (idx >> 9) % L_IN;
  int b = idx / (DM*L_IN);
  float acc = 0.f;
  #pragma unroll
  for (int tt = 0; tt < 3; ++tt){
    int ls = l + tt - 1;
    ls = (ls < 0) ? ls + L_IN : (ls >= L_IN ? ls - L_IN : ls);
    long long xo = ((long long)(b*L_IN + ls))*7;
    #pragma unroll
    for (int c = 0; c < 7; ++c)
      acc += ldv(x, xo + c, f32) * ldv(cw, d*21 + c*3 + tt, f32);
  }
  int d2 = d & ~1;
  float dv  = expf(-(float)d2 * (9.210340371976184f/512.f));
  float ang = (float)l * dv;
  acc += (d & 1) ? cosf(ang) : sinf(ang);
  long long to = ((long long)(b*L_IN + l))*4;
  #pragma unroll
  for (int f = 0; f < 4; ++f) acc += ldv(t, to + f, f32) * ldv(tw, f*DM + d, f32);
  acc += ldv(tb, d, f32);
  out[idx] = acc;
}

// ---------------- batched per-layer weight transpose ----------------
__device__ inline void trans32(const void* W, long long wOff, int K, int N, int k0, int n0,
                               u16* __restrict__ Wt, bool f32, float* tb, int tid)
{
  int c = tid & 31, r0 = tid >> 5;
  #pragma unroll
  for (int rr = 0; rr < 32; rr += 8)
    tb[(r0+rr)*33 + c] = ldv(W, wOff + (long long)(k0+r0+rr)*N + n0 + c, f32);
  __syncthreads();
  #pragma unroll
  for (int rr = 0; rr < 32; rr += 8)
    Wt[(size_t)(n0+r0+rr)*K + k0 + c] = f2b(tb[c*33 + r0+rr]);
}

// 6 weights per layer: wq,wk,wv [512,768] -> Wt3 rows 0/768/1536; wo [768,512] -> WtO;
// w1,w2 [512,512] -> Wt1, Wt2. grid = 2048 blocks x 256 thr
__global__ __launch_bounds__(256)
void wt_batch(const void* wq, const void* wk, const void* wv,
              const void* wo, const void* w1, const void* w2,
              long long wO, long long oO, long long fO,
              u16* __restrict__ Wt3, u16* __restrict__ WtO,
              u16* __restrict__ Wt1, u16* __restrict__ Wt2,
              const u16* __restrict__ det)
{
  __shared__ float tb[32*33];
  bool f32 = is_f32(det);
  int t = blockIdx.x, tid = threadIdx.x;
  if (t < 384)       trans32(wq, wO, 512, 768, (t/24)*32, (t%24)*32, Wt3,               f32, tb, tid);
  else if (t < 768)  { int u = t-384;  trans32(wk, wO, 512, 768, (u/24)*32, (u%24)*32, Wt3 + (size_t)768*512,  f32, tb, tid); }
  else if (t < 1152) { int u = t-768;  trans32(wv, wO, 512, 768, (u/24)*32, (u%24)*32, Wt3 + (size_t)1536*512, f32, tb, tid); }
  else if (t < 1536) { int u = t-1152; trans32(wo, oO, 768, 512, (u/16)*32, (u%16)*32, WtO, f32, tb, tid); }
  else if (t < 1792) { int u = t-1536; trans32(w1, fO, 512, 512, (u/16)*32, (u%16)*32, Wt1, f32, tb, tid); }
  else               { int u = t-1792; trans32(w2, fO, 512, 512, (u/16)*32, (u%16)*32, Wt2, f32, tb, tid); }
}

// ---------------- MFMA GEMM: C = A[M,K] @ W via Wt bf16 [N,K] ----------------
template<int EPI, int ABF, int CBF>
__global__ __launch_bounds__(256)
void gemm_mfma(const void* __restrict__ Av, const u16* __restrict__ Wt,
               const void* __restrict__ bias, long long bOff, const float* __restrict__ R,
               void* __restrict__ Cv, const u16* __restrict__ det,
               int K, int N, int La, int Lc, int off)
{
  __shared__ u16 As[128][64];
  __shared__ u16 Bs[128][64];
  bool f32 = is_f32(det);
  int tid = threadIdx.x;
  int row0 = blockIdx.y*128, col0 = blockIdx.x*128;
  int wave = tid >> 6, lane = tid & 63;
  int wm = (wave >> 1)*64, wn = (wave & 1)*64;
  int lm = lane & 15, quad = lane >> 4;
  int sr = tid >> 1;
  int sh = (tid & 1) * 32;
  int swzS = (sr & 7) * 8;
  f32x4v acc[4][4];
  #pragma unroll
  for (int i = 0; i < 4; ++i)
    #pragma unroll
    for (int j = 0; j < 4; ++j) acc[i][j] = (f32x4v){0.f,0.f,0.f,0.f};

  for (int k0 = 0; k0 < K; k0 += 64){
    if (ABF){
      const u16* src = (const u16*)Av + (size_t)(row0+sr)*K + k0 + sh;
      uint4 v0 = *(const uint4*)(src+0);
      uint4 v1 = *(const uint4*)(src+8);
      uint4 v2 = *(const uint4*)(src+16);
      uint4 v3 = *(const uint4*)(src+24);
      *(uint4*)&As[sr][(sh+0)^swzS]  = v0;
      *(uint4*)&As[sr][(sh+8)^swzS]  = v1;
      *(uint4*)&As[sr][(sh+16)^swzS] = v2;
      *(uint4*)&As[sr][(sh+24)^swzS] = v3;
    } else {
      const float* src = (const float*)Av + (size_t)(row0+sr)*K + k0 + sh;
      #pragma unroll
      for (int j = 0; j < 4; ++j){
        float4 f0 = *(const float4*)(src + 8*j);
        float4 f1 = *(const float4*)(src + 8*j + 4);
        uint4 o;
        o.x = pk2(f0.x, f0.y); o.y = pk2(f0.z, f0.w);
        o.z = pk2(f1.x, f1.y); o.w = pk2(f1.z, f1.w);
        *(uint4*)&As[sr][(sh + 8*j)^swzS] = o;
      }
    }
    {
      const u16* src = Wt + (size_t)(col0+sr)*K + k0 + sh;
      uint4 v0 = *(const uint4*)(src+0);
      uint4 v1 = *(const uint4*)(src+8);
      uint4 v2 = *(const uint4*)(src+16);
      uint4 v3 = *(const uint4*)(src+24);
      *(uint4*)&Bs[sr][(sh+0)^swzS]  = v0;
      *(uint4*)&Bs[sr][(sh+8)^swzS]  = v1;
      *(uint4*)&Bs[sr][(sh+16)^swzS] = v2;
      *(uint4*)&Bs[sr][(sh+24)^swzS] = v3;
    }
    __syncthreads();
    bf16x8 af[4][2], bfr[4][2];
    #pragma unroll
    for (int mi = 0; mi < 4; ++mi){
      int m = wm + mi*16 + lm;
      int sz = (m & 7)*8;
      af[mi][0] = *(const bf16x8*)&As[m][(quad*8) ^ sz];
      af[mi][1] = *(const bf16x8*)&As[m][(32 + quad*8) ^ sz];
    }
    #pragma unroll
    for (int ni = 0; ni < 4; ++ni){
      int n = wn + ni*16 + lm;
      int sz = (n & 7)*8;
      bfr[ni][0] = *(const bf16x8*)&Bs[n][(quad*8) ^ sz];
      bfr[ni][1] = *(const bf16x8*)&Bs[n][(32 + quad*8) ^ sz];
    }
    #pragma unroll
    for (int mi = 0; mi < 4; ++mi)
      #pragma unroll
      for (int ni = 0; ni < 4; ++ni){
        acc[mi][ni] = __builtin_amdgcn_mfma_f32_16x16x32_bf16(af[mi][0], bfr[ni][0], acc[mi][ni], 0, 0, 0);
        acc[mi][ni] = __builtin_amdgcn_mfma_f32_16x16x32_bf16(af[mi][1], bfr[ni][1], acc[mi][ni], 0, 0, 0);
      }
    __syncthreads();
  }
  #pragma unroll
  for (int mi = 0; mi < 4; ++mi){
    #pragma unroll
    for (int r = 0; r < 4; ++r){
      int row = row0 + wm + mi*16 + quad*4 + r;
      int bb = row / La, l = row - bb*La;
      size_t crow = ((size_t)bb*Lc + off + l)*(size_t)N;
      #pragma unroll
      for (int ni = 0; ni < 4; ++ni){
        int col = col0 + wn + ni*16 + lm;
        float vv = acc[mi][ni][r] + ldv(bias, bOff + col, f32);
        if (EPI == 1) vv = 0.5f*vv*(1.f + erff(vv*0.70710678118654752f));
        if (EPI == 2) vv += R[crow + col];
        if (CBF) ((u16*)Cv)[crow + col] = f2b(vv);
        else     ((float*)Cv)[crow + col] = vv;
      }
    }
  }
}

// ---------------- fused QKV / KV MFMA GEMM (A f32, out bf16, K=512) ----------------
// Wt rows are concat of per-output [768][512] blocks. sel = col/768 picks (out,bias).
__global__ __launch_bounds__(256)
void gemm_qkv(const float* __restrict__ A, const u16* __restrict__ Wt,
              const void* __restrict__ b0, const void* __restrict__ b1, const void* __restrict__ b2,
              long long bOff, u16* __restrict__ o0, u16* __restrict__ o1, u16* __restrict__ o2,
              const u16* __restrict__ det, int La, int Lc, int off)
{
  __shared__ u16 As[128][64];
  __shared__ u16 Bs[128][64];
  bool f32 = is_f32(det);
  const int K = 512;
  int tid = threadIdx.x;
  int row0 = blockIdx.y*128, col0 = blockIdx.x*128;
  int wave = tid >> 6, lane = tid & 63;
  int wm = (wave >> 1)*64, wn = (wave & 1)*64;
  int lm = lane & 15, quad = lane >> 4;
  int sr = tid >> 1;
  int sh = (tid & 1) * 32;
  int swzS = (sr & 7) * 8;
  f32x4v acc[4][4];
  #pragma unroll
  for (int i = 0; i < 4; ++i)
    #pragma unroll
    for (int j = 0; j < 4; ++j) acc[i][j] = (f32x4v){0.f,0.f,0.f,0.f};

  for (int k0 = 0; k0 < K; k0 += 64){
    {
      const float* src = A + (size_t)(row0+sr)*K + k0 + sh;
      #pragma unroll
      for (int j = 0; j < 4; ++j){
        float4 f0 = *(const float4*)(src + 8*j);
        float4 f1 = *(const float4*)(src + 8*j + 4);
        uint4 o;
        o.x = pk2(f0.x, f0.y); o.y = pk2(f0.z, f0.w);
        o.z = pk2(f1.x, f1.y); o.w = pk2(f1.z, f1.w);
        *(uint4*)&As[sr][(sh + 8*j)^swzS] = o;
      }
    }
    {
      const u16* src = Wt + (size_t)(col0+sr)*K + k0 + sh;
      uint4 v0 = *(const uint4*)(src+0);
      uint4 v1 = *(const uint4*)(src+8);
      uint4 v2 = *(const uint4*)(src+16);
      uint4 v3 = *(const uint4*)(src+24);
      *(uint4*)&Bs[sr][(sh+0)^swzS]  = v0;
      *(uint4*)&Bs[sr][(sh+8)^swzS]  = v1;
      *(uint4*)&Bs[sr][(sh+16)^swzS] = v2;
      *(uint4*)&Bs[sr][(sh+24)^swzS] = v3;
    }
    __syncthreads();
    bf16x8 af[4][2], bfr[4][2];
    #pragma unroll
    for (int mi = 0; mi < 4; ++mi){
      int m = wm + mi*16 + lm;
      int sz = (m & 7)*8;
      af[mi][0] = *(const bf16x8*)&As[m][(quad*8) ^ sz];
      af[mi][1] = *(const bf16x8*)&As[m][(32 + quad*8) ^ sz];
    }
    #pragma unroll
    for (int ni = 0; ni < 4; ++ni){
      int n = wn + ni*16 + lm;
      int sz = (n & 7)*8;
      bfr[ni][0] = *(const bf16x8*)&Bs[n][(quad*8) ^ sz];
      bfr[ni][1] = *(const bf16x8*)&Bs[n][(32 + quad*8) ^ sz];
    }
    #pragma unroll
    for (int mi = 0; mi < 4; ++mi)
      #pragma unroll
      for (int ni = 0; ni < 4; ++ni){
        acc[mi][ni] = __builtin_amdgcn_mfma_f32_16x16x32_bf16(af[mi][0], bfr[ni][0], acc[mi][ni], 0, 0, 0);
        acc[mi][ni] = __builtin_amdgcn_mfma_f32_16x16x32_bf16(af[mi][1], bfr[ni][1], acc[mi][ni], 0, 0, 0);
      }
    __syncthreads();
  }
  #pragma unroll
  for (int mi = 0; mi < 4; ++mi){
    #pragma unroll
    for (int r = 0; r < 4; ++r){
      int row = row0 + wm + mi*16 + quad*4 + r;
      int bb = row / La, l = row - bb*La;
      size_t crow = ((size_t)bb*Lc + off + l)*(size_t)HD;
      #pragma unroll
      for (int ni = 0; ni < 4; ++ni){
        int col = col0 + wn + ni*16 + lm;
        int sel = (col >= 1536) ? 2 : (col >= 768 ? 1 : 0);
        int colr = col - sel*768;
        const void* bp = (sel == 0) ? b0 : (sel == 1) ? b1 : b2;
        u16* dst = (sel == 0) ? o0 : (sel == 1) ? o1 : o2;
        float vv = acc[mi][ni][r] + ldv(bp, bOff + colr, f32);
        dst[crow + colr] = f2b(vv);
      }
    }
  }
}

// ---------------- SIMT GEMM (bottleneck only) ----------------
#define BM 64
#define BN 64
#define BK 16
__global__ __launch_bounds__(256)
void gemm_k(const float* __restrict__ A, const void* __restrict__ W, long long wOff,
            const void* __restrict__ bias, long long bOff,
            float* __restrict__ C, const u16* __restrict__ det, int K, int N)
{
  __shared__ float As2[BK][BM+4];
  __shared__ float Bs2[BK][BN+4];
  bool f32 = is_f32(det);
  int tid = threadIdx.x;
  int row0 = blockIdx.y * BM, col0 = blockIdx.x * BN;
  int ty = tid >> 4, tx = tid & 15;
  int lr = tid >> 2, lc4 = (tid & 3) << 2;
  int wr = tid >> 4, wc4 = (tid & 15) << 2;
  float acc[4][4] = {};
  for (int k0 = 0; k0 < K; k0 += BK){
    float4 av = *(const float4*)(A + (size_t)(row0 + lr)*K + k0 + lc4);
    As2[lc4+0][lr] = av.x; As2[lc4+1][lr] = av.y;
    As2[lc4+2][lr] = av.z; As2[lc4+3][lr] = av.w;
    float4 wv = ldv4(W, wOff + (long long)(k0 + wr)*N + col0 + wc4, f32);
    *(float4*)&Bs2[wr][wc4] = wv;
    __syncthreads();
    #pragma unroll
    for (int kk = 0; kk < BK; ++kk){
      float4 a  = *(const float4*)&As2[kk][ty << 2];
      float4 bb = *(const float4*)&Bs2[kk][tx << 2];
      acc[0][0] += a.x*bb.x; acc[0][1] += a.x*bb.y; acc[0][2] += a.x*bb.z; acc[0][3] += a.x*bb.w;
      acc[1][0] += a.y*bb.x; acc[1][1] += a.y*bb.y; acc[1][2] += a.y*bb.z; acc[1][3] += a.y*bb.w;
      acc[2][0] += a.z*bb.x; acc[2][1] += a.z*bb.y; acc[2][2] += a.z*bb.z; acc[2][3] += a.z*bb.w;
      acc[3][0] += a.w*bb.x; acc[3][1] += a.w*bb.y; acc[3][2] += a.w*bb.z; acc[3][3] += a.w*bb.w;
    }
    __syncthreads();
  }
  #pragma unroll
  for (int i = 0; i < 4; ++i){
    int r = row0 + (ty << 2) + i;
    size_t crow = (size_t)r*(size_t)N;
    #pragma unroll
    for (int j = 0; j < 4; ++j){
      int c = col0 + (tx << 2) + j;
      C[crow + c] = acc[i][j] + ldv(bias, bOff + c, f32);
    }
  }
}

// ---------------- bottleneck conv + BN + ELU ----------------
__global__ void conv_bn_elu_kernel(const float* __restrict__ in, int inStride, int inOff,
                                   float* __restrict__ out, int outStride, int outOff, int Lout,
                                   const void* __restrict__ w, const void* __restrict__ cb,
                                   const void* __restrict__ bg, const void* __restrict__ bb,
                                   const void* __restrict__ bm, const void* __restrict__ bv,
                                   const u16* __restrict__ det, int lay)
{
  bool f32 = is_f32(det);
  int idx = blockIdx.x * 256 + threadIdx.x;
  int total = BSZ * Lout * 128;
  if (idx >= total) return;
  int co = idx & 127;
  int j  = (idx >> 7) % Lout;
  int b  = idx / (128 * Lout);
  const float* ir = in + ((size_t)(b*inStride + inOff + j*4))*128;
  long long wo = (long long)lay*65536 + (long long)co*512;
  float acc = 0.f;
  for (int ci = 0; ci < 128; ++ci){
    #pragma unroll
    for (int tt = 0; tt < 4; ++tt)
      acc += ir[tt*128 + ci] * ldv(w, wo + ci*4 + tt, f32);
  }
  long long po = (long long)lay*128 + co;
  acc += ldv(cb, po, f32);
  acc = (acc - ldv(bm, po, f32)) * rsqrtf(ldv(bv, po, f32) + 1e-5f) * ldv(bg, po, f32) + ldv(bb, po, f32);
  acc = acc > 0.f ? acc : (__expf(acc) - 1.f);
  out[((size_t)(b*outStride + outOff + j))*128 + co] = acc;
}

// ---------------- LayerNorm ----------------
__global__ __launch_bounds__(64)
void ln_kernel(const float* __restrict__ X, const void* __restrict__ g, long long gOff,
               const void* __restrict__ bt, long long bOff, float eps,
               float* __restrict__ Out, const u16* __restrict__ det)
{
  bool f32 = is_f32(det);
  int row = blockIdx.x, lane = threadIdx.x;
  const float* xr = X + (size_t)row*DM;
  float v[8]; float s = 0.f;
  #pragma unroll
  for (int i = 0; i < 8; ++i){ v[i] = xr[lane + i*64]; s += v[i]; }
  #pragma unroll
  for (int o = 32; o > 0; o >>= 1) s += __shfl_xor(s, o);
  float mean = s * (1.f/512.f);
  float q = 0.f;
  #pragma unroll
  for (int i = 0; i < 8; ++i){ float d = v[i]-mean; q += d*d; }
  #pragma unroll
  for (int o = 32; o > 0; o >>= 1) q += __shfl_xor(q, o);
  float inv = rsqrtf(q*(1.f/512.f) + eps);
  float* orow = Out + (size_t)row*DM;
  #pragma unroll
  for (int i = 0; i < 8; ++i){
    int c = lane + i*64;
    orow[c] = (v[i]-mean)*inv*ldv(g, gOff + c, f32) + ldv(bt, bOff + c, f32);
  }
}

// ---------------- concat + LayerNorm(1e-5) ----------------
__global__ __launch_bounds__(64)
void concat_ln_kernel(const float* __restrict__ emb, const float* __restrict__ up,
                      const void* __restrict__ g, const void* __restrict__ bt,
                      float* __restrict__ Out, const u16* __restrict__ det)
{
  bool f32 = is_f32(det);
  int row = blockIdx.x, lane = threadIdx.x;
  int b = row / S1, l = row - b*S1;
  const float* xr = (l < L_IN) ? emb + ((size_t)(b*L_IN + l))*DM
                               : up  + ((size_t)(b*54 + (l - L_IN)))*DM;
  float v[8]; float s = 0.f;
  #pragma unroll
  for (int i = 0; i < 8; ++i){ v[i] = xr[lane + i*64]; s += v[i]; }
  #pragma unroll
  for (int o = 32; o > 0; o >>= 1) s += __shfl_xor(s, o);
  float mean = s * (1.f/512.f);
  float q = 0.f;
  #pragma unroll
  for (int i = 0; i < 8; ++i){ float d = v[i]-mean; q += d*d; }
  #pragma unroll
  for (int o = 32; o > 0; o >>= 1) q += __shfl_xor(q, o);
  float inv = rsqrtf(q*(1.f/512.f) + 1e-5f);
  float* orow = Out + (size_t)row*DM;
  #pragma unroll
  for (int i = 0; i < 8; ++i){
    int c = lane + i*64;
    orow[c] = (v[i]-mean)*inv*ldv(g, c, f32) + ldv(bt, c, f32);
  }
}

// ---------------- encoder attention: PAM-sparse, one wave per (b,q,h) ----------------
__global__ __launch_bounds__(384)
void attn_enc_sparse(u16* __restrict__ q, const u16* __restrict__ k,
                     const u16* __restrict__ v, const int* __restrict__ nbr)
{
  __shared__ int nb[12];
  int blk = blockIdx.x;
  int b = blk / S1, qr = blk - b*S1;
  if (threadIdx.x < 12) nb[threadIdx.x] = nbr[qr*12 + threadIdx.x];
  __syncthreads();
  int h = threadIdx.x >> 6;
  int lane = threadIdx.x & 63;
  const float scale = 0.088388347648318447f;
  size_t rowoff = ((size_t)b*S1 + qr)*HD + h*DK;
  u32 qw = ((const u32*)(q + rowoff))[lane];
  float q0 = b2f((u16)(qw & 0xffff)), q1 = b2f((u16)(qw >> 16));
  float pj[12];
  #pragma unroll
  for (int j = 0; j < 12; ++j){
    int kg = nb[j];
    float p = 0.f;
    if (kg >= 0){
      u32 kw = ((const u32*)(k + ((size_t)b*S1 + kg)*HD + h*DK))[lane];
      p = q0*b2f((u16)(kw & 0xffff)) + q1*b2f((u16)(kw >> 16));
    }
    #pragma unroll
    for (int o = 32; o > 0; o >>= 1) p += __shfl_xor(p, o);
    pj[j] = (kg >= 0) ? p*scale : -1e30f;
  }
  float m = -1e30f;
  #pragma unroll
  for (int j = 0; j < 12; ++j) m = fmaxf(m, pj[j]);
  float s = 0.f;
  #pragma unroll
  for (int j = 0; j < 12; ++j){
    pj[j] = (nb[j] >= 0) ? __expf(pj[j]-m) : 0.f;
    s += pj[j];
  }
  float inv = 1.f / s;
  float o0 = 0.f, o1 = 0.f;
  #pragma unroll
  for (int j = 0; j < 12; ++j){
    int kg = nb[j];
    if (kg >= 0){
      u32 vw = ((const u32*)(v + ((size_t)b*S1 + kg)*HD + h*DK))[lane];
      o0 += pj[j]*b2f((u16)(vw & 0xffff));
      o1 += pj[j]*b2f((u16)(vw >> 16));
    }
  }
  u32 ow = ((u32)f2b(o1*inv) << 16) | (u32)f2b(o0*inv);
  ((u32*)(q + rowoff))[lane] = ow;
}

// ---------------- decoder attention: MFMA flash, one block per (b,h,64-q-tile) ----------------
#define FQT 64
__global__ __launch_bounds__(256)
void attn_dec_mfma(u16* __restrict__ q, const u16* __restrict__ k,
                   const u16* __restrict__ v)
{
  __shared__ u16 Qs[FQT][136];    // pad 136: 2-way-free banks for b128 frag reads
  __shared__ u16 Ks[32][136];
  __shared__ u32 Vt[128][20];     // transposed V, u32 = key-pair, pitch 20 (16B-aligned rows)
  __shared__ u16 Pls[4][16][32];  // per-wave P tile (C-layout -> A-layout round trip)
  int b = blockIdx.z, h = blockIdx.y;
  int qt0 = blockIdx.x * FQT;
  int tid = threadIdx.x;
  int wave = tid >> 6, lane = tid & 63;
  int lm = lane & 15, quad = lane >> 4;
  const float scale = 0.088388347648318447f;
  const size_t qb0 = (size_t)b*L_IN*HD + (size_t)h*DK;
  const size_t kb0 = (size_t)b*SKV*HD + (size_t)h*DK;

  // stage Q tile
  for (int i = tid*4; i < FQT*128; i += 1024){
    int row = i >> 7, d = i & 127;
    int qg = qt0 + row;
    ushort4 w = make_ushort4(0,0,0,0);
    if (qg < L_IN) w = *(const ushort4*)(q + qb0 + (size_t)qg*HD + d);
    *(ushort4*)&Qs[row][d] = w;
  }
  __syncthreads();
  // preload Q A-frags (wave owns q rows wave*16..+15)
  bf16x8 qf[4];
  #pragma unroll
  for (int ks = 0; ks < 4; ++ks)
    qf[ks] = *(const bf16x8*)&Qs[wave*16 + lm][ks*32 + quad*8];

  float mold[4], lsum[4];
  #pragma unroll
  for (int r = 0; r < 4; ++r){ mold[r] = -1e30f; lsum[r] = 0.f; }
  f32x4v oacc[8];
  #pragma unroll
  for (int f = 0; f < 8; ++f) oacc[f] = (f32x4v){0.f,0.f,0.f,0.f};

  int kEnd = S1 + qt0 + FQT; if (kEnd > SKV) kEnd = SKV;
  for (int kt0 = 0; kt0 < kEnd; kt0 += 32){
    __syncthreads();   // protect Ks/Vt reuse
    // stage K tile [32][128]
    for (int i = tid*4; i < 32*128; i += 1024){
      int kk = i >> 7, d = i & 127;
      int kg = kt0 + kk;
      ushort4 w = make_ushort4(0,0,0,0);
      if (kg < SKV) w = *(const ushort4*)(k + kb0 + (size_t)kg*HD + d);
      *(ushort4*)&Ks[kk][d] = w;
    }
    // stage V transposed: Vt[d][pair] = V[2p][d] | V[2p+1][d]<<16
    for (int t2 = tid; t2 < 512; t2 += 256){
      int g = t2 & 31, p = t2 >> 5;
      int kg0 = kt0 + 2*p, d0 = g*4;
      ushort4 a = make_ushort4(0,0,0,0), c = make_ushort4(0,0,0,0);
      if (kg0     < SKV) a = *(const ushort4*)(v + kb0 + (size_t)kg0*HD + d0);
      if (kg0 + 1 < SKV) c = *(const ushort4*)(v + kb0 + (size_t)(kg0+1)*HD + d0);
      Vt[d0+0][p] = (u32)a.x | ((u32)c.x << 16);
      Vt[d0+1][p] = (u32)a.y | ((u32)c.y << 16);
      Vt[d0+2][p] = (u32)a.z | ((u32)c.z << 16);
      Vt[d0+3][p] = (u32)a.w | ((u32)c.w << 16);
    }
    __syncthreads();
    // scores: 2 key-subtiles x 4 d-steps
    f32x4v sacc[2];
    sacc[0] = (f32x4v){0.f,0.f,0.f,0.f};
    sacc[1] = (f32x4v){0.f,0.f,0.f,0.f};
    #pragma unroll
    for (int t = 0; t < 2; ++t)
      #pragma unroll
      for (int ks = 0; ks < 4; ++ks){
        bf16x8 kf = *(const bf16x8*)&Ks[t*16 + lm][ks*32 + quad*8];
        sacc[t] = __builtin_amdgcn_mfma_f32_16x16x32_bf16(qf[ks], kf, sacc[t], 0, 0, 0);
      }
    // mask + scale; online softmax update (rows quad*4+r, cols t*16+lm)
    float p[2][4];
    #pragma unroll
    for (int r = 0; r < 4; ++r){
      int qg = qt0 + wave*16 + quad*4 + r;
      float s0, s1;
      {
        int kg = kt0 + lm;
        bool ok = (kg < SKV) && (qg < L_IN) && (kg <= S1 + qg);
        s0 = ok ? sacc[0][r]*scale : -1e30f;
      }
      {
        int kg = kt0 + 16 + lm;
        bool ok = (kg < SKV) && (qg < L_IN) && (kg <= S1 + qg);
        s1 = ok ? sacc[1][r]*scale : -1e30f;
      }
      float mn = fmaxf(s0, s1);
      #pragma unroll
      for (int o = 8; o > 0; o >>= 1) mn = fmaxf(mn, __shfl_xor(mn, o));
      float mi = fmaxf(mold[r], mn);
      float alpha = __expf(mold[r] - mi);
      mold[r] = mi;
      p[0][r] = __expf(s0 - mi);
      p[1][r] = __expf(s1 - mi);
      float rs = p[0][r] + p[1][r];
      #pragma unroll
      for (int o = 8; o > 0; o >>= 1) rs += __shfl_xor(rs, o);
      lsum[r] = lsum[r]*alpha + rs;
      #pragma unroll
      for (int f = 0; f < 8; ++f) oacc[f][r] *= alpha;
    }
    // write P (bf16) to per-wave LDS tile, read back in A-layout (wave-internal, in-order DS pipe)
    #pragma unroll
    for (int r = 0; r < 4; ++r){
      Pls[wave][quad*4+r][lm]      = f2b(p[0][r]);
      Pls[wave][quad*4+r][16 + lm] = f2b(p[1][r]);
    }
    bf16x8 pa = *(const bf16x8*)&Pls[wave][lm][quad*8];
    // PV: 8 d-frags from Vt
    #pragma unroll
    for (int f = 0; f < 8; ++f){
      bf16x8 vf = *(const bf16x8*)&Vt[f*16 + lm][quad*4];
      oacc[f] = __builtin_amdgcn_mfma_f32_16x16x32_bf16(pa, vf, oacc[f], 0, 0, 0);
    }
  }
  // epilogue
  #pragma unroll
  for (int r = 0; r < 4; ++r){
    int qg = qt0 + wave*16 + quad*4 + r;
    if (qg < L_IN){
      float inv = 1.f / lsum[r];
      #pragma unroll
      for (int f = 0; f < 8; ++f)
        q[qb0 + (size_t)qg*HD + f*16 + lm] = f2b(oacc[f][r]*inv);
    }
  }
}

// ---------------- prediction head ----------------
__global__ void pred_kernel(const float* __restrict__ X, const void* __restrict__ w,
                            void* __restrict__ out, const u16* __restrict__ det)
{
  bool f32 = is_f32(det);
  int idx = blockIdx.x * 256 + threadIdx.x;
  if (idx >= BSZ*L_IN*7) return;
  int c  = idx % 7;
  int rl = idx / 7;
  const float* xr = X + (size_t)rl*DM;
  float acc = 0.f;
  for (int kk = 0; kk < DM; ++kk) acc += xr[kk] * ldv(w, kk*7 + c, f32);
  if (f32) ((float*)out)[idx] = acc;
  else     ((u16*)out)[idx] = f2b(acc);
}

// ---------------- launch ----------------
extern "C" void kernel_launch(void* const* d_in, const int* in_sizes, int n_in,
                              void* d_out, int out_size, void* d_ws, size_t ws_size,
                              hipStream_t stream)
{
  (void)in_sizes; (void)n_in; (void)out_size; (void)ws_size;
  #define IN(i) ((const void*)d_in[i])
  const u16* det = (const u16*)d_in[20];
  float* ws   = (float*)d_ws;
  float* encx = ws + OFF_ENCX;
  float* decx = ws + OFF_DECX;
  u16*   qb   = (u16*)(ws + OFF_QB);
  u16*   kb   = (u16*)(ws + OFF_KB);
  u16*   vb   = (u16*)(ws + OFF_VB);
  int*   nbr  = (int*)(ws + OFF_NBR);
  // phase-disjoint aliases
  float* tmp1  = ws + OFF_VB;                               // f32 pre-LN sums (V dead)
  u16*   WtE3  = (u16*)(ws + OFF_VB + (size_t)BSZ*S1*DM);   // enc Wt concat [2304][512]
  u16*   WtEO  = WtE3 + (size_t)2304*512;
  u16*   WtE1  = WtEO + (size_t)768*512;
  u16*   WtE2  = WtE1 + (size_t)512*512;
  u16*   WtD3  = (u16*)(ws + OFF_QB + (size_t)BSZ*L_IN*HD/2);
  u16*   WtDO  = WtD3 + (size_t)2304*512;
  u16*   WtD1  = WtDO + (size_t)768*512;
  u16*   WtD2  = WtD1 + (size_t)512*512;
  u16*   tmph  = (u16*)(ws + OFF_KB);                       // bf16 ffn hidden (K dead)
  float* embE  = ws + OFF_VB;                               // f32 enc embed (pre-encoder)
  float* bdown = ws + OFF_KB;
  float* bconv = bdown + (size_t)BSZ*L_IN*128;
  float* bup   = bconv + (size_t)BSZ*54*128;

  build_nbr_kernel<<<1, 256, 0, stream>>>(nbr);

  embed_kernel<<<(BSZ*L_IN*DM)/256, 256, 0, stream>>>(IN(0), IN(1), IN(4), IN(5), IN(6), det, embE);
  embed_kernel<<<(BSZ*L_IN*DM)/256, 256, 0, stream>>>(IN(2), IN(3), IN(7), IN(8), IN(9), det, decx);

  // bottleneck
  gemm_k<<<dim3(128/BN, (BSZ*L_IN)/BM), 256, 0, stream>>>(
      embE, IN(10), 0, IN(11), 0, bdown, det, 512, 128);
  conv_bn_elu_kernel<<<(BSZ*42*128)/256, 256, 0, stream>>>(
      bdown, L_IN, 0, bconv, 54, 0, 42, IN(12), IN(13), IN(14), IN(15), IN(16), IN(17), det, 0);
  conv_bn_elu_kernel<<<(BSZ*10*128)/256, 256, 0, stream>>>(
      bconv, 54, 0, bconv, 54, 42, 10, IN(12), IN(13), IN(14), IN(15), IN(16), IN(17), det, 1);
  conv_bn_elu_kernel<<<(BSZ*2*128)/256, 256, 0, stream>>>(
      bconv, 54, 42, bconv, 54, 52, 2, IN(12), IN(13), IN(14), IN(15), IN(16), IN(17), det, 2);
  gemm_k<<<dim3(512/BN, (BSZ*54)/BM), 256, 0, stream>>>(
      bconv, IN(18), 0, IN(19), 0, bup, det, 128, 512);
  concat_ln_kernel<<<BSZ*S1, 64, 0, stream>>>(embE, bup, IN(20), IN(21), encx, det);

  // encoder layers
  for (int i = 0; i < 6; ++i){
    long long wO = (long long)i*512*768, oO = (long long)i*768*512;
    long long bO = (long long)i*768, dO = (long long)i*512;
    long long fO = (long long)i*512*512;
    wt_batch<<<2048, 256, 0, stream>>>(IN(22), IN(24), IN(26), IN(28), IN(32), IN(34),
                                       wO, oO, fO, WtE3, WtEO, WtE1, WtE2, det);
    gemm_qkv<<<dim3(18, 111), 256, 0, stream>>>(
        encx, WtE3, IN(23), IN(25), IN(27), bO, qb, kb, vb, det, S1, S1, 0);
    attn_enc_sparse<<<dim3(BSZ*S1), 384, 0, stream>>>(qb, kb, vb, nbr);
    gemm_mfma<2,1,0><<<dim3(4, 111), 256, 0, stream>>>(
        qb, WtEO, IN(29), dO, encx, tmp1, det, 768, 512, S1, S1, 0);
    ln_kernel<<<BSZ*S1, 64, 0, stream>>>(tmp1, IN(30), dO, IN(31), dO, 1e-6f, encx, det);
    gemm_mfma<1,0,1><<<dim3(4, 111), 256, 0, stream>>>(
        encx, WtE1, IN(33), dO, nullptr, tmph, det, 512, 512, S1, S1, 0);
    gemm_mfma<2,1,0><<<dim3(4, 111), 256, 0, stream>>>(
        tmph, WtE2, IN(35), dO, encx, tmp1, det, 512, 512, S1, S1, 0);
    ln_kernel<<<BSZ*S1, 64, 0, stream>>>(tmp1, IN(36), dO, IN(37), dO, 1e-6f, encx, det);
  }

  // decoder layers
  for (int i = 0; i < 2; ++i){
    long long wO = (long long)i*512*768, oO = (long long)i*768*512;
    long long bO = (long long)i*768, dO = (long long)i*512;
    long long fO = (long long)i*512*512;
    wt_batch<<<2048, 256, 0, stream>>>(IN(38), IN(40), IN(42), IN(44), IN(48), IN(50),
                                       wO, oO, fO, WtD3, WtDO, WtD1, WtD2, det);
    gemm_mfma<0,0,1><<<dim3(6, 84), 256, 0, stream>>>(
        decx, WtD3, IN(39), bO, nullptr, qb, det, 512, 768, L_IN, L_IN, 0);
    gemm_qkv<<<dim3(12, 111), 256, 0, stream>>>(
        encx, WtD3 + (size_t)768*512, IN(41), IN(43), IN(43), bO, kb, vb, vb, det, S1, SKV, 0);
    gemm_qkv<<<dim3(12, 84), 256, 0, stream>>>(
        decx, WtD3 + (size_t)768*512, IN(41), IN(43), IN(43), bO, kb, vb, vb, det, L_IN, SKV, S1);
    attn_dec_mfma<<<dim3(3, NHD, BSZ), 256, 0, stream>>>(qb, kb, vb);
    gemm_mfma<2,1,0><<<dim3(4, 84), 256, 0, stream>>>(
        qb, WtDO, IN(45), dO, decx, tmp1, det, 768, 512, L_IN, L_IN, 0);
    ln_kernel<<<BSZ*L_IN, 64, 0, stream>>>(tmp1, IN(46), dO, IN(47), dO, 1e-6f, decx, det);
    gemm_mfma<1,0,1><<<dim3(4, 84), 256, 0, stream>>>(
        decx, WtD1, IN(49), dO, nullptr, tmph, det, 512, 512, L_IN, L_IN, 0);
    gemm_mfma<2,1,0><<<dim3(4, 84), 256, 0, stream>>>(
        tmph, WtD2, IN(51), dO, decx, tmp1, det, 512, 512, L_IN, L_IN, 0);
    ln_kernel<<<BSZ*L_IN, 64, 0, stream>>>(tmp1, IN(52), dO, IN(53), dO, 1e-6f, decx, det);
  }

  pred_kernel<<<(BSZ*L_IN*7 + 255)/256, 256, 0, stream>>>(decx, IN(54), d_out, det);
  #undef IN
}

// Round 7
// 3701.810 us; speedup vs baseline: 3.9779x; 1.2302x over previous
//
#include <hip/hip_runtime.h>
#include <cstdint>
#include <cstddef>

// ---------------- model constants ----------------
#define BSZ   64
#define L_IN  168
#define S1    222
#define SKV   390
#define DM    512
#define HD    768
#define NHD   6
#define DK    128

typedef unsigned short u16;
typedef unsigned int u32;
typedef __attribute__((ext_vector_type(8))) short bf16x8;
typedef __attribute__((ext_vector_type(4))) float f32x4v;

// ---------------- bf16 helpers ----------------
__device__ inline float b2f(u16 u){
  union { u32 i; float f; } v; v.i = ((u32)u) << 16; return v.f;
}
__device__ inline u16 f2b(float f){
  union { float f; u32 i; } v; v.f = f;
  u32 x = v.i;
  return (u16)((x + 0x7fffu + ((x >> 16) & 1u)) >> 16);
}
__device__ inline u32 pk2(float a, float b){
  return ((u32)f2b(b) << 16) | (u32)f2b(a);
}
__device__ inline float ldv(const void* p, long long i, bool f32){
  return f32 ? ((const float*)p)[i] : b2f(((const u16*)p)[i]);
}
__device__ inline float4 ldv4(const void* p, long long i, bool f32){
  if (f32) return *(const float4*)((const float*)p + i);
  ushort4 w = *(const ushort4*)((const u16*)p + i);
  return make_float4(b2f(w.x), b2f(w.y), b2f(w.z), b2f(w.w));
}
__device__ inline bool is_f32(const u16* det){ return det[0] != 0x3F80; }
// unpack 8 bf16 (uint4) -> 8 floats
__device__ inline void unpack8(uint4 w, float* f){
  union { u32 i; float fl; } a;
  a.i = w.x << 16;          f[0] = a.fl;
  a.i = w.x & 0xffff0000u;  f[1] = a.fl;
  a.i = w.y << 16;          f[2] = a.fl;
  a.i = w.y & 0xffff0000u;  f[3] = a.fl;
  a.i = w.z << 16;          f[4] = a.fl;
  a.i = w.z & 0xffff0000u;  f[5] = a.fl;
  a.i = w.w << 16;          f[6] = a.fl;
  a.i = w.w & 0xffff0000u;  f[7] = a.fl;
}

// ---------------- workspace layout (float-equivalent offsets) ----------------
constexpr size_t OFF_ENCX = 0;
constexpr size_t OFF_DECX = OFF_ENCX + (size_t)BSZ*S1*DM;
constexpr size_t OFF_QB   = OFF_DECX + (size_t)BSZ*L_IN*DM;
constexpr size_t OFF_KB   = OFF_QB   + (size_t)BSZ*S1*HD/2;
constexpr size_t OFF_VB   = OFF_KB   + (size_t)BSZ*SKV*HD/2;
constexpr size_t OFF_NBR  = OFF_VB   + (size_t)BSZ*SKV*HD/2;

// ---------------- PAM sparsity ----------------
__device__ inline int scale_of(int i, int& ii){
  if (i < 168){ ii = i;       return 0; }
  if (i < 210){ ii = i - 168; return 1; }
  if (i < 220){ ii = i - 210; return 2; }
  ii = i - 220; return 3;
}
__device__ inline bool pam_ok(int i, int j){
  int ii, jj;
  int li = scale_of(i, ii);
  int lj = scale_of(j, jj);
  const int n[4] = {168, 42, 10, 2};
  if (li == lj){ int d = ii - jj; return (d <= 1 && d >= -1); }
  if (li == lj + 1){ int lo = ii*4, hi = (ii == n[li]-1) ? n[lj] : ii*4+4; return (jj >= lo && jj < hi); }
  if (lj == li + 1){ int lo = jj*4, hi = (jj == n[lj]-1) ? n[li] : jj*4+4; return (ii >= lo && ii < hi); }
  return false;
}
__global__ void build_nbr_kernel(int* __restrict__ nbr){
  int q = blockIdx.x * 256 + threadIdx.x;
  if (q >= S1) return;
  int cnt = 0;
  int list[12];
  for (int j = 0; j < S1; ++j)
    if (pam_ok(q, j) && cnt < 12) list[cnt++] = j;
  #pragma unroll
  for (int t = 0; t < 12; ++t) nbr[q*12 + t] = (t < cnt) ? list[t] : -1;
}

// ---------------- embedding ----------------
__global__ void embed_kernel(const void* __restrict__ x, const void* __restrict__ t,
                             const void* __restrict__ cw, const void* __restrict__ tw,
                             const void* __restrict__ tb, const u16* __restrict__ det,
                             float* __restrict__ out)
{
  bool f32 = is_f32(det);
  int idx = blockIdx.x * 256 + threadIdx.x;
  if (idx >= BSZ*L_IN*DM) return;
  int d = idx & (DM-1);
  int l = (idx >> 9) % L_IN;
  int b = idx / (DM*L_IN);
  float acc = 0.f;
  #pragma unroll
  for (int tt = 0; tt < 3; ++tt){
    int ls = l + tt - 1;
    ls = (ls < 0) ? ls + L_IN : (ls >= L_IN ? ls - L_IN : ls);
    long long xo = ((long long)(b*L_IN + ls))*7;
    #pragma unroll
    for (int c = 0; c < 7; ++c)
      acc += ldv(x, xo + c, f32) * ldv(cw, d*21 + c*3 + tt, f32);
  }
  int d2 = d & ~1;
  float dv  = expf(-(float)d2 * (9.210340371976184f/512.f));
  float ang = (float)l * dv;
  acc += (d & 1) ? cosf(ang) : sinf(ang);
  long long to = ((long long)(b*L_IN + l))*4;
  #pragma unroll
  for (int f = 0; f < 4; ++f) acc += ldv(t, to + f, f32) * ldv(tw, f*DM + d, f32);
  acc += ldv(tb, d, f32);
  out[idx] = acc;
}

// ---------------- batched per-layer weight transpose ----------------
__device__ inline void trans32(const void* W, long long wOff, int K, int N, int k0, int n0,
                               u16* __restrict__ Wt, bool f32, float* tb, int tid)
{
  int c = tid & 31, r0 = tid >> 5;
  #pragma unroll
  for (int rr = 0; rr < 32; rr += 8)
    tb[(r0+rr)*33 + c] = ldv(W, wOff + (long long)(k0+r0+rr)*N + n0 + c, f32);
  __syncthreads();
  #pragma unroll
  for (int rr = 0; rr < 32; rr += 8)
    Wt[(size_t)(n0+r0+rr)*K + k0 + c] = f2b(tb[c*33 + r0+rr]);
}

__global__ __launch_bounds__(256)
void wt_batch(const void* wq, const void* wk, const void* wv,
              const void* wo, const void* w1, const void* w2,
              long long wO, long long oO, long long fO,
              u16* __restrict__ Wt3, u16* __restrict__ WtO,
              u16* __restrict__ Wt1, u16* __restrict__ Wt2,
              const u16* __restrict__ det)
{
  __shared__ float tb[32*33];
  bool f32 = is_f32(det);
  int t = blockIdx.x, tid = threadIdx.x;
  if (t < 384)       trans32(wq, wO, 512, 768, (t/24)*32, (t%24)*32, Wt3,               f32, tb, tid);
  else if (t < 768)  { int u = t-384;  trans32(wk, wO, 512, 768, (u/24)*32, (u%24)*32, Wt3 + (size_t)768*512,  f32, tb, tid); }
  else if (t < 1152) { int u = t-768;  trans32(wv, wO, 512, 768, (u/24)*32, (u%24)*32, Wt3 + (size_t)1536*512, f32, tb, tid); }
  else if (t < 1536) { int u = t-1152; trans32(wo, oO, 768, 512, (u/16)*32, (u%16)*32, WtO, f32, tb, tid); }
  else if (t < 1792) { int u = t-1536; trans32(w1, fO, 512, 512, (u/16)*32, (u%16)*32, Wt1, f32, tb, tid); }
  else               { int u = t-1792; trans32(w2, fO, 512, 512, (u/16)*32, (u%16)*32, Wt2, f32, tb, tid); }
}

// ---------------- MFMA GEMM: C = A[M,K] @ W via Wt bf16 [N,K] ----------------
template<int EPI, int ABF, int CBF>
__global__ __launch_bounds__(256)
void gemm_mfma(const void* __restrict__ Av, const u16* __restrict__ Wt,
               const void* __restrict__ bias, long long bOff, const float* __restrict__ R,
               void* __restrict__ Cv, const u16* __restrict__ det,
               int K, int N, int La, int Lc, int off)
{
  __shared__ u16 As[128][64];
  __shared__ u16 Bs[128][64];
  bool f32 = is_f32(det);
  int tid = threadIdx.x;
  int row0 = blockIdx.y*128, col0 = blockIdx.x*128;
  int wave = tid >> 6, lane = tid & 63;
  int wm = (wave >> 1)*64, wn = (wave & 1)*64;
  int lm = lane & 15, quad = lane >> 4;
  int sr = tid >> 1;
  int sh = (tid & 1) * 32;
  int swzS = (sr & 7) * 8;
  f32x4v acc[4][4];
  #pragma unroll
  for (int i = 0; i < 4; ++i)
    #pragma unroll
    for (int j = 0; j < 4; ++j) acc[i][j] = (f32x4v){0.f,0.f,0.f,0.f};

  for (int k0 = 0; k0 < K; k0 += 64){
    if (ABF){
      const u16* src = (const u16*)Av + (size_t)(row0+sr)*K + k0 + sh;
      uint4 v0 = *(const uint4*)(src+0);
      uint4 v1 = *(const uint4*)(src+8);
      uint4 v2 = *(const uint4*)(src+16);
      uint4 v3 = *(const uint4*)(src+24);
      *(uint4*)&As[sr][(sh+0)^swzS]  = v0;
      *(uint4*)&As[sr][(sh+8)^swzS]  = v1;
      *(uint4*)&As[sr][(sh+16)^swzS] = v2;
      *(uint4*)&As[sr][(sh+24)^swzS] = v3;
    } else {
      const float* src = (const float*)Av + (size_t)(row0+sr)*K + k0 + sh;
      #pragma unroll
      for (int j = 0; j < 4; ++j){
        float4 f0 = *(const float4*)(src + 8*j);
        float4 f1 = *(const float4*)(src + 8*j + 4);
        uint4 o;
        o.x = pk2(f0.x, f0.y); o.y = pk2(f0.z, f0.w);
        o.z = pk2(f1.x, f1.y); o.w = pk2(f1.z, f1.w);
        *(uint4*)&As[sr][(sh + 8*j)^swzS] = o;
      }
    }
    {
      const u16* src = Wt + (size_t)(col0+sr)*K + k0 + sh;
      uint4 v0 = *(const uint4*)(src+0);
      uint4 v1 = *(const uint4*)(src+8);
      uint4 v2 = *(const uint4*)(src+16);
      uint4 v3 = *(const uint4*)(src+24);
      *(uint4*)&Bs[sr][(sh+0)^swzS]  = v0;
      *(uint4*)&Bs[sr][(sh+8)^swzS]  = v1;
      *(uint4*)&Bs[sr][(sh+16)^swzS] = v2;
      *(uint4*)&Bs[sr][(sh+24)^swzS] = v3;
    }
    __syncthreads();
    bf16x8 af[4][2], bfr[4][2];
    #pragma unroll
    for (int mi = 0; mi < 4; ++mi){
      int m = wm + mi*16 + lm;
      int sz = (m & 7)*8;
      af[mi][0] = *(const bf16x8*)&As[m][(quad*8) ^ sz];
      af[mi][1] = *(const bf16x8*)&As[m][(32 + quad*8) ^ sz];
    }
    #pragma unroll
    for (int ni = 0; ni < 4; ++ni){
      int n = wn + ni*16 + lm;
      int sz = (n & 7)*8;
      bfr[ni][0] = *(const bf16x8*)&Bs[n][(quad*8) ^ sz];
      bfr[ni][1] = *(const bf16x8*)&Bs[n][(32 + quad*8) ^ sz];
    }
    #pragma unroll
    for (int mi = 0; mi < 4; ++mi)
      #pragma unroll
      for (int ni = 0; ni < 4; ++ni){
        acc[mi][ni] = __builtin_amdgcn_mfma_f32_16x16x32_bf16(af[mi][0], bfr[ni][0], acc[mi][ni], 0, 0, 0);
        acc[mi][ni] = __builtin_amdgcn_mfma_f32_16x16x32_bf16(af[mi][1], bfr[ni][1], acc[mi][ni], 0, 0, 0);
      }
    __syncthreads();
  }
  #pragma unroll
  for (int mi = 0; mi < 4; ++mi){
    #pragma unroll
    for (int r = 0; r < 4; ++r){
      int row = row0 + wm + mi*16 + quad*4 + r;
      int bb = row / La, l = row - bb*La;
      size_t crow = ((size_t)bb*Lc + off + l)*(size_t)N;
      #pragma unroll
      for (int ni = 0; ni < 4; ++ni){
        int col = col0 + wn + ni*16 + lm;
        float vv = acc[mi][ni][r] + ldv(bias, bOff + col, f32);
        if (EPI == 1) vv = 0.5f*vv*(1.f + erff(vv*0.70710678118654752f));
        if (EPI == 2) vv += R[crow + col];
        if (CBF) ((u16*)Cv)[crow + col] = f2b(vv);
        else     ((float*)Cv)[crow + col] = vv;
      }
    }
  }
}

// ---------------- fused QKV / KV MFMA GEMM (A f32, out bf16, K=512) ----------------
__global__ __launch_bounds__(256)
void gemm_qkv(const float* __restrict__ A, const u16* __restrict__ Wt,
              const void* __restrict__ b0, const void* __restrict__ b1, const void* __restrict__ b2,
              long long bOff, u16* __restrict__ o0, u16* __restrict__ o1, u16* __restrict__ o2,
              const u16* __restrict__ det, int La, int Lc, int off)
{
  __shared__ u16 As[128][64];
  __shared__ u16 Bs[128][64];
  bool f32 = is_f32(det);
  const int K = 512;
  int tid = threadIdx.x;
  int row0 = blockIdx.y*128, col0 = blockIdx.x*128;
  int wave = tid >> 6, lane = tid & 63;
  int wm = (wave >> 1)*64, wn = (wave & 1)*64;
  int lm = lane & 15, quad = lane >> 4;
  int sr = tid >> 1;
  int sh = (tid & 1) * 32;
  int swzS = (sr & 7) * 8;
  f32x4v acc[4][4];
  #pragma unroll
  for (int i = 0; i < 4; ++i)
    #pragma unroll
    for (int j = 0; j < 4; ++j) acc[i][j] = (f32x4v){0.f,0.f,0.f,0.f};

  for (int k0 = 0; k0 < K; k0 += 64){
    {
      const float* src = A + (size_t)(row0+sr)*K + k0 + sh;
      #pragma unroll
      for (int j = 0; j < 4; ++j){
        float4 f0 = *(const float4*)(src + 8*j);
        float4 f1 = *(const float4*)(src + 8*j + 4);
        uint4 o;
        o.x = pk2(f0.x, f0.y); o.y = pk2(f0.z, f0.w);
        o.z = pk2(f1.x, f1.y); o.w = pk2(f1.z, f1.w);
        *(uint4*)&As[sr][(sh + 8*j)^swzS] = o;
      }
    }
    {
      const u16* src = Wt + (size_t)(col0+sr)*K + k0 + sh;
      uint4 v0 = *(const uint4*)(src+0);
      uint4 v1 = *(const uint4*)(src+8);
      uint4 v2 = *(const uint4*)(src+16);
      uint4 v3 = *(const uint4*)(src+24);
      *(uint4*)&Bs[sr][(sh+0)^swzS]  = v0;
      *(uint4*)&Bs[sr][(sh+8)^swzS]  = v1;
      *(uint4*)&Bs[sr][(sh+16)^swzS] = v2;
      *(uint4*)&Bs[sr][(sh+24)^swzS] = v3;
    }
    __syncthreads();
    bf16x8 af[4][2], bfr[4][2];
    #pragma unroll
    for (int mi = 0; mi < 4; ++mi){
      int m = wm + mi*16 + lm;
      int sz = (m & 7)*8;
      af[mi][0] = *(const bf16x8*)&As[m][(quad*8) ^ sz];
      af[mi][1] = *(const bf16x8*)&As[m][(32 + quad*8) ^ sz];
    }
    #pragma unroll
    for (int ni = 0; ni < 4; ++ni){
      int n = wn + ni*16 + lm;
      int sz = (n & 7)*8;
      bfr[ni][0] = *(const bf16x8*)&Bs[n][(quad*8) ^ sz];
      bfr[ni][1] = *(const bf16x8*)&Bs[n][(32 + quad*8) ^ sz];
    }
    #pragma unroll
    for (int mi = 0; mi < 4; ++mi)
      #pragma unroll
      for (int ni = 0; ni < 4; ++ni){
        acc[mi][ni] = __builtin_amdgcn_mfma_f32_16x16x32_bf16(af[mi][0], bfr[ni][0], acc[mi][ni], 0, 0, 0);
        acc[mi][ni] = __builtin_amdgcn_mfma_f32_16x16x32_bf16(af[mi][1], bfr[ni][1], acc[mi][ni], 0, 0, 0);
      }
    __syncthreads();
  }
  #pragma unroll
  for (int mi = 0; mi < 4; ++mi){
    #pragma unroll
    for (int r = 0; r < 4; ++r){
      int row = row0 + wm + mi*16 + quad*4 + r;
      int bb = row / La, l = row - bb*La;
      size_t crow = ((size_t)bb*Lc + off + l)*(size_t)HD;
      #pragma unroll
      for (int ni = 0; ni < 4; ++ni){
        int col = col0 + wn + ni*16 + lm;
        int sel = (col >= 1536) ? 2 : (col >= 768 ? 1 : 0);
        int colr = col - sel*768;
        const void* bp = (sel == 0) ? b0 : (sel == 1) ? b1 : b2;
        u16* dst = (sel == 0) ? o0 : (sel == 1) ? o1 : o2;
        float vv = acc[mi][ni][r] + ldv(bp, bOff + colr, f32);
        dst[crow + colr] = f2b(vv);
      }
    }
  }
}

// ---------------- SIMT GEMM (bottleneck) ----------------
#define BM 64
#define BN 64
#define BK 16
__global__ __launch_bounds__(256)
void gemm_k(const float* __restrict__ A, const void* __restrict__ W, long long wOff,
            const void* __restrict__ bias, long long bOff,
            float* __restrict__ C, const u16* __restrict__ det, int K, int N)
{
  __shared__ float As2[BK][BM+4];
  __shared__ float Bs2[BK][BN+4];
  bool f32 = is_f32(det);
  int tid = threadIdx.x;
  int row0 = blockIdx.y * BM, col0 = blockIdx.x * BN;
  int ty = tid >> 4, tx = tid & 15;
  int lr = tid >> 2, lc4 = (tid & 3) << 2;
  int wr = tid >> 4, wc4 = (tid & 15) << 2;
  float acc[4][4] = {};
  for (int k0 = 0; k0 < K; k0 += BK){
    float4 av = *(const float4*)(A + (size_t)(row0 + lr)*K + k0 + lc4);
    As2[lc4+0][lr] = av.x; As2[lc4+1][lr] = av.y;
    As2[lc4+2][lr] = av.z; As2[lc4+3][lr] = av.w;
    float4 wv = ldv4(W, wOff + (long long)(k0 + wr)*N + col0 + wc4, f32);
    *(float4*)&Bs2[wr][wc4] = wv;
    __syncthreads();
    #pragma unroll
    for (int kk = 0; kk < BK; ++kk){
      float4 a  = *(const float4*)&As2[kk][ty << 2];
      float4 bb = *(const float4*)&Bs2[kk][tx << 2];
      acc[0][0] += a.x*bb.x; acc[0][1] += a.x*bb.y; acc[0][2] += a.x*bb.z; acc[0][3] += a.x*bb.w;
      acc[1][0] += a.y*bb.x; acc[1][1] += a.y*bb.y; acc[1][2] += a.y*bb.z; acc[1][3] += a.y*bb.w;
      acc[2][0] += a.z*bb.x; acc[2][1] += a.z*bb.y; acc[2][2] += a.z*bb.z; acc[2][3] += a.z*bb.w;
      acc[3][0] += a.w*bb.x; acc[3][1] += a.w*bb.y; acc[3][2] += a.w*bb.z; acc[3][3] += a.w*bb.w;
    }
    __syncthreads();
  }
  #pragma unroll
  for (int i = 0; i < 4; ++i){
    int r = row0 + (ty << 2) + i;
    size_t crow = (size_t)r*(size_t)N;
    #pragma unroll
    for (int j = 0; j < 4; ++j){
      int c = col0 + (tx << 2) + j;
      C[crow + c] = acc[i][j] + ldv(bias, bOff + c, f32);
    }
  }
}

// ---------------- conv weight reorder: w[lay][co][ci][tt] -> Wc[lay][tt*128+ci][co] (f32) ----------------
__global__ void wc_kernel(const void* __restrict__ w, float* __restrict__ Wc,
                          const u16* __restrict__ det)
{
  bool f32 = is_f32(det);
  int idx = blockIdx.x * 256 + threadIdx.x;
  if (idx >= 3*512*128) return;
  int co = idx & 127;
  int kk = (idx >> 7) & 511;
  int lay = idx >> 16;
  int tt = kk >> 7, ci = kk & 127;
  Wc[idx] = ldv(w, (long long)lay*65536 + co*512 + ci*4 + tt, f32);
}

// ---------------- bottleneck conv as GEMM [B*Lout,512]x[512,128] + BN + ELU ----------------
__global__ __launch_bounds__(256)
void conv_gemm(const float* __restrict__ in, int inStride, int inOff,
               float* __restrict__ out, int outStride, int outOff, int Lout,
               const float* __restrict__ Wc,   // [512][128] for this layer
               const void* __restrict__ cb, const void* __restrict__ bg,
               const void* __restrict__ bb, const void* __restrict__ bm,
               const void* __restrict__ bv, const u16* __restrict__ det, int lay)
{
  __shared__ float As2[BK][BM+4];
  __shared__ float Bs2[BK][BN+4];
  bool f32 = is_f32(det);
  int tid = threadIdx.x;
  int row0 = blockIdx.y * BM, col0 = blockIdx.x * BN;
  int ty = tid >> 4, tx = tid & 15;
  int lr = tid >> 2, lc4 = (tid & 3) << 2;
  int wr = tid >> 4, wc4 = (tid & 15) << 2;
  // per-thread staging row base (input rows j*4.. are 512 contiguous floats)
  int rs = row0 + lr;
  int bs = rs / Lout, js = rs - bs*Lout;
  const float* arow = in + ((size_t)(bs*inStride + inOff + js*4))*128;
  float acc[4][4] = {};
  for (int k0 = 0; k0 < 512; k0 += BK){
    float4 av = *(const float4*)(arow + k0 + lc4);
    As2[lc4+0][lr] = av.x; As2[lc4+1][lr] = av.y;
    As2[lc4+2][lr] = av.z; As2[lc4+3][lr] = av.w;
    float4 wv = *(const float4*)(Wc + (size_t)(k0 + wr)*128 + col0 + wc4);
    *(float4*)&Bs2[wr][wc4] = wv;
    __syncthreads();
    #pragma unroll
    for (int kk = 0; kk < BK; ++kk){
      float4 a  = *(const float4*)&As2[kk][ty << 2];
      float4 bb2 = *(const float4*)&Bs2[kk][tx << 2];
      acc[0][0] += a.x*bb2.x; acc[0][1] += a.x*bb2.y; acc[0][2] += a.x*bb2.z; acc[0][3] += a.x*bb2.w;
      acc[1][0] += a.y*bb2.x; acc[1][1] += a.y*bb2.y; acc[1][2] += a.y*bb2.z; acc[1][3] += a.y*bb2.w;
      acc[2][0] += a.z*bb2.x; acc[2][1] += a.z*bb2.y; acc[2][2] += a.z*bb2.z; acc[2][3] += a.z*bb2.w;
      acc[3][0] += a.w*bb2.x; acc[3][1] += a.w*bb2.y; acc[3][2] += a.w*bb2.z; acc[3][3] += a.w*bb2.w;
    }
    __syncthreads();
  }
  #pragma unroll
  for (int i = 0; i < 4; ++i){
    int r = row0 + (ty << 2) + i;
    int b = r / Lout, j = r - b*Lout;
    float* orow = out + ((size_t)(b*outStride + outOff + j))*128;
    #pragma unroll
    for (int jj = 0; jj < 4; ++jj){
      int co = col0 + (tx << 2) + jj;
      long long po = (long long)lay*128 + co;
      float a = acc[i][jj] + ldv(cb, po, f32);
      a = (a - ldv(bm, po, f32)) * rsqrtf(ldv(bv, po, f32) + 1e-5f) * ldv(bg, po, f32) + ldv(bb, po, f32);
      a = a > 0.f ? a : (__expf(a) - 1.f);
      orow[co] = a;
    }
  }
}

// ---------------- LayerNorm (4 rows per block) ----------------
__global__ __launch_bounds__(256)
void ln_kernel(const float* __restrict__ X, const void* __restrict__ g, long long gOff,
               const void* __restrict__ bt, long long bOff, float eps,
               float* __restrict__ Out, const u16* __restrict__ det)
{
  bool f32 = is_f32(det);
  int row = blockIdx.x*4 + (threadIdx.x >> 6);
  int lane = threadIdx.x & 63;
  const float* xr = X + (size_t)row*DM;
  float v[8]; float s = 0.f;
  #pragma unroll
  for (int i = 0; i < 8; ++i){ v[i] = xr[lane + i*64]; s += v[i]; }
  #pragma unroll
  for (int o = 32; o > 0; o >>= 1) s += __shfl_xor(s, o);
  float mean = s * (1.f/512.f);
  float q = 0.f;
  #pragma unroll
  for (int i = 0; i < 8; ++i){ float d = v[i]-mean; q += d*d; }
  #pragma unroll
  for (int o = 32; o > 0; o >>= 1) q += __shfl_xor(q, o);
  float inv = rsqrtf(q*(1.f/512.f) + eps);
  float* orow = Out + (size_t)row*DM;
  #pragma unroll
  for (int i = 0; i < 8; ++i){
    int c = lane + i*64;
    orow[c] = (v[i]-mean)*inv*ldv(g, gOff + c, f32) + ldv(bt, bOff + c, f32);
  }
}

// ---------------- concat + LayerNorm(1e-5), 4 rows per block ----------------
__global__ __launch_bounds__(256)
void concat_ln_kernel(const float* __restrict__ emb, const float* __restrict__ up,
                      const void* __restrict__ g, const void* __restrict__ bt,
                      float* __restrict__ Out, const u16* __restrict__ det)
{
  bool f32 = is_f32(det);
  int row = blockIdx.x*4 + (threadIdx.x >> 6);
  int lane = threadIdx.x & 63;
  int b = row / S1, l = row - b*S1;
  const float* xr = (l < L_IN) ? emb + ((size_t)(b*L_IN + l))*DM
                               : up  + ((size_t)(b*54 + (l - L_IN)))*DM;
  float v[8]; float s = 0.f;
  #pragma unroll
  for (int i = 0; i < 8; ++i){ v[i] = xr[lane + i*64]; s += v[i]; }
  #pragma unroll
  for (int o = 32; o > 0; o >>= 1) s += __shfl_xor(s, o);
  float mean = s * (1.f/512.f);
  float q = 0.f;
  #pragma unroll
  for (int i = 0; i < 8; ++i){ float d = v[i]-mean; q += d*d; }
  #pragma unroll
  for (int o = 32; o > 0; o >>= 1) q += __shfl_xor(q, o);
  float inv = rsqrtf(q*(1.f/512.f) + 1e-5f);
  float* orow = Out + (size_t)row*DM;
  #pragma unroll
  for (int i = 0; i < 8; ++i){
    int c = lane + i*64;
    orow[c] = (v[i]-mean)*inv*ldv(g, c, f32) + ldv(bt, c, f32);
  }
}

// ---------------- encoder attention: PAM-sparse, 16-lane unit per (b,q,h) ----------------
__global__ __launch_bounds__(256)
void attn_enc_sparse(u16* __restrict__ q, const u16* __restrict__ k,
                     const u16* __restrict__ v, const int* __restrict__ nbr)
{
  int u = blockIdx.x * 16 + (threadIdx.x >> 4);   // unit = (b*S1+qr)*NHD + h
  int lane16 = threadIdx.x & 15;
  int h = u % NHD;
  int bq = u / NHD;
  int b = bq / S1, qr = bq - b*S1;
  const float scale = 0.088388347648318447f;
  size_t rowoff = (size_t)bq*HD + h*DK + lane16*8;
  uint4 qw = *(const uint4*)(q + rowoff);
  float qd[8]; unpack8(qw, qd);
  const int* nb = nbr + qr*12;
  size_t base = (size_t)b*S1*HD + h*DK + lane16*8;
  float pj[12];
  #pragma unroll
  for (int j = 0; j < 12; ++j){
    int kg = nb[j];
    int kgc = kg < 0 ? 0 : kg;
    uint4 kw = *(const uint4*)(k + (size_t)kgc*HD + base);
    float kd[8]; unpack8(kw, kd);
    float p = qd[0]*kd[0] + qd[1]*kd[1] + qd[2]*kd[2] + qd[3]*kd[3]
            + qd[4]*kd[4] + qd[5]*kd[5] + qd[6]*kd[6] + qd[7]*kd[7];
    p += __shfl_xor(p, 1); p += __shfl_xor(p, 2);
    p += __shfl_xor(p, 4); p += __shfl_xor(p, 8);
    pj[j] = (kg >= 0) ? p*scale : -1e30f;
  }
  float m = -1e30f;
  #pragma unroll
  for (int j = 0; j < 12; ++j) m = fmaxf(m, pj[j]);
  float s = 0.f;
  #pragma unroll
  for (int j = 0; j < 12; ++j){ pj[j] = __expf(pj[j] - m); s += pj[j]; }
  float inv = 1.f / s;
  float o[8];
  #pragma unroll
  for (int i = 0; i < 8; ++i) o[i] = 0.f;
  #pragma unroll
  for (int j = 0; j < 12; ++j){
    int kg = nb[j];
    int kgc = kg < 0 ? 0 : kg;
    uint4 vw = *(const uint4*)(v + (size_t)kgc*HD + base);
    float vd[8]; unpack8(vw, vd);
    #pragma unroll
    for (int i = 0; i < 8; ++i) o[i] += pj[j]*vd[i];
  }
  uint4 ow;
  ow.x = pk2(o[0]*inv, o[1]*inv);
  ow.y = pk2(o[2]*inv, o[3]*inv);
  ow.z = pk2(o[4]*inv, o[5]*inv);
  ow.w = pk2(o[6]*inv, o[7]*inv);
  *(uint4*)(q + rowoff) = ow;
}

// ---------------- decoder attention: MFMA flash ----------------
#define FQT 64
__global__ __launch_bounds__(256)
void attn_dec_mfma(u16* __restrict__ q, const u16* __restrict__ k,
                   const u16* __restrict__ v)
{
  __shared__ u16 Qs[FQT][136];
  __shared__ u16 Ks[32][136];
  __shared__ u32 Vt[128][20];
  __shared__ u16 Pls[4][16][32];
  int b = blockIdx.z, h = blockIdx.y;
  int qt0 = blockIdx.x * FQT;
  int tid = threadIdx.x;
  int wave = tid >> 6, lane = tid & 63;
  int lm = lane & 15, quad = lane >> 4;
  const float scale = 0.088388347648318447f;
  const size_t qb0 = (size_t)b*L_IN*HD + (size_t)h*DK;
  const size_t kb0 = (size_t)b*SKV*HD + (size_t)h*DK;

  for (int i = tid*4; i < FQT*128; i += 1024){
    int row = i >> 7, d = i & 127;
    int qg = qt0 + row;
    ushort4 w = make_ushort4(0,0,0,0);
    if (qg < L_IN) w = *(const ushort4*)(q + qb0 + (size_t)qg*HD + d);
    *(ushort4*)&Qs[row][d] = w;
  }
  __syncthreads();
  bf16x8 qf[4];
  #pragma unroll
  for (int ks = 0; ks < 4; ++ks)
    qf[ks] = *(const bf16x8*)&Qs[wave*16 + lm][ks*32 + quad*8];

  float mold[4], lsum[4];
  #pragma unroll
  for (int r = 0; r < 4; ++r){ mold[r] = -1e30f; lsum[r] = 0.f; }
  f32x4v oacc[8];
  #pragma unroll
  for (int f = 0; f < 8; ++f) oacc[f] = (f32x4v){0.f,0.f,0.f,0.f};

  int kEnd = S1 + qt0 + FQT; if (kEnd > SKV) kEnd = SKV;
  for (int kt0 = 0; kt0 < kEnd; kt0 += 32){
    __syncthreads();
    for (int i = tid*4; i < 32*128; i += 1024){
      int kk = i >> 7, d = i & 127;
      int kg = kt0 + kk;
      ushort4 w = make_ushort4(0,0,0,0);
      if (kg < SKV) w = *(const ushort4*)(k + kb0 + (size_t)kg*HD + d);
      *(ushort4*)&Ks[kk][d] = w;
    }
    for (int t2 = tid; t2 < 512; t2 += 256){
      int g = t2 & 31, p = t2 >> 5;
      int kg0 = kt0 + 2*p, d0 = g*4;
      ushort4 a = make_ushort4(0,0,0,0), c = make_ushort4(0,0,0,0);
      if (kg0     < SKV) a = *(const ushort4*)(v + kb0 + (size_t)kg0*HD + d0);
      if (kg0 + 1 < SKV) c = *(const ushort4*)(v + kb0 + (size_t)(kg0+1)*HD + d0);
      Vt[d0+0][p] = (u32)a.x | ((u32)c.x << 16);
      Vt[d0+1][p] = (u32)a.y | ((u32)c.y << 16);
      Vt[d0+2][p] = (u32)a.z | ((u32)c.z << 16);
      Vt[d0+3][p] = (u32)a.w | ((u32)c.w << 16);
    }
    __syncthreads();
    f32x4v sacc[2];
    sacc[0] = (f32x4v){0.f,0.f,0.f,0.f};
    sacc[1] = (f32x4v){0.f,0.f,0.f,0.f};
    #pragma unroll
    for (int t = 0; t < 2; ++t)
      #pragma unroll
      for (int ks = 0; ks < 4; ++ks){
        bf16x8 kf = *(const bf16x8*)&Ks[t*16 + lm][ks*32 + quad*8];
        sacc[t] = __builtin_amdgcn_mfma_f32_16x16x32_bf16(qf[ks], kf, sacc[t], 0, 0, 0);
      }
    float p[2][4];
    #pragma unroll
    for (int r = 0; r < 4; ++r){
      int qg = qt0 + wave*16 + quad*4 + r;
      float s0, s1;
      {
        int kg = kt0 + lm;
        bool ok = (kg < SKV) && (qg < L_IN) && (kg <= S1 + qg);
        s0 = ok ? sacc[0][r]*scale : -1e30f;
      }
      {
        int kg = kt0 + 16 + lm;
        bool ok = (kg < SKV) && (qg < L_IN) && (kg <= S1 + qg);
        s1 = ok ? sacc[1][r]*scale : -1e30f;
      }
      float mn = fmaxf(s0, s1);
      #pragma unroll
      for (int o = 8; o > 0; o >>= 1) mn = fmaxf(mn, __shfl_xor(mn, o));
      float mi = fmaxf(mold[r], mn);
      float alpha = __expf(mold[r] - mi);
      mold[r] = mi;
      p[0][r] = __expf(s0 - mi);
      p[1][r] = __expf(s1 - mi);
      float rs = p[0][r] + p[1][r];
      #pragma unroll
      for (int o = 8; o > 0; o >>= 1) rs += __shfl_xor(rs, o);
      lsum[r] = lsum[r]*alpha + rs;
      #pragma unroll
      for (int f = 0; f < 8; ++f) oacc[f][r] *= alpha;
    }
    #pragma unroll
    for (int r = 0; r < 4; ++r){
      Pls[wave][quad*4+r][lm]      = f2b(p[0][r]);
      Pls[wave][quad*4+r][16 + lm] = f2b(p[1][r]);
    }
    bf16x8 pa = *(const bf16x8*)&Pls[wave][lm][quad*8];
    #pragma unroll
    for (int f = 0; f < 8; ++f){
      bf16x8 vf = *(const bf16x8*)&Vt[f*16 + lm][quad*4];
      oacc[f] = __builtin_amdgcn_mfma_f32_16x16x32_bf16(pa, vf, oacc[f], 0, 0, 0);
    }
  }
  #pragma unroll
  for (int r = 0; r < 4; ++r){
    int qg = qt0 + wave*16 + quad*4 + r;
    if (qg < L_IN){
      float inv = 1.f / lsum[r];
      #pragma unroll
      for (int f = 0; f < 8; ++f)
        q[qb0 + (size_t)qg*HD + f*16 + lm] = f2b(oacc[f][r]*inv);
    }
  }
}

// ---------------- prediction head ----------------
__global__ void pred_kernel(const float* __restrict__ X, const void* __restrict__ w,
                            void* __restrict__ out, const u16* __restrict__ det)
{
  bool f32 = is_f32(det);
  int idx = blockIdx.x * 256 + threadIdx.x;
  if (idx >= BSZ*L_IN*7) return;
  int c  = idx % 7;
  int rl = idx / 7;
  const float* xr = X + (size_t)rl*DM;
  float acc = 0.f;
  for (int kk = 0; kk < DM; ++kk) acc += xr[kk] * ldv(w, kk*7 + c, f32);
  if (f32) ((float*)out)[idx] = acc;
  else     ((u16*)out)[idx] = f2b(acc);
}

// ---------------- launch ----------------
extern "C" void kernel_launch(void* const* d_in, const int* in_sizes, int n_in,
                              void* d_out, int out_size, void* d_ws, size_t ws_size,
                              hipStream_t stream)
{
  (void)in_sizes; (void)n_in; (void)out_size; (void)ws_size;
  #define IN(i) ((const void*)d_in[i])
  const u16* det = (const u16*)d_in[20];
  float* ws   = (float*)d_ws;
  float* encx = ws + OFF_ENCX;
  float* decx = ws + OFF_DECX;
  u16*   qb   = (u16*)(ws + OFF_QB);
  u16*   kb   = (u16*)(ws + OFF_KB);
  u16*   vb   = (u16*)(ws + OFF_VB);
  int*   nbr  = (int*)(ws + OFF_NBR);
  // phase-disjoint aliases
  float* tmp1  = ws + OFF_VB;                               // f32 pre-LN sums (V dead)
  u16*   WtE3  = (u16*)(ws + OFF_VB + (size_t)BSZ*S1*DM);   // enc Wt concat [2304][512]
  u16*   WtEO  = WtE3 + (size_t)2304*512;
  u16*   WtE1  = WtEO + (size_t)768*512;
  u16*   WtE2  = WtE1 + (size_t)512*512;
  u16*   WtD3  = (u16*)(ws + OFF_QB + (size_t)BSZ*L_IN*HD/2);
  u16*   WtDO  = WtD3 + (size_t)2304*512;
  u16*   WtD1  = WtDO + (size_t)768*512;
  u16*   WtD2  = WtD1 + (size_t)512*512;
  u16*   tmph  = (u16*)(ws + OFF_KB);                       // bf16 ffn hidden (K dead)
  float* embE  = ws + OFF_VB;                               // f32 enc embed (pre-encoder)
  float* Wc    = ws + OFF_QB;                               // conv weights reordered (qb dead in bottleneck)
  float* bdown = ws + OFF_KB;
  float* bconv = bdown + (size_t)BSZ*L_IN*128;
  float* bup   = bconv + (size_t)BSZ*54*128;

  build_nbr_kernel<<<1, 256, 0, stream>>>(nbr);

  embed_kernel<<<(BSZ*L_IN*DM)/256, 256, 0, stream>>>(IN(0), IN(1), IN(4), IN(5), IN(6), det, embE);
  embed_kernel<<<(BSZ*L_IN*DM)/256, 256, 0, stream>>>(IN(2), IN(3), IN(7), IN(8), IN(9), det, decx);

  // bottleneck
  wc_kernel<<<(3*512*128)/256, 256, 0, stream>>>(IN(12), Wc, det);
  gemm_k<<<dim3(128/BN, (BSZ*L_IN)/BM), 256, 0, stream>>>(
      embE, IN(10), 0, IN(11), 0, bdown, det, 512, 128);
  conv_gemm<<<dim3(2, (BSZ*42)/BM), 256, 0, stream>>>(
      bdown, L_IN, 0, bconv, 54, 0, 42, Wc, IN(13), IN(14), IN(15), IN(16), IN(17), det, 0);
  conv_gemm<<<dim3(2, (BSZ*10)/BM), 256, 0, stream>>>(
      bconv, 54, 0, bconv, 54, 42, 10, Wc + 65536, IN(13), IN(14), IN(15), IN(16), IN(17), det, 1);
  conv_gemm<<<dim3(2, (BSZ*2)/BM), 256, 0, stream>>>(
      bconv, 54, 42, bconv, 54, 52, 2, Wc + 131072, IN(13), IN(14), IN(15), IN(16), IN(17), det, 2);
  gemm_k<<<dim3(512/BN, (BSZ*54)/BM), 256, 0, stream>>>(
      bconv, IN(18), 0, IN(19), 0, bup, det, 128, 512);
  concat_ln_kernel<<<(BSZ*S1)/4, 256, 0, stream>>>(embE, bup, IN(20), IN(21), encx, det);

  // encoder layers
  for (int i = 0; i < 6; ++i){
    long long wO = (long long)i*512*768, oO = (long long)i*768*512;
    long long bO = (long long)i*768, dO = (long long)i*512;
    long long fO = (long long)i*512*512;
    wt_batch<<<2048, 256, 0, stream>>>(IN(22), IN(24), IN(26), IN(28), IN(32), IN(34),
                                       wO, oO, fO, WtE3, WtEO, WtE1, WtE2, det);
    gemm_qkv<<<dim3(18, 111), 256, 0, stream>>>(
        encx, WtE3, IN(23), IN(25), IN(27), bO, qb, kb, vb, det, S1, S1, 0);
    attn_enc_sparse<<<(BSZ*S1*NHD)/16, 256, 0, stream>>>(qb, kb, vb, nbr);
    gemm_mfma<2,1,0><<<dim3(4, 111), 256, 0, stream>>>(
        qb, WtEO, IN(29), dO, encx, tmp1, det, 768, 512, S1, S1, 0);
    ln_kernel<<<(BSZ*S1)/4, 256, 0, stream>>>(tmp1, IN(30), dO, IN(31), dO, 1e-6f, encx, det);
    gemm_mfma<1,0,1><<<dim3(4, 111), 256, 0, stream>>>(
        encx, WtE1, IN(33), dO, nullptr, tmph, det, 512, 512, S1, S1, 0);
    gemm_mfma<2,1,0><<<dim3(4, 111), 256, 0, stream>>>(
        tmph, WtE2, IN(35), dO, encx, tmp1, det, 512, 512, S1, S1, 0);
    ln_kernel<<<(BSZ*S1)/4, 256, 0, stream>>>(tmp1, IN(36), dO, IN(37), dO, 1e-6f, encx, det);
  }

  // decoder layers
  for (int i = 0; i < 2; ++i){
    long long wO = (long long)i*512*768, oO = (long long)i*768*512;
    long long bO = (long long)i*768, dO = (long long)i*512;
    long long fO = (long long)i*512*512;
    wt_batch<<<2048, 256, 0, stream>>>(IN(38), IN(40), IN(42), IN(44), IN(48), IN(50),
                                       wO, oO, fO, WtD3, WtDO, WtD1, WtD2, det);
    gemm_mfma<0,0,1><<<dim3(6, 84), 256, 0, stream>>>(
        decx, WtD3, IN(39), bO, nullptr, qb, det, 512, 768, L_IN, L_IN, 0);
    gemm_qkv<<<dim3(12, 111), 256, 0, stream>>>(
        encx, WtD3 + (size_t)768*512, IN(41), IN(43), IN(43), bO, kb, vb, vb, det, S1, SKV, 0);
    gemm_qkv<<<dim3(12, 84), 256, 0, stream>>>(
        decx, WtD3 + (size_t)768*512, IN(41), IN(43), IN(43), bO, kb, vb, vb, det, L_IN, SKV, S1);
    attn_dec_mfma<<<dim3(3, NHD, BSZ), 256, 0, stream>>>(qb, kb, vb);
    gemm_mfma<2,1,0><<<dim3(4, 84), 256, 0, stream>>>(
        qb, WtDO, IN(45), dO, decx, tmp1, det, 768, 512, L_IN, L_IN, 0);
    ln_kernel<<<(BSZ*L_IN)/4, 256, 0, stream>>>(tmp1, IN(46), dO, IN(47), dO, 1e-6f, decx, det);
    gemm_mfma<1,0,1><<<dim3(4, 84), 256, 0, stream>>>(
        decx, WtD1, IN(49), dO, nullptr, tmph, det, 512, 512, L_IN, L_IN, 0);
    gemm_mfma<2,1,0><<<dim3(4, 84), 256, 0, stream>>>(
        tmph, WtD2, IN(51), dO, decx, tmp1, det, 512, 512, L_IN, L_IN, 0);
    ln_kernel<<<(BSZ*L_IN)/4, 256, 0, stream>>>(tmp1, IN(52), dO, IN(53), dO, 1e-6f, decx, det);
  }

  pred_kernel<<<(BSZ*L_IN*7 + 255)/256, 256, 0, stream>>>(decx, IN(54), d_out, det);
  #undef IN
}

// Round 8
// 3241.628 us; speedup vs baseline: 4.5426x; 1.1420x over previous
//
#include <hip/hip_runtime.h>
#include <cstdint>
#include <cstddef>

// ---------------- model constants ----------------
#define BSZ   64
#define L_IN  168
#define S1    222
#define SKV   390
#define DM    512
#define HD    768
#define NHD   6
#define DK    128

typedef unsigned short u16;
typedef unsigned int u32;
typedef __attribute__((ext_vector_type(8))) short bf16x8;
typedef __attribute__((ext_vector_type(4))) float f32x4v;

// ---------------- bf16 helpers ----------------
__device__ inline float b2f(u16 u){
  union { u32 i; float f; } v; v.i = ((u32)u) << 16; return v.f;
}
__device__ inline u16 f2b(float f){
  union { float f; u32 i; } v; v.f = f;
  u32 x = v.i;
  return (u16)((x + 0x7fffu + ((x >> 16) & 1u)) >> 16);
}
__device__ inline u32 pk2(float a, float b){
  return ((u32)f2b(b) << 16) | (u32)f2b(a);
}
__device__ inline float ldv(const void* p, long long i, bool f32){
  return f32 ? ((const float*)p)[i] : b2f(((const u16*)p)[i]);
}
__device__ inline float4 ldv4(const void* p, long long i, bool f32){
  if (f32) return *(const float4*)((const float*)p + i);
  ushort4 w = *(const ushort4*)((const u16*)p + i);
  return make_float4(b2f(w.x), b2f(w.y), b2f(w.z), b2f(w.w));
}
__device__ inline bool is_f32(const u16* det){ return det[0] != 0x3F80; }
__device__ inline void unpack8(uint4 w, float* f){
  union { u32 i; float fl; } a;
  a.i = w.x << 16;          f[0] = a.fl;
  a.i = w.x & 0xffff0000u;  f[1] = a.fl;
  a.i = w.y << 16;          f[2] = a.fl;
  a.i = w.y & 0xffff0000u;  f[3] = a.fl;
  a.i = w.z << 16;          f[4] = a.fl;
  a.i = w.z & 0xffff0000u;  f[5] = a.fl;
  a.i = w.w << 16;          f[6] = a.fl;
  a.i = w.w & 0xffff0000u;  f[7] = a.fl;
}

// ---------------- workspace layout (float-equivalent offsets) ----------------
constexpr size_t OFF_ENCX = 0;
constexpr size_t OFF_DECX = OFF_ENCX + (size_t)BSZ*S1*DM;
constexpr size_t OFF_QB   = OFF_DECX + (size_t)BSZ*L_IN*DM;
constexpr size_t OFF_KB   = OFF_QB   + (size_t)BSZ*S1*HD/2;
constexpr size_t OFF_VB   = OFF_KB   + (size_t)BSZ*SKV*HD/2;
constexpr size_t OFF_NBR  = OFF_VB   + (size_t)BSZ*SKV*HD/2;
constexpr size_t OFF_ENCB = OFF_NBR  + 4096;                     // bf16 shadow of encx
constexpr size_t OFF_DECB = OFF_ENCB + (size_t)BSZ*S1*DM/2;      // bf16 shadow of decx
constexpr size_t WS_NEED  = (OFF_DECB + (size_t)BSZ*L_IN*DM/2) * 4;

// ---------------- PAM sparsity ----------------
__device__ inline int scale_of(int i, int& ii){
  if (i < 168){ ii = i;       return 0; }
  if (i < 210){ ii = i - 168; return 1; }
  if (i < 220){ ii = i - 210; return 2; }
  ii = i - 220; return 3;
}
__device__ inline bool pam_ok(int i, int j){
  int ii, jj;
  int li = scale_of(i, ii);
  int lj = scale_of(j, jj);
  const int n[4] = {168, 42, 10, 2};
  if (li == lj){ int d = ii - jj; return (d <= 1 && d >= -1); }
  if (li == lj + 1){ int lo = ii*4, hi = (ii == n[li]-1) ? n[lj] : ii*4+4; return (jj >= lo && jj < hi); }
  if (lj == li + 1){ int lo = jj*4, hi = (jj == n[lj]-1) ? n[li] : jj*4+4; return (ii >= lo && ii < hi); }
  return false;
}
__global__ void build_nbr_kernel(int* __restrict__ nbr){
  int q = blockIdx.x * 256 + threadIdx.x;
  if (q >= S1) return;
  int cnt = 0;
  int list[12];
  for (int j = 0; j < S1; ++j)
    if (pam_ok(q, j) && cnt < 12) list[cnt++] = j;
  #pragma unroll
  for (int t = 0; t < 12; ++t) nbr[q*12 + t] = (t < cnt) ? list[t] : -1;
}

// ---------------- embedding (optional bf16 shadow out2) ----------------
__global__ void embed_kernel(const void* __restrict__ x, const void* __restrict__ t,
                             const void* __restrict__ cw, const void* __restrict__ tw,
                             const void* __restrict__ tb, const u16* __restrict__ det,
                             float* __restrict__ out, u16* __restrict__ out2)
{
  bool f32 = is_f32(det);
  int idx = blockIdx.x * 256 + threadIdx.x;
  if (idx >= BSZ*L_IN*DM) return;
  int d = idx & (DM-1);
  int l = (idx >> 9) % L_IN;
  int b = idx / (DM*L_IN);
  float acc = 0.f;
  #pragma unroll
  for (int tt = 0; tt < 3; ++tt){
    int ls = l + tt - 1;
    ls = (ls < 0) ? ls + L_IN : (ls >= L_IN ? ls - L_IN : ls);
    long long xo = ((long long)(b*L_IN + ls))*7;
    #pragma unroll
    for (int c = 0; c < 7; ++c)
      acc += ldv(x, xo + c, f32) * ldv(cw, d*21 + c*3 + tt, f32);
  }
  int d2 = d & ~1;
  float dv  = expf(-(float)d2 * (9.210340371976184f/512.f));
  float ang = (float)l * dv;
  acc += (d & 1) ? cosf(ang) : sinf(ang);
  long long to = ((long long)(b*L_IN + l))*4;
  #pragma unroll
  for (int f = 0; f < 4; ++f) acc += ldv(t, to + f, f32) * ldv(tw, f*DM + d, f32);
  acc += ldv(tb, d, f32);
  out[idx] = acc;
  if (out2) out2[idx] = f2b(acc);
}

// ---------------- batched per-layer weight transpose ----------------
__device__ inline void trans32(const void* W, long long wOff, int K, int N, int k0, int n0,
                               u16* __restrict__ Wt, bool f32, float* tb, int tid)
{
  int c = tid & 31, r0 = tid >> 5;
  #pragma unroll
  for (int rr = 0; rr < 32; rr += 8)
    tb[(r0+rr)*33 + c] = ldv(W, wOff + (long long)(k0+r0+rr)*N + n0 + c, f32);
  __syncthreads();
  #pragma unroll
  for (int rr = 0; rr < 32; rr += 8)
    Wt[(size_t)(n0+r0+rr)*K + k0 + c] = f2b(tb[c*33 + r0+rr]);
}

__global__ __launch_bounds__(256)
void wt_batch(const void* wq, const void* wk, const void* wv,
              const void* wo, const void* w1, const void* w2,
              long long wO, long long oO, long long fO,
              u16* __restrict__ Wt3, u16* __restrict__ WtO,
              u16* __restrict__ Wt1, u16* __restrict__ Wt2,
              const u16* __restrict__ det)
{
  __shared__ float tb[32*33];
  bool f32 = is_f32(det);
  int t = blockIdx.x, tid = threadIdx.x;
  if (t < 384)       trans32(wq, wO, 512, 768, (t/24)*32, (t%24)*32, Wt3,               f32, tb, tid);
  else if (t < 768)  { int u = t-384;  trans32(wk, wO, 512, 768, (u/24)*32, (u%24)*32, Wt3 + (size_t)768*512,  f32, tb, tid); }
  else if (t < 1152) { int u = t-768;  trans32(wv, wO, 512, 768, (u/24)*32, (u%24)*32, Wt3 + (size_t)1536*512, f32, tb, tid); }
  else if (t < 1536) { int u = t-1152; trans32(wo, oO, 768, 512, (u/16)*32, (u%16)*32, WtO, f32, tb, tid); }
  else if (t < 1792) { int u = t-1536; trans32(w1, fO, 512, 512, (u/16)*32, (u%16)*32, Wt1, f32, tb, tid); }
  else               { int u = t-1792; trans32(w2, fO, 512, 512, (u/16)*32, (u%16)*32, Wt2, f32, tb, tid); }
}

// ---------------- XCD-exclusive row-panel swizzle ----------------
// 1-D grid of 8*rpx*CP blocks; XCD i owns row-panels {i, i+8, ...}; B col panel
// changes every rpx blocks within an XCD, so the A slab stays L2-resident.
__device__ inline bool swz(int t, int RP, int CP, int rpx, int& row0, int& col0){
  int xcd = t & 7, j = t >> 3;
  int rp = xcd + 8*(j % rpx);
  int cp = j / rpx;
  if (rp >= RP || cp >= CP) return false;
  row0 = rp*128; col0 = cp*128;
  return true;
}

// ---------------- MFMA GEMM: C = A[M,K] @ W via Wt bf16 [N,K] ----------------
template<int EPI, int ABF, int CBF>
__global__ __launch_bounds__(256)
void gemm_mfma(const void* __restrict__ Av, const u16* __restrict__ Wt,
               const void* __restrict__ bias, long long bOff, const float* __restrict__ R,
               void* __restrict__ Cv, const u16* __restrict__ det,
               int K, int N, int La, int Lc, int off, int RP, int CP, int rpx)
{
  __shared__ u16 As[128][64];
  __shared__ u16 Bs[128][64];
  bool f32 = is_f32(det);
  int tid = threadIdx.x;
  int row0, col0;
  if (!swz(blockIdx.x, RP, CP, rpx, row0, col0)) return;
  int wave = tid >> 6, lane = tid & 63;
  int wm = (wave >> 1)*64, wn = (wave & 1)*64;
  int lm = lane & 15, quad = lane >> 4;
  int sr = tid >> 1;
  int sh = (tid & 1) * 32;
  int swzS = (sr & 7) * 8;
  f32x4v acc[4][4];
  #pragma unroll
  for (int i = 0; i < 4; ++i)
    #pragma unroll
    for (int j = 0; j < 4; ++j) acc[i][j] = (f32x4v){0.f,0.f,0.f,0.f};

  for (int k0 = 0; k0 < K; k0 += 64){
    if (ABF){
      const u16* src = (const u16*)Av + (size_t)(row0+sr)*K + k0 + sh;
      uint4 v0 = *(const uint4*)(src+0);
      uint4 v1 = *(const uint4*)(src+8);
      uint4 v2 = *(const uint4*)(src+16);
      uint4 v3 = *(const uint4*)(src+24);
      *(uint4*)&As[sr][(sh+0)^swzS]  = v0;
      *(uint4*)&As[sr][(sh+8)^swzS]  = v1;
      *(uint4*)&As[sr][(sh+16)^swzS] = v2;
      *(uint4*)&As[sr][(sh+24)^swzS] = v3;
    } else {
      const float* src = (const float*)Av + (size_t)(row0+sr)*K + k0 + sh;
      #pragma unroll
      for (int j = 0; j < 4; ++j){
        float4 f0 = *(const float4*)(src + 8*j);
        float4 f1 = *(const float4*)(src + 8*j + 4);
        uint4 o;
        o.x = pk2(f0.x, f0.y); o.y = pk2(f0.z, f0.w);
        o.z = pk2(f1.x, f1.y); o.w = pk2(f1.z, f1.w);
        *(uint4*)&As[sr][(sh + 8*j)^swzS] = o;
      }
    }
    {
      const u16* src = Wt + (size_t)(col0+sr)*K + k0 + sh;
      uint4 v0 = *(const uint4*)(src+0);
      uint4 v1 = *(const uint4*)(src+8);
      uint4 v2 = *(const uint4*)(src+16);
      uint4 v3 = *(const uint4*)(src+24);
      *(uint4*)&Bs[sr][(sh+0)^swzS]  = v0;
      *(uint4*)&Bs[sr][(sh+8)^swzS]  = v1;
      *(uint4*)&Bs[sr][(sh+16)^swzS] = v2;
      *(uint4*)&Bs[sr][(sh+24)^swzS] = v3;
    }
    __syncthreads();
    bf16x8 af[4][2], bfr[4][2];
    #pragma unroll
    for (int mi = 0; mi < 4; ++mi){
      int m = wm + mi*16 + lm;
      int sz = (m & 7)*8;
      af[mi][0] = *(const bf16x8*)&As[m][(quad*8) ^ sz];
      af[mi][1] = *(const bf16x8*)&As[m][(32 + quad*8) ^ sz];
    }
    #pragma unroll
    for (int ni = 0; ni < 4; ++ni){
      int n = wn + ni*16 + lm;
      int sz = (n & 7)*8;
      bfr[ni][0] = *(const bf16x8*)&Bs[n][(quad*8) ^ sz];
      bfr[ni][1] = *(const bf16x8*)&Bs[n][(32 + quad*8) ^ sz];
    }
    #pragma unroll
    for (int mi = 0; mi < 4; ++mi)
      #pragma unroll
      for (int ni = 0; ni < 4; ++ni){
        acc[mi][ni] = __builtin_amdgcn_mfma_f32_16x16x32_bf16(af[mi][0], bfr[ni][0], acc[mi][ni], 0, 0, 0);
        acc[mi][ni] = __builtin_amdgcn_mfma_f32_16x16x32_bf16(af[mi][1], bfr[ni][1], acc[mi][ni], 0, 0, 0);
      }
    __syncthreads();
  }
  #pragma unroll
  for (int mi = 0; mi < 4; ++mi){
    #pragma unroll
    for (int r = 0; r < 4; ++r){
      int row = row0 + wm + mi*16 + quad*4 + r;
      int bb = row / La, l = row - bb*La;
      size_t crow = ((size_t)bb*Lc + off + l)*(size_t)N;
      #pragma unroll
      for (int ni = 0; ni < 4; ++ni){
        int col = col0 + wn + ni*16 + lm;
        float vv = acc[mi][ni][r] + ldv(bias, bOff + col, f32);
        if (EPI == 1) vv = 0.5f*vv*(1.f + erff(vv*0.70710678118654752f));
        if (EPI == 2) vv += R[crow + col];
        if (CBF) ((u16*)Cv)[crow + col] = f2b(vv);
        else     ((float*)Cv)[crow + col] = vv;
      }
    }
  }
}

// ---------------- fused QKV / KV MFMA GEMM (K=512), swizzled ----------------
template<int ABF>
__global__ __launch_bounds__(256)
void gemm_qkv(const void* __restrict__ Av, const u16* __restrict__ Wt,
              const void* __restrict__ b0, const void* __restrict__ b1, const void* __restrict__ b2,
              long long bOff, u16* __restrict__ o0, u16* __restrict__ o1, u16* __restrict__ o2,
              const u16* __restrict__ det, int La, int Lc, int off, int RP, int CP, int rpx)
{
  __shared__ u16 As[128][64];
  __shared__ u16 Bs[128][64];
  bool f32 = is_f32(det);
  const int K = 512;
  int tid = threadIdx.x;
  int row0, col0;
  if (!swz(blockIdx.x, RP, CP, rpx, row0, col0)) return;
  int wave = tid >> 6, lane = tid & 63;
  int wm = (wave >> 1)*64, wn = (wave & 1)*64;
  int lm = lane & 15, quad = lane >> 4;
  int sr = tid >> 1;
  int sh = (tid & 1) * 32;
  int swzS = (sr & 7) * 8;
  f32x4v acc[4][4];
  #pragma unroll
  for (int i = 0; i < 4; ++i)
    #pragma unroll
    for (int j = 0; j < 4; ++j) acc[i][j] = (f32x4v){0.f,0.f,0.f,0.f};

  for (int k0 = 0; k0 < K; k0 += 64){
    if (ABF){
      const u16* src = (const u16*)Av + (size_t)(row0+sr)*K + k0 + sh;
      uint4 v0 = *(const uint4*)(src+0);
      uint4 v1 = *(const uint4*)(src+8);
      uint4 v2 = *(const uint4*)(src+16);
      uint4 v3 = *(const uint4*)(src+24);
      *(uint4*)&As[sr][(sh+0)^swzS]  = v0;
      *(uint4*)&As[sr][(sh+8)^swzS]  = v1;
      *(uint4*)&As[sr][(sh+16)^swzS] = v2;
      *(uint4*)&As[sr][(sh+24)^swzS] = v3;
    } else {
      const float* src = (const float*)Av + (size_t)(row0+sr)*K + k0 + sh;
      #pragma unroll
      for (int j = 0; j < 4; ++j){
        float4 f0 = *(const float4*)(src + 8*j);
        float4 f1 = *(const float4*)(src + 8*j + 4);
        uint4 o;
        o.x = pk2(f0.x, f0.y); o.y = pk2(f0.z, f0.w);
        o.z = pk2(f1.x, f1.y); o.w = pk2(f1.z, f1.w);
        *(uint4*)&As[sr][(sh + 8*j)^swzS] = o;
      }
    }
    {
      const u16* src = Wt + (size_t)(col0+sr)*K + k0 + sh;
      uint4 v0 = *(const uint4*)(src+0);
      uint4 v1 = *(const uint4*)(src+8);
      uint4 v2 = *(const uint4*)(src+16);
      uint4 v3 = *(const uint4*)(src+24);
      *(uint4*)&Bs[sr][(sh+0)^swzS]  = v0;
      *(uint4*)&Bs[sr][(sh+8)^swzS]  = v1;
      *(uint4*)&Bs[sr][(sh+16)^swzS] = v2;
      *(uint4*)&Bs[sr][(sh+24)^swzS] = v3;
    }
    __syncthreads();
    bf16x8 af[4][2], bfr[4][2];
    #pragma unroll
    for (int mi = 0; mi < 4; ++mi){
      int m = wm + mi*16 + lm;
      int sz = (m & 7)*8;
      af[mi][0] = *(const bf16x8*)&As[m][(quad*8) ^ sz];
      af[mi][1] = *(const bf16x8*)&As[m][(32 + quad*8) ^ sz];
    }
    #pragma unroll
    for (int ni = 0; ni < 4; ++ni){
      int n = wn + ni*16 + lm;
      int sz = (n & 7)*8;
      bfr[ni][0] = *(const bf16x8*)&Bs[n][(quad*8) ^ sz];
      bfr[ni][1] = *(const bf16x8*)&Bs[n][(32 + quad*8) ^ sz];
    }
    #pragma unroll
    for (int mi = 0; mi < 4; ++mi)
      #pragma unroll
      for (int ni = 0; ni < 4; ++ni){
        acc[mi][ni] = __builtin_amdgcn_mfma_f32_16x16x32_bf16(af[mi][0], bfr[ni][0], acc[mi][ni], 0, 0, 0);
        acc[mi][ni] = __builtin_amdgcn_mfma_f32_16x16x32_bf16(af[mi][1], bfr[ni][1], acc[mi][ni], 0, 0, 0);
      }
    __syncthreads();
  }
  #pragma unroll
  for (int mi = 0; mi < 4; ++mi){
    #pragma unroll
    for (int r = 0; r < 4; ++r){
      int row = row0 + wm + mi*16 + quad*4 + r;
      int bb = row / La, l = row - bb*La;
      size_t crow = ((size_t)bb*Lc + off + l)*(size_t)HD;
      #pragma unroll
      for (int ni = 0; ni < 4; ++ni){
        int col = col0 + wn + ni*16 + lm;
        int sel = (col >= 1536) ? 2 : (col >= 768 ? 1 : 0);
        int colr = col - sel*768;
        const void* bp = (sel == 0) ? b0 : (sel == 1) ? b1 : b2;
        u16* dst = (sel == 0) ? o0 : (sel == 1) ? o1 : o2;
        float vv = acc[mi][ni][r] + ldv(bp, bOff + colr, f32);
        dst[crow + colr] = f2b(vv);
      }
    }
  }
}

// ---------------- SIMT GEMM (bottleneck) ----------------
#define BM 64
#define BN 64
#define BK 16
__global__ __launch_bounds__(256)
void gemm_k(const float* __restrict__ A, const void* __restrict__ W, long long wOff,
            const void* __restrict__ bias, long long bOff,
            float* __restrict__ C, const u16* __restrict__ det, int K, int N)
{
  __shared__ float As2[BK][BM+4];
  __shared__ float Bs2[BK][BN+4];
  bool f32 = is_f32(det);
  int tid = threadIdx.x;
  int row0 = blockIdx.y * BM, col0 = blockIdx.x * BN;
  int ty = tid >> 4, tx = tid & 15;
  int lr = tid >> 2, lc4 = (tid & 3) << 2;
  int wr = tid >> 4, wc4 = (tid & 15) << 2;
  float acc[4][4] = {};
  for (int k0 = 0; k0 < K; k0 += BK){
    float4 av = *(const float4*)(A + (size_t)(row0 + lr)*K + k0 + lc4);
    As2[lc4+0][lr] = av.x; As2[lc4+1][lr] = av.y;
    As2[lc4+2][lr] = av.z; As2[lc4+3][lr] = av.w;
    float4 wv = ldv4(W, wOff + (long long)(k0 + wr)*N + col0 + wc4, f32);
    *(float4*)&Bs2[wr][wc4] = wv;
    __syncthreads();
    #pragma unroll
    for (int kk = 0; kk < BK; ++kk){
      float4 a  = *(const float4*)&As2[kk][ty << 2];
      float4 bb = *(const float4*)&Bs2[kk][tx << 2];
      acc[0][0] += a.x*bb.x; acc[0][1] += a.x*bb.y; acc[0][2] += a.x*bb.z; acc[0][3] += a.x*bb.w;
      acc[1][0] += a.y*bb.x; acc[1][1] += a.y*bb.y; acc[1][2] += a.y*bb.z; acc[1][3] += a.y*bb.w;
      acc[2][0] += a.z*bb.x; acc[2][1] += a.z*bb.y; acc[2][2] += a.z*bb.z; acc[2][3] += a.z*bb.w;
      acc[3][0] += a.w*bb.x; acc[3][1] += a.w*bb.y; acc[3][2] += a.w*bb.z; acc[3][3] += a.w*bb.w;
    }
    __syncthreads();
  }
  #pragma unroll
  for (int i = 0; i < 4; ++i){
    int r = row0 + (ty << 2) + i;
    size_t crow = (size_t)r*(size_t)N;
    #pragma unroll
    for (int j = 0; j < 4; ++j){
      int c = col0 + (tx << 2) + j;
      C[crow + c] = acc[i][j] + ldv(bias, bOff + c, f32);
    }
  }
}

// ---------------- conv weight reorder ----------------
__global__ void wc_kernel(const void* __restrict__ w, float* __restrict__ Wc,
                          const u16* __restrict__ det)
{
  bool f32 = is_f32(det);
  int idx = blockIdx.x * 256 + threadIdx.x;
  if (idx >= 3*512*128) return;
  int co = idx & 127;
  int kk = (idx >> 7) & 511;
  int lay = idx >> 16;
  int tt = kk >> 7, ci = kk & 127;
  Wc[idx] = ldv(w, (long long)lay*65536 + co*512 + ci*4 + tt, f32);
}

// ---------------- bottleneck conv as GEMM + BN + ELU ----------------
__global__ __launch_bounds__(256)
void conv_gemm(const float* __restrict__ in, int inStride, int inOff,
               float* __restrict__ out, int outStride, int outOff, int Lout,
               const float* __restrict__ Wc,
               const void* __restrict__ cb, const void* __restrict__ bg,
               const void* __restrict__ bb, const void* __restrict__ bm,
               const void* __restrict__ bv, const u16* __restrict__ det, int lay)
{
  __shared__ float As2[BK][BM+4];
  __shared__ float Bs2[BK][BN+4];
  bool f32 = is_f32(det);
  int tid = threadIdx.x;
  int row0 = blockIdx.y * BM, col0 = blockIdx.x * BN;
  int ty = tid >> 4, tx = tid & 15;
  int lr = tid >> 2, lc4 = (tid & 3) << 2;
  int wr = tid >> 4, wc4 = (tid & 15) << 2;
  int rs = row0 + lr;
  int bs = rs / Lout, js = rs - bs*Lout;
  const float* arow = in + ((size_t)(bs*inStride + inOff + js*4))*128;
  float acc[4][4] = {};
  for (int k0 = 0; k0 < 512; k0 += BK){
    float4 av = *(const float4*)(arow + k0 + lc4);
    As2[lc4+0][lr] = av.x; As2[lc4+1][lr] = av.y;
    As2[lc4+2][lr] = av.z; As2[lc4+3][lr] = av.w;
    float4 wv = *(const float4*)(Wc + (size_t)(k0 + wr)*128 + col0 + wc4);
    *(float4*)&Bs2[wr][wc4] = wv;
    __syncthreads();
    #pragma unroll
    for (int kk = 0; kk < BK; ++kk){
      float4 a  = *(const float4*)&As2[kk][ty << 2];
      float4 bb2 = *(const float4*)&Bs2[kk][tx << 2];
      acc[0][0] += a.x*bb2.x; acc[0][1] += a.x*bb2.y; acc[0][2] += a.x*bb2.z; acc[0][3] += a.x*bb2.w;
      acc[1][0] += a.y*bb2.x; acc[1][1] += a.y*bb2.y; acc[1][2] += a.y*bb2.z; acc[1][3] += a.y*bb2.w;
      acc[2][0] += a.z*bb2.x; acc[2][1] += a.z*bb2.y; acc[2][2] += a.z*bb2.z; acc[2][3] += a.z*bb2.w;
      acc[3][0] += a.w*bb2.x; acc[3][1] += a.w*bb2.y; acc[3][2] += a.w*bb2.z; acc[3][3] += a.w*bb2.w;
    }
    __syncthreads();
  }
  #pragma unroll
  for (int i = 0; i < 4; ++i){
    int r = row0 + (ty << 2) + i;
    int b = r / Lout, j = r - b*Lout;
    float* orow = out + ((size_t)(b*outStride + outOff + j))*128;
    #pragma unroll
    for (int jj = 0; jj < 4; ++jj){
      int co = col0 + (tx << 2) + jj;
      long long po = (long long)lay*128 + co;
      float a = acc[i][jj] + ldv(cb, po, f32);
      a = (a - ldv(bm, po, f32)) * rsqrtf(ldv(bv, po, f32) + 1e-5f) * ldv(bg, po, f32) + ldv(bb, po, f32);
      a = a > 0.f ? a : (__expf(a) - 1.f);
      orow[co] = a;
    }
  }
}

// ---------------- LayerNorm (4 rows/block, optional bf16 shadow) ----------------
__global__ __launch_bounds__(256)
void ln_kernel(const float* __restrict__ X, const void* __restrict__ g, long long gOff,
               const void* __restrict__ bt, long long bOff, float eps,
               float* __restrict__ Out, u16* __restrict__ OutB, const u16* __restrict__ det)
{
  bool f32 = is_f32(det);
  int row = blockIdx.x*4 + (threadIdx.x >> 6);
  int lane = threadIdx.x & 63;
  const float* xr = X + (size_t)row*DM;
  float v[8]; float s = 0.f;
  #pragma unroll
  for (int i = 0; i < 8; ++i){ v[i] = xr[lane + i*64]; s += v[i]; }
  #pragma unroll
  for (int o = 32; o > 0; o >>= 1) s += __shfl_xor(s, o);
  float mean = s * (1.f/512.f);
  float q = 0.f;
  #pragma unroll
  for (int i = 0; i < 8; ++i){ float d = v[i]-mean; q += d*d; }
  #pragma unroll
  for (int o = 32; o > 0; o >>= 1) q += __shfl_xor(q, o);
  float inv = rsqrtf(q*(1.f/512.f) + eps);
  float* orow = Out + (size_t)row*DM;
  #pragma unroll
  for (int i = 0; i < 8; ++i){
    int c = lane + i*64;
    float val = (v[i]-mean)*inv*ldv(g, gOff + c, f32) + ldv(bt, bOff + c, f32);
    orow[c] = val;
    if (OutB) OutB[(size_t)row*DM + c] = f2b(val);
  }
}

// ---------------- concat + LayerNorm(1e-5), 4 rows/block, optional shadow ----------------
__global__ __launch_bounds__(256)
void concat_ln_kernel(const float* __restrict__ emb, const float* __restrict__ up,
                      const void* __restrict__ g, const void* __restrict__ bt,
                      float* __restrict__ Out, u16* __restrict__ OutB, const u16* __restrict__ det)
{
  bool f32 = is_f32(det);
  int row = blockIdx.x*4 + (threadIdx.x >> 6);
  int lane = threadIdx.x & 63;
  int b = row / S1, l = row - b*S1;
  const float* xr = (l < L_IN) ? emb + ((size_t)(b*L_IN + l))*DM
                               : up  + ((size_t)(b*54 + (l - L_IN)))*DM;
  float v[8]; float s = 0.f;
  #pragma unroll
  for (int i = 0; i < 8; ++i){ v[i] = xr[lane + i*64]; s += v[i]; }
  #pragma unroll
  for (int o = 32; o > 0; o >>= 1) s += __shfl_xor(s, o);
  float mean = s * (1.f/512.f);
  float q = 0.f;
  #pragma unroll
  for (int i = 0; i < 8; ++i){ float d = v[i]-mean; q += d*d; }
  #pragma unroll
  for (int o = 32; o > 0; o >>= 1) q += __shfl_xor(q, o);
  float inv = rsqrtf(q*(1.f/512.f) + 1e-5f);
  float* orow = Out + (size_t)row*DM;
  #pragma unroll
  for (int i = 0; i < 8; ++i){
    int c = lane + i*64;
    float val = (v[i]-mean)*inv*ldv(g, c, f32) + ldv(bt, c, f32);
    orow[c] = val;
    if (OutB) OutB[(size_t)row*DM + c] = f2b(val);
  }
}

// ---------------- encoder attention: PAM-sparse, 16-lane unit per (b,q,h) ----------------
__global__ __launch_bounds__(256)
void attn_enc_sparse(u16* __restrict__ q, const u16* __restrict__ k,
                     const u16* __restrict__ v, const int* __restrict__ nbr)
{
  int u = blockIdx.x * 16 + (threadIdx.x >> 4);
  int lane16 = threadIdx.x & 15;
  int h = u % NHD;
  int bq = u / NHD;
  int b = bq / S1, qr = bq - b*S1;
  const float scale = 0.088388347648318447f;
  size_t rowoff = (size_t)bq*HD + h*DK + lane16*8;
  uint4 qw = *(const uint4*)(q + rowoff);
  float qd[8]; unpack8(qw, qd);
  const int* nb = nbr + qr*12;
  size_t base = (size_t)b*S1*HD + h*DK + lane16*8;
  float pj[12];
  #pragma unroll
  for (int j = 0; j < 12; ++j){
    int kg = nb[j];
    int kgc = kg < 0 ? 0 : kg;
    uint4 kw = *(const uint4*)(k + (size_t)kgc*HD + base);
    float kd[8]; unpack8(kw, kd);
    float p = qd[0]*kd[0] + qd[1]*kd[1] + qd[2]*kd[2] + qd[3]*kd[3]
            + qd[4]*kd[4] + qd[5]*kd[5] + qd[6]*kd[6] + qd[7]*kd[7];
    p += __shfl_xor(p, 1); p += __shfl_xor(p, 2);
    p += __shfl_xor(p, 4); p += __shfl_xor(p, 8);
    pj[j] = (kg >= 0) ? p*scale : -1e30f;
  }
  float m = -1e30f;
  #pragma unroll
  for (int j = 0; j < 12; ++j) m = fmaxf(m, pj[j]);
  float s = 0.f;
  #pragma unroll
  for (int j = 0; j < 12; ++j){ pj[j] = __expf(pj[j] - m); s += pj[j]; }
  float inv = 1.f / s;
  float o[8];
  #pragma unroll
  for (int i = 0; i < 8; ++i) o[i] = 0.f;
  #pragma unroll
  for (int j = 0; j < 12; ++j){
    int kg = nb[j];
    int kgc = kg < 0 ? 0 : kg;
    uint4 vw = *(const uint4*)(v + (size_t)kgc*HD + base);
    float vd[8]; unpack8(vw, vd);
    #pragma unroll
    for (int i = 0; i < 8; ++i) o[i] += pj[j]*vd[i];
  }
  uint4 ow;
  ow.x = pk2(o[0]*inv, o[1]*inv);
  ow.y = pk2(o[2]*inv, o[3]*inv);
  ow.z = pk2(o[4]*inv, o[5]*inv);
  ow.w = pk2(o[6]*inv, o[7]*inv);
  *(uint4*)(q + rowoff) = ow;
}

// ---------------- decoder attention: MFMA flash ----------------
#define FQT 64
__global__ __launch_bounds__(256)
void attn_dec_mfma(u16* __restrict__ q, const u16* __restrict__ k,
                   const u16* __restrict__ v)
{
  __shared__ u16 Qs[FQT][136];
  __shared__ u16 Ks[32][136];
  __shared__ u32 Vt[128][20];
  __shared__ u16 Pls[4][16][32];
  int b = blockIdx.z, h = blockIdx.y;
  int qt0 = blockIdx.x * FQT;
  int tid = threadIdx.x;
  int wave = tid >> 6, lane = tid & 63;
  int lm = lane & 15, quad = lane >> 4;
  const float scale = 0.088388347648318447f;
  const size_t qb0 = (size_t)b*L_IN*HD + (size_t)h*DK;
  const size_t kb0 = (size_t)b*SKV*HD + (size_t)h*DK;

  for (int i = tid*4; i < FQT*128; i += 1024){
    int row = i >> 7, d = i & 127;
    int qg = qt0 + row;
    ushort4 w = make_ushort4(0,0,0,0);
    if (qg < L_IN) w = *(const ushort4*)(q + qb0 + (size_t)qg*HD + d);
    *(ushort4*)&Qs[row][d] = w;
  }
  __syncthreads();
  bf16x8 qf[4];
  #pragma unroll
  for (int ks = 0; ks < 4; ++ks)
    qf[ks] = *(const bf16x8*)&Qs[wave*16 + lm][ks*32 + quad*8];

  float mold[4], lsum[4];
  #pragma unroll
  for (int r = 0; r < 4; ++r){ mold[r] = -1e30f; lsum[r] = 0.f; }
  f32x4v oacc[8];
  #pragma unroll
  for (int f = 0; f < 8; ++f) oacc[f] = (f32x4v){0.f,0.f,0.f,0.f};

  int kEnd = S1 + qt0 + FQT; if (kEnd > SKV) kEnd = SKV;
  for (int kt0 = 0; kt0 < kEnd; kt0 += 32){
    __syncthreads();
    for (int i = tid*4; i < 32*128; i += 1024){
      int kk = i >> 7, d = i & 127;
      int kg = kt0 + kk;
      ushort4 w = make_ushort4(0,0,0,0);
      if (kg < SKV) w = *(const ushort4*)(k + kb0 + (size_t)kg*HD + d);
      *(ushort4*)&Ks[kk][d] = w;
    }
    for (int t2 = tid; t2 < 512; t2 += 256){
      int g = t2 & 31, p = t2 >> 5;
      int kg0 = kt0 + 2*p, d0 = g*4;
      ushort4 a = make_ushort4(0,0,0,0), c = make_ushort4(0,0,0,0);
      if (kg0     < SKV) a = *(const ushort4*)(v + kb0 + (size_t)kg0*HD + d0);
      if (kg0 + 1 < SKV) c = *(const ushort4*)(v + kb0 + (size_t)(kg0+1)*HD + d0);
      Vt[d0+0][p] = (u32)a.x | ((u32)c.x << 16);
      Vt[d0+1][p] = (u32)a.y | ((u32)c.y << 16);
      Vt[d0+2][p] = (u32)a.z | ((u32)c.z << 16);
      Vt[d0+3][p] = (u32)a.w | ((u32)c.w << 16);
    }
    __syncthreads();
    f32x4v sacc[2];
    sacc[0] = (f32x4v){0.f,0.f,0.f,0.f};
    sacc[1] = (f32x4v){0.f,0.f,0.f,0.f};
    #pragma unroll
    for (int t = 0; t < 2; ++t)
      #pragma unroll
      for (int ks = 0; ks < 4; ++ks){
        bf16x8 kf = *(const bf16x8*)&Ks[t*16 + lm][ks*32 + quad*8];
        sacc[t] = __builtin_amdgcn_mfma_f32_16x16x32_bf16(qf[ks], kf, sacc[t], 0, 0, 0);
      }
    float p[2][4];
    #pragma unroll
    for (int r = 0; r < 4; ++r){
      int qg = qt0 + wave*16 + quad*4 + r;
      float s0, s1;
      {
        int kg = kt0 + lm;
        bool ok = (kg < SKV) && (qg < L_IN) && (kg <= S1 + qg);
        s0 = ok ? sacc[0][r]*scale : -1e30f;
      }
      {
        int kg = kt0 + 16 + lm;
        bool ok = (kg < SKV) && (qg < L_IN) && (kg <= S1 + qg);
        s1 = ok ? sacc[1][r]*scale : -1e30f;
      }
      float mn = fmaxf(s0, s1);
      #pragma unroll
      for (int o = 8; o > 0; o >>= 1) mn = fmaxf(mn, __shfl_xor(mn, o));
      float mi = fmaxf(mold[r], mn);
      float alpha = __expf(mold[r] - mi);
      mold[r] = mi;
      p[0][r] = __expf(s0 - mi);
      p[1][r] = __expf(s1 - mi);
      float rs = p[0][r] + p[1][r];
      #pragma unroll
      for (int o = 8; o > 0; o >>= 1) rs += __shfl_xor(rs, o);
      lsum[r] = lsum[r]*alpha + rs;
      #pragma unroll
      for (int f = 0; f < 8; ++f) oacc[f][r] *= alpha;
    }
    #pragma unroll
    for (int r = 0; r < 4; ++r){
      Pls[wave][quad*4+r][lm]      = f2b(p[0][r]);
      Pls[wave][quad*4+r][16 + lm] = f2b(p[1][r]);
    }
    bf16x8 pa = *(const bf16x8*)&Pls[wave][lm][quad*8];
    #pragma unroll
    for (int f = 0; f < 8; ++f){
      bf16x8 vf = *(const bf16x8*)&Vt[f*16 + lm][quad*4];
      oacc[f] = __builtin_amdgcn_mfma_f32_16x16x32_bf16(pa, vf, oacc[f], 0, 0, 0);
    }
  }
  #pragma unroll
  for (int r = 0; r < 4; ++r){
    int qg = qt0 + wave*16 + quad*4 + r;
    if (qg < L_IN){
      float inv = 1.f / lsum[r];
      #pragma unroll
      for (int f = 0; f < 8; ++f)
        q[qb0 + (size_t)qg*HD + f*16 + lm] = f2b(oacc[f][r]*inv);
    }
  }
}

// ---------------- prediction head ----------------
__global__ void pred_kernel(const float* __restrict__ X, const void* __restrict__ w,
                            void* __restrict__ out, const u16* __restrict__ det)
{
  bool f32 = is_f32(det);
  int idx = blockIdx.x * 256 + threadIdx.x;
  if (idx >= BSZ*L_IN*7) return;
  int c  = idx % 7;
  int rl = idx / 7;
  const float* xr = X + (size_t)rl*DM;
  float acc = 0.f;
  for (int kk = 0; kk < DM; ++kk) acc += xr[kk] * ldv(w, kk*7 + c, f32);
  if (f32) ((float*)out)[idx] = acc;
  else     ((u16*)out)[idx] = f2b(acc);
}

// ---------------- launch ----------------
extern "C" void kernel_launch(void* const* d_in, const int* in_sizes, int n_in,
                              void* d_out, int out_size, void* d_ws, size_t ws_size,
                              hipStream_t stream)
{
  (void)in_sizes; (void)n_in; (void)out_size;
  #define IN(i) ((const void*)d_in[i])
  const u16* det = (const u16*)d_in[20];
  float* ws   = (float*)d_ws;
  float* encx = ws + OFF_ENCX;
  float* decx = ws + OFF_DECX;
  u16*   qb   = (u16*)(ws + OFF_QB);
  u16*   kb   = (u16*)(ws + OFF_KB);
  u16*   vb   = (u16*)(ws + OFF_VB);
  int*   nbr  = (int*)(ws + OFF_NBR);
  bool haveShadow = ws_size >= WS_NEED;
  u16*   encb = haveShadow ? (u16*)(ws + OFF_ENCB) : nullptr;
  u16*   decb = haveShadow ? (u16*)(ws + OFF_DECB) : nullptr;
  // phase-disjoint aliases
  float* tmp1  = ws + OFF_VB;
  u16*   WtE3  = (u16*)(ws + OFF_VB + (size_t)BSZ*S1*DM);
  u16*   WtEO  = WtE3 + (size_t)2304*512;
  u16*   WtE1  = WtEO + (size_t)768*512;
  u16*   WtE2  = WtE1 + (size_t)512*512;
  u16*   WtD3  = (u16*)(ws + OFF_QB + (size_t)BSZ*L_IN*HD/2);
  u16*   WtDO  = WtD3 + (size_t)2304*512;
  u16*   WtD1  = WtDO + (size_t)768*512;
  u16*   WtD2  = WtD1 + (size_t)512*512;
  u16*   tmph  = (u16*)(ws + OFF_KB);
  float* embE  = ws + OFF_VB;
  float* Wc    = ws + OFF_QB;
  float* bdown = ws + OFF_KB;
  float* bconv = bdown + (size_t)BSZ*L_IN*128;
  float* bup   = bconv + (size_t)BSZ*54*128;

  // swizzle geometry: RP=row panels, CP=col panels, rpx=ceil(RP/8); grid=8*rpx*CP
  const int RPe = 111, rpxE = 14;   // (BSZ*S1)/128
  const int RPd = 84,  rpxD = 11;   // (BSZ*L_IN)/128

  build_nbr_kernel<<<1, 256, 0, stream>>>(nbr);

  embed_kernel<<<(BSZ*L_IN*DM)/256, 256, 0, stream>>>(IN(0), IN(1), IN(4), IN(5), IN(6), det, embE, nullptr);
  embed_kernel<<<(BSZ*L_IN*DM)/256, 256, 0, stream>>>(IN(2), IN(3), IN(7), IN(8), IN(9), det, decx, decb);

  // bottleneck
  wc_kernel<<<(3*512*128)/256, 256, 0, stream>>>(IN(12), Wc, det);
  gemm_k<<<dim3(128/BN, (BSZ*L_IN)/BM), 256, 0, stream>>>(
      embE, IN(10), 0, IN(11), 0, bdown, det, 512, 128);
  conv_gemm<<<dim3(2, (BSZ*42)/BM), 256, 0, stream>>>(
      bdown, L_IN, 0, bconv, 54, 0, 42, Wc, IN(13), IN(14), IN(15), IN(16), IN(17), det, 0);
  conv_gemm<<<dim3(2, (BSZ*10)/BM), 256, 0, stream>>>(
      bconv, 54, 0, bconv, 54, 42, 10, Wc + 65536, IN(13), IN(14), IN(15), IN(16), IN(17), det, 1);
  conv_gemm<<<dim3(2, (BSZ*2)/BM), 256, 0, stream>>>(
      bconv, 54, 42, bconv, 54, 52, 2, Wc + 131072, IN(13), IN(14), IN(15), IN(16), IN(17), det, 2);
  gemm_k<<<dim3(512/BN, (BSZ*54)/BM), 256, 0, stream>>>(
      bconv, IN(18), 0, IN(19), 0, bup, det, 128, 512);
  concat_ln_kernel<<<(BSZ*S1)/4, 256, 0, stream>>>(embE, bup, IN(20), IN(21), encx, encb, det);

  // encoder layers
  for (int i = 0; i < 6; ++i){
    long long wO = (long long)i*512*768, oO = (long long)i*768*512;
    long long bO = (long long)i*768, dO = (long long)i*512;
    long long fO = (long long)i*512*512;
    wt_batch<<<2048, 256, 0, stream>>>(IN(22), IN(24), IN(26), IN(28), IN(32), IN(34),
                                       wO, oO, fO, WtE3, WtEO, WtE1, WtE2, det);
    if (haveShadow)
      gemm_qkv<1><<<8*rpxE*18, 256, 0, stream>>>(
          encb, WtE3, IN(23), IN(25), IN(27), bO, qb, kb, vb, det, S1, S1, 0, RPe, 18, rpxE);
    else
      gemm_qkv<0><<<8*rpxE*18, 256, 0, stream>>>(
          encx, WtE3, IN(23), IN(25), IN(27), bO, qb, kb, vb, det, S1, S1, 0, RPe, 18, rpxE);
    attn_enc_sparse<<<(BSZ*S1*NHD)/16, 256, 0, stream>>>(qb, kb, vb, nbr);
    gemm_mfma<2,1,0><<<8*rpxE*4, 256, 0, stream>>>(
        qb, WtEO, IN(29), dO, encx, tmp1, det, 768, 512, S1, S1, 0, RPe, 4, rpxE);
    ln_kernel<<<(BSZ*S1)/4, 256, 0, stream>>>(tmp1, IN(30), dO, IN(31), dO, 1e-6f, encx, encb, det);
    if (haveShadow)
      gemm_mfma<1,1,1><<<8*rpxE*4, 256, 0, stream>>>(
          encb, WtE1, IN(33), dO, nullptr, tmph, det, 512, 512, S1, S1, 0, RPe, 4, rpxE);
    else
      gemm_mfma<1,0,1><<<8*rpxE*4, 256, 0, stream>>>(
          encx, WtE1, IN(33), dO, nullptr, tmph, det, 512, 512, S1, S1, 0, RPe, 4, rpxE);
    gemm_mfma<2,1,0><<<8*rpxE*4, 256, 0, stream>>>(
        tmph, WtE2, IN(35), dO, encx, tmp1, det, 512, 512, S1, S1, 0, RPe, 4, rpxE);
    ln_kernel<<<(BSZ*S1)/4, 256, 0, stream>>>(tmp1, IN(36), dO, IN(37), dO, 1e-6f, encx, encb, det);
  }

  // decoder layers
  for (int i = 0; i < 2; ++i){
    long long wO = (long long)i*512*768, oO = (long long)i*768*512;
    long long bO = (long long)i*768, dO = (long long)i*512;
    long long fO = (long long)i*512*512;
    wt_batch<<<2048, 256, 0, stream>>>(IN(38), IN(40), IN(42), IN(44), IN(48), IN(50),
                                       wO, oO, fO, WtD3, WtDO, WtD1, WtD2, det);
    if (haveShadow){
      gemm_mfma<0,1,1><<<8*rpxD*6, 256, 0, stream>>>(
          decb, WtD3, IN(39), bO, nullptr, qb, det, 512, 768, L_IN, L_IN, 0, RPd, 6, rpxD);
      gemm_qkv<1><<<8*rpxE*12, 256, 0, stream>>>(
          encb, WtD3 + (size_t)768*512, IN(41), IN(43), IN(43), bO, kb, vb, vb, det, S1, SKV, 0, RPe, 12, rpxE);
      gemm_qkv<1><<<8*rpxD*12, 256, 0, stream>>>(
          decb, WtD3 + (size_t)768*512, IN(41), IN(43), IN(43), bO, kb, vb, vb, det, L_IN, SKV, S1, RPd, 12, rpxD);
    } else {
      gemm_mfma<0,0,1><<<8*rpxD*6, 256, 0, stream>>>(
          decx, WtD3, IN(39), bO, nullptr, qb, det, 512, 768, L_IN, L_IN, 0, RPd, 6, rpxD);
      gemm_qkv<0><<<8*rpxE*12, 256, 0, stream>>>(
          encx, WtD3 + (size_t)768*512, IN(41), IN(43), IN(43), bO, kb, vb, vb, det, S1, SKV, 0, RPe, 12, rpxE);
      gemm_qkv<0><<<8*rpxD*12, 256, 0, stream>>>(
          decx, WtD3 + (size_t)768*512, IN(41), IN(43), IN(43), bO, kb, vb, vb, det, L_IN, SKV, S1, RPd, 12, rpxD);
    }
    attn_dec_mfma<<<dim3(3, NHD, BSZ), 256, 0, stream>>>(qb, kb, vb);
    gemm_mfma<2,1,0><<<8*rpxD*4, 256, 0, stream>>>(
        qb, WtDO, IN(45), dO, decx, tmp1, det, 768, 512, L_IN, L_IN, 0, RPd, 4, rpxD);
    ln_kernel<<<(BSZ*L_IN)/4, 256, 0, stream>>>(tmp1, IN(46), dO, IN(47), dO, 1e-6f, decx, decb, det);
    if (haveShadow)
      gemm_mfma<1,1,1><<<8*rpxD*4, 256, 0, stream>>>(
          decb, WtD1, IN(49), dO, nullptr, tmph, det, 512, 512, L_IN, L_IN, 0, RPd, 4, rpxD);
    else
      gemm_mfma<1,0,1><<<8*rpxD*4, 256, 0, stream>>>(
          decx, WtD1, IN(49), dO, nullptr, tmph, det, 512, 512, L_IN, L_IN, 0, RPd, 4, rpxD);
    gemm_mfma<2,1,0><<<8*rpxD*4, 256, 0, stream>>>(
        tmph, WtD2, IN(51), dO, decx, tmp1, det, 512, 512, L_IN, L_IN, 0, RPd, 4, rpxD);
    ln_kernel<<<(BSZ*L_IN)/4, 256, 0, stream>>>(tmp1, IN(52), dO, IN(53), dO, 1e-6f, decx, decb, det);
  }

  pred_kernel<<<(BSZ*L_IN*7 + 255)/256, 256, 0, stream>>>(decx, IN(54), d_out, det);
  #undef IN
}

// Round 10
// 3224.722 us; speedup vs baseline: 4.5664x; 1.0052x over previous
//
#include <hip/hip_runtime.h>
#include <cstdint>
#include <cstddef>

// ---------------- model constants ----------------
#define BSZ   64
#define L_IN  168
#define S1    222
#define SKV   390
#define DM    512
#define HD    768
#define NHD   6
#define DK    128

typedef unsigned short u16;
typedef unsigned int u32;
typedef __attribute__((ext_vector_type(8))) short bf16x8;
typedef __attribute__((ext_vector_type(4))) float f32x4v;

// ---------------- bf16 helpers ----------------
__device__ inline float b2f(u16 u){
  union { u32 i; float f; } v; v.i = ((u32)u) << 16; return v.f;
}
__device__ inline u16 f2b(float f){
  union { float f; u32 i; } v; v.f = f;
  u32 x = v.i;
  return (u16)((x + 0x7fffu + ((x >> 16) & 1u)) >> 16);
}
__device__ inline u32 pk2(float a, float b){
  return ((u32)f2b(b) << 16) | (u32)f2b(a);
}
__device__ inline float ldv(const void* p, long long i, bool f32){
  return f32 ? ((const float*)p)[i] : b2f(((const u16*)p)[i]);
}
__device__ inline float4 ldv4(const void* p, long long i, bool f32){
  if (f32) return *(const float4*)((const float*)p + i);
  ushort4 w = *(const ushort4*)((const u16*)p + i);
  return make_float4(b2f(w.x), b2f(w.y), b2f(w.z), b2f(w.w));
}
__device__ inline bool is_f32(const u16* det){ return det[0] != 0x3F80; }
__device__ inline void unpack8(uint4 w, float* f){
  union { u32 i; float fl; } a;
  a.i = w.x << 16;          f[0] = a.fl;
  a.i = w.x & 0xffff0000u;  f[1] = a.fl;
  a.i = w.y << 16;          f[2] = a.fl;
  a.i = w.y & 0xffff0000u;  f[3] = a.fl;
  a.i = w.z << 16;          f[4] = a.fl;
  a.i = w.z & 0xffff0000u;  f[5] = a.fl;
  a.i = w.w << 16;          f[6] = a.fl;
  a.i = w.w & 0xffff0000u;  f[7] = a.fl;
}

// ---------------- workspace layout (float-equivalent offsets) ----------------
constexpr size_t OFF_ENCX = 0;
constexpr size_t OFF_DECX = OFF_ENCX + (size_t)BSZ*S1*DM;
constexpr size_t OFF_QB   = OFF_DECX + (size_t)BSZ*L_IN*DM;
constexpr size_t OFF_KB   = OFF_QB   + (size_t)BSZ*S1*HD/2;
constexpr size_t OFF_VB   = OFF_KB   + (size_t)BSZ*SKV*HD/2;
constexpr size_t OFF_NBR  = OFF_VB   + (size_t)BSZ*SKV*HD/2;
constexpr size_t OFF_ENCB = OFF_NBR  + 4096;
constexpr size_t OFF_DECB = OFF_ENCB + (size_t)BSZ*S1*DM/2;
constexpr size_t OFF_WT   = OFF_DECB + (size_t)BSZ*L_IN*DM/2;     // all-layer Wt: 8 slots x 2,097,152 u16
constexpr size_t WT_SLOT  = 2097152;                               // u16 per layer slot
constexpr size_t WS_NEED  = (OFF_WT) * 4;                          // shadow path
constexpr size_t WS_NEED2 = (OFF_WT + 8*WT_SLOT/2) * 4;            // + wt_all region

// ---------------- PAM sparsity ----------------
__device__ inline int scale_of(int i, int& ii){
  if (i < 168){ ii = i;       return 0; }
  if (i < 210){ ii = i - 168; return 1; }
  if (i < 220){ ii = i - 210; return 2; }
  ii = i - 220; return 3;
}
__device__ inline bool pam_ok(int i, int j){
  int ii, jj;
  int li = scale_of(i, ii);
  int lj = scale_of(j, jj);
  const int n[4] = {168, 42, 10, 2};
  if (li == lj){ int d = ii - jj; return (d <= 1 && d >= -1); }
  if (li == lj + 1){ int lo = ii*4, hi = (ii == n[li]-1) ? n[lj] : ii*4+4; return (jj >= lo && jj < hi); }
  if (lj == li + 1){ int lo = jj*4, hi = (jj == n[lj]-1) ? n[li] : jj*4+4; return (ii >= lo && ii < hi); }
  return false;
}
__global__ void build_nbr_kernel(int* __restrict__ nbr){
  int q = blockIdx.x * 256 + threadIdx.x;
  if (q >= S1) return;
  int cnt = 0;
  int list[12];
  for (int j = 0; j < S1; ++j)
    if (pam_ok(q, j) && cnt < 12) list[cnt++] = j;
  #pragma unroll
  for (int t = 0; t < 12; ++t) nbr[q*12 + t] = (t < cnt) ? list[t] : -1;
}

// ---------------- embedding (fast transcendentals; optional bf16 shadow) ----------------
__global__ void embed_kernel(const void* __restrict__ x, const void* __restrict__ t,
                             const void* __restrict__ cw, const void* __restrict__ tw,
                             const void* __restrict__ tb, const u16* __restrict__ det,
                             float* __restrict__ out, u16* __restrict__ out2)
{
  bool f32 = is_f32(det);
  int idx = blockIdx.x * 256 + threadIdx.x;
  if (idx >= BSZ*L_IN*DM) return;
  int d = idx & (DM-1);
  int l = (idx >> 9) % L_IN;
  int b = idx / (DM*L_IN);
  float acc = 0.f;
  #pragma unroll
  for (int tt = 0; tt < 3; ++tt){
    int ls = l + tt - 1;
    ls = (ls < 0) ? ls + L_IN : (ls >= L_IN ? ls - L_IN : ls);
    long long xo = ((long long)(b*L_IN + ls))*7;
    #pragma unroll
    for (int c = 0; c < 7; ++c)
      acc += ldv(x, xo + c, f32) * ldv(cw, d*21 + c*3 + tt, f32);
  }
  int d2 = d & ~1;
  // dv = exp(-d2*ln(10000)/512) via fast hw exp
  float dv  = __expf(-(float)d2 * (9.210340371976184f/512.f));
  float ang = (float)l * dv;
  acc += (d & 1) ? __cosf(ang) : __sinf(ang);
  long long to = ((long long)(b*L_IN + l))*4;
  #pragma unroll
  for (int f = 0; f < 4; ++f) acc += ldv(t, to + f, f32) * ldv(tw, f*DM + d, f32);
  acc += ldv(tb, d, f32);
  out[idx] = acc;
  if (out2) out2[idx] = f2b(acc);
}

// ---------------- weight transpose helpers ----------------
__device__ inline void trans32(const void* W, long long wOff, int K, int N, int k0, int n0,
                               u16* __restrict__ Wt, bool f32, float* tb, int tid)
{
  int c = tid & 31, r0 = tid >> 5;
  #pragma unroll
  for (int rr = 0; rr < 32; rr += 8)
    tb[(r0+rr)*33 + c] = ldv(W, wOff + (long long)(k0+r0+rr)*N + n0 + c, f32);
  __syncthreads();
  #pragma unroll
  for (int rr = 0; rr < 32; rr += 8)
    Wt[(size_t)(n0+r0+rr)*K + k0 + c] = f2b(tb[c*33 + r0+rr]);
}

__device__ inline void wt_layer_body(int t, const void* wq, const void* wk, const void* wv,
                                     const void* wo, const void* w1, const void* w2,
                                     long long wO, long long oO, long long fO,
                                     u16* Wt3, u16* WtO, u16* Wt1, u16* Wt2,
                                     bool f32, float* tb, int tid)
{
  if (t < 384)       trans32(wq, wO, 512, 768, (t/24)*32, (t%24)*32, Wt3,               f32, tb, tid);
  else if (t < 768)  { int u = t-384;  trans32(wk, wO, 512, 768, (u/24)*32, (u%24)*32, Wt3 + (size_t)768*512,  f32, tb, tid); }
  else if (t < 1152) { int u = t-768;  trans32(wv, wO, 512, 768, (u/24)*32, (u%24)*32, Wt3 + (size_t)1536*512, f32, tb, tid); }
  else if (t < 1536) { int u = t-1152; trans32(wo, oO, 768, 512, (u/16)*32, (u%16)*32, WtO, f32, tb, tid); }
  else if (t < 1792) { int u = t-1536; trans32(w1, fO, 512, 512, (u/16)*32, (u%16)*32, Wt1, f32, tb, tid); }
  else               { int u = t-1792; trans32(w2, fO, 512, 512, (u/16)*32, (u%16)*32, Wt2, f32, tb, tid); }
}

// per-layer fallback
__global__ __launch_bounds__(256)
void wt_batch(const void* wq, const void* wk, const void* wv,
              const void* wo, const void* w1, const void* w2,
              long long wO, long long oO, long long fO,
              u16* __restrict__ Wt3, u16* __restrict__ WtO,
              u16* __restrict__ Wt1, u16* __restrict__ Wt2,
              const u16* __restrict__ det)
{
  __shared__ float tb[32*33];
  bool f32 = is_f32(det);
  wt_layer_body(blockIdx.x, wq, wk, wv, wo, w1, w2, wO, oO, fO, Wt3, WtO, Wt1, Wt2,
                f32, tb, threadIdx.x);
}

// all 8 layers in one launch: slots 0..5 = enc layers, 6..7 = dec layers
__global__ __launch_bounds__(256)
void wt_all(const void* ewq, const void* ewk, const void* ewv, const void* ewo,
            const void* ew1, const void* ew2,
            const void* dwq, const void* dwk, const void* dwv, const void* dwo,
            const void* dw1, const void* dw2,
            u16* __restrict__ WtAll, const u16* __restrict__ det)
{
  __shared__ float tb[32*33];
  bool f32 = is_f32(det);
  int s = blockIdx.x >> 11;
  int t = blockIdx.x & 2047;
  bool enc = s < 6;
  int li = enc ? s : s - 6;
  long long wO = (long long)li*512*768, oO = (long long)li*768*512, fO = (long long)li*512*512;
  u16* base = WtAll + (size_t)s*WT_SLOT;
  wt_layer_body(t,
                enc ? ewq : dwq, enc ? ewk : dwk, enc ? ewv : dwv,
                enc ? ewo : dwo, enc ? ew1 : dw1, enc ? ew2 : dw2,
                wO, oO, fO,
                base, base + (size_t)2304*512,
                base + (size_t)2304*512 + (size_t)512*768,
                base + (size_t)2304*512 + (size_t)512*768 + (size_t)512*512,
                f32, tb, threadIdx.x);
}

// ---------------- XCD-exclusive row-panel swizzle ----------------
__device__ inline bool swz(int t, int RP, int CP, int rpx, int& row0, int& col0){
  int xcd = t & 7, j = t >> 3;
  int rp = xcd + 8*(j % rpx);
  int cp = j / rpx;
  if (rp >= RP || cp >= CP) return false;
  row0 = rp*128; col0 = cp*128;
  return true;
}

// ---------------- MFMA GEMM: C = A[M,K] @ W via Wt bf16 [N,K] ----------------
template<int EPI, int ABF, int CBF>
__global__ __launch_bounds__(256)
void gemm_mfma(const void* __restrict__ Av, const u16* __restrict__ Wt,
               const void* __restrict__ bias, long long bOff, const float* __restrict__ R,
               void* __restrict__ Cv, const u16* __restrict__ det,
               int K, int N, int La, int Lc, int off, int RP, int CP, int rpx)
{
  __shared__ u16 As[128][64];
  __shared__ u16 Bs[128][64];
  bool f32 = is_f32(det);
  int tid = threadIdx.x;
  int row0, col0;
  if (!swz(blockIdx.x, RP, CP, rpx, row0, col0)) return;
  int wave = tid >> 6, lane = tid & 63;
  int wm = (wave >> 1)*64, wn = (wave & 1)*64;
  int lm = lane & 15, quad = lane >> 4;
  int sr = tid >> 1;
  int sh = (tid & 1) * 32;
  int swzS = (sr & 7) * 8;
  f32x4v acc[4][4];
  #pragma unroll
  for (int i = 0; i < 4; ++i)
    #pragma unroll
    for (int j = 0; j < 4; ++j) acc[i][j] = (f32x4v){0.f,0.f,0.f,0.f};

  for (int k0 = 0; k0 < K; k0 += 64){
    if (ABF){
      const u16* src = (const u16*)Av + (size_t)(row0+sr)*K + k0 + sh;
      uint4 v0 = *(const uint4*)(src+0);
      uint4 v1 = *(const uint4*)(src+8);
      uint4 v2 = *(const uint4*)(src+16);
      uint4 v3 = *(const uint4*)(src+24);
      *(uint4*)&As[sr][(sh+0)^swzS]  = v0;
      *(uint4*)&As[sr][(sh+8)^swzS]  = v1;
      *(uint4*)&As[sr][(sh+16)^swzS] = v2;
      *(uint4*)&As[sr][(sh+24)^swzS] = v3;
    } else {
      const float* src = (const float*)Av + (size_t)(row0+sr)*K + k0 + sh;
      #pragma unroll
      for (int j = 0; j < 4; ++j){
        float4 f0 = *(const float4*)(src + 8*j);
        float4 f1 = *(const float4*)(src + 8*j + 4);
        uint4 o;
        o.x = pk2(f0.x, f0.y); o.y = pk2(f0.z, f0.w);
        o.z = pk2(f1.x, f1.y); o.w = pk2(f1.z, f1.w);
        *(uint4*)&As[sr][(sh + 8*j)^swzS] = o;
      }
    }
    {
      const u16* src = Wt + (size_t)(col0+sr)*K + k0 + sh;
      uint4 v0 = *(const uint4*)(src+0);
      uint4 v1 = *(const uint4*)(src+8);
      uint4 v2 = *(const uint4*)(src+16);
      uint4 v3 = *(const uint4*)(src+24);
      *(uint4*)&Bs[sr][(sh+0)^swzS]  = v0;
      *(uint4*)&Bs[sr][(sh+8)^swzS]  = v1;
      *(uint4*)&Bs[sr][(sh+16)^swzS] = v2;
      *(uint4*)&Bs[sr][(sh+24)^swzS] = v3;
    }
    __syncthreads();
    bf16x8 af[4][2], bfr[4][2];
    #pragma unroll
    for (int mi = 0; mi < 4; ++mi){
      int m = wm + mi*16 + lm;
      int sz = (m & 7)*8;
      af[mi][0] = *(const bf16x8*)&As[m][(quad*8) ^ sz];
      af[mi][1] = *(const bf16x8*)&As[m][(32 + quad*8) ^ sz];
    }
    #pragma unroll
    for (int ni = 0; ni < 4; ++ni){
      int n = wn + ni*16 + lm;
      int sz = (n & 7)*8;
      bfr[ni][0] = *(const bf16x8*)&Bs[n][(quad*8) ^ sz];
      bfr[ni][1] = *(const bf16x8*)&Bs[n][(32 + quad*8) ^ sz];
    }
    #pragma unroll
    for (int mi = 0; mi < 4; ++mi)
      #pragma unroll
      for (int ni = 0; ni < 4; ++ni){
        acc[mi][ni] = __builtin_amdgcn_mfma_f32_16x16x32_bf16(af[mi][0], bfr[ni][0], acc[mi][ni], 0, 0, 0);
        acc[mi][ni] = __builtin_amdgcn_mfma_f32_16x16x32_bf16(af[mi][1], bfr[ni][1], acc[mi][ni], 0, 0, 0);
      }
    __syncthreads();
  }
  #pragma unroll
  for (int mi = 0; mi < 4; ++mi){
    #pragma unroll
    for (int r = 0; r < 4; ++r){
      int row = row0 + wm + mi*16 + quad*4 + r;
      int bb = row / La, l = row - bb*La;
      size_t crow = ((size_t)bb*Lc + off + l)*(size_t)N;
      #pragma unroll
      for (int ni = 0; ni < 4; ++ni){
        int col = col0 + wn + ni*16 + lm;
        float vv = acc[mi][ni][r] + ldv(bias, bOff + col, f32);
        if (EPI == 1) vv = 0.5f*vv*(1.f + erff(vv*0.70710678118654752f));
        if (EPI == 2) vv += R[crow + col];
        if (CBF) ((u16*)Cv)[crow + col] = f2b(vv);
        else     ((float*)Cv)[crow + col] = vv;
      }
    }
  }
}

// ---------------- fused QKV / KV MFMA GEMM (K=512), swizzled ----------------
template<int ABF>
__global__ __launch_bounds__(256)
void gemm_qkv(const void* __restrict__ Av, const u16* __restrict__ Wt,
              const void* __restrict__ b0, const void* __restrict__ b1, const void* __restrict__ b2,
              long long bOff, u16* __restrict__ o0, u16* __restrict__ o1, u16* __restrict__ o2,
              const u16* __restrict__ det, int La, int Lc, int off, int RP, int CP, int rpx)
{
  __shared__ u16 As[128][64];
  __shared__ u16 Bs[128][64];
  bool f32 = is_f32(det);
  const int K = 512;
  int tid = threadIdx.x;
  int row0, col0;
  if (!swz(blockIdx.x, RP, CP, rpx, row0, col0)) return;
  int wave = tid >> 6, lane = tid & 63;
  int wm = (wave >> 1)*64, wn = (wave & 1)*64;
  int lm = lane & 15, quad = lane >> 4;
  int sr = tid >> 1;
  int sh = (tid & 1) * 32;
  int swzS = (sr & 7) * 8;
  f32x4v acc[4][4];
  #pragma unroll
  for (int i = 0; i < 4; ++i)
    #pragma unroll
    for (int j = 0; j < 4; ++j) acc[i][j] = (f32x4v){0.f,0.f,0.f,0.f};

  for (int k0 = 0; k0 < K; k0 += 64){
    if (ABF){
      const u16* src = (const u16*)Av + (size_t)(row0+sr)*K + k0 + sh;
      uint4 v0 = *(const uint4*)(src+0);
      uint4 v1 = *(const uint4*)(src+8);
      uint4 v2 = *(const uint4*)(src+16);
      uint4 v3 = *(const uint4*)(src+24);
      *(uint4*)&As[sr][(sh+0)^swzS]  = v0;
      *(uint4*)&As[sr][(sh+8)^swzS]  = v1;
      *(uint4*)&As[sr][(sh+16)^swzS] = v2;
      *(uint4*)&As[sr][(sh+24)^swzS] = v3;
    } else {
      const float* src = (const float*)Av + (size_t)(row0+sr)*K + k0 + sh;
      #pragma unroll
      for (int j = 0; j < 4; ++j){
        float4 f0 = *(const float4*)(src + 8*j);
        float4 f1 = *(const float4*)(src + 8*j + 4);
        uint4 o;
        o.x = pk2(f0.x, f0.y); o.y = pk2(f0.z, f0.w);
        o.z = pk2(f1.x, f1.y); o.w = pk2(f1.z, f1.w);
        *(uint4*)&As[sr][(sh + 8*j)^swzS] = o;
      }
    }
    {
      const u16* src = Wt + (size_t)(col0+sr)*K + k0 + sh;
      uint4 v0 = *(const uint4*)(src+0);
      uint4 v1 = *(const uint4*)(src+8);
      uint4 v2 = *(const uint4*)(src+16);
      uint4 v3 = *(const uint4*)(src+24);
      *(uint4*)&Bs[sr][(sh+0)^swzS]  = v0;
      *(uint4*)&Bs[sr][(sh+8)^swzS]  = v1;
      *(uint4*)&Bs[sr][(sh+16)^swzS] = v2;
      *(uint4*)&Bs[sr][(sh+24)^swzS] = v3;
    }
    __syncthreads();
    bf16x8 af[4][2], bfr[4][2];
    #pragma unroll
    for (int mi = 0; mi < 4; ++mi){
      int m = wm + mi*16 + lm;
      int sz = (m & 7)*8;
      af[mi][0] = *(const bf16x8*)&As[m][(quad*8) ^ sz];
      af[mi][1] = *(const bf16x8*)&As[m][(32 + quad*8) ^ sz];
    }
    #pragma unroll
    for (int ni = 0; ni < 4; ++ni){
      int n = wn + ni*16 + lm;
      int sz = (n & 7)*8;
      bfr[ni][0] = *(const bf16x8*)&Bs[n][(quad*8) ^ sz];
      bfr[ni][1] = *(const bf16x8*)&Bs[n][(32 + quad*8) ^ sz];
    }
    #pragma unroll
    for (int mi = 0; mi < 4; ++mi)
      #pragma unroll
      for (int ni = 0; ni < 4; ++ni){
        acc[mi][ni] = __builtin_amdgcn_mfma_f32_16x16x32_bf16(af[mi][0], bfr[ni][0], acc[mi][ni], 0, 0, 0);
        acc[mi][ni] = __builtin_amdgcn_mfma_f32_16x16x32_bf16(af[mi][1], bfr[ni][1], acc[mi][ni], 0, 0, 0);
      }
    __syncthreads();
  }
  #pragma unroll
  for (int mi = 0; mi < 4; ++mi){
    #pragma unroll
    for (int r = 0; r < 4; ++r){
      int row = row0 + wm + mi*16 + quad*4 + r;
      int bb = row / La, l = row - bb*La;
      size_t crow = ((size_t)bb*Lc + off + l)*(size_t)HD;
      #pragma unroll
      for (int ni = 0; ni < 4; ++ni){
        int col = col0 + wn + ni*16 + lm;
        int sel = (col >= 1536) ? 2 : (col >= 768 ? 1 : 0);
        int colr = col - sel*768;
        const void* bp = (sel == 0) ? b0 : (sel == 1) ? b1 : b2;
        u16* dst = (sel == 0) ? o0 : (sel == 1) ? o1 : o2;
        float vv = acc[mi][ni][r] + ldv(bp, bOff + colr, f32);
        dst[crow + colr] = f2b(vv);
      }
    }
  }
}

// ---------------- SIMT GEMM (bottleneck) ----------------
#define BM 64
#define BN 64
#define BK 16
__global__ __launch_bounds__(256)
void gemm_k(const float* __restrict__ A, const void* __restrict__ W, long long wOff,
            const void* __restrict__ bias, long long bOff,
            float* __restrict__ C, const u16* __restrict__ det, int K, int N)
{
  __shared__ float As2[BK][BM+4];
  __shared__ float Bs2[BK][BN+4];
  bool f32 = is_f32(det);
  int tid = threadIdx.x;
  int row0 = blockIdx.y * BM, col0 = blockIdx.x * BN;
  int ty = tid >> 4, tx = tid & 15;
  int lr = tid >> 2, lc4 = (tid & 3) << 2;
  int wr = tid >> 4, wc4 = (tid & 15) << 2;
  float acc[4][4] = {};
  for (int k0 = 0; k0 < K; k0 += BK){
    float4 av = *(const float4*)(A + (size_t)(row0 + lr)*K + k0 + lc4);
    As2[lc4+0][lr] = av.x; As2[lc4+1][lr] = av.y;
    As2[lc4+2][lr] = av.z; As2[lc4+3][lr] = av.w;
    float4 wv = ldv4(W, wOff + (long long)(k0 + wr)*N + col0 + wc4, f32);
    *(float4*)&Bs2[wr][wc4] = wv;
    __syncthreads();
    #pragma unroll
    for (int kk = 0; kk < BK; ++kk){
      float4 a  = *(const float4*)&As2[kk][ty << 2];
      float4 bb = *(const float4*)&Bs2[kk][tx << 2];
      acc[0][0] += a.x*bb.x; acc[0][1] += a.x*bb.y; acc[0][2] += a.x*bb.z; acc[0][3] += a.x*bb.w;
      acc[1][0] += a.y*bb.x; acc[1][1] += a.y*bb.y; acc[1][2] += a.y*bb.z; acc[1][3] += a.y*bb.w;
      acc[2][0] += a.z*bb.x; acc[2][1] += a.z*bb.y; acc[2][2] += a.z*bb.z; acc[2][3] += a.z*bb.w;
      acc[3][0] += a.w*bb.x; acc[3][1] += a.w*bb.y; acc[3][2] += a.w*bb.z; acc[3][3] += a.w*bb.w;
    }
    __syncthreads();
  }
  #pragma unroll
  for (int i = 0; i < 4; ++i){
    int r = row0 + (ty << 2) + i;
    size_t crow = (size_t)r*(size_t)N;
    #pragma unroll
    for (int j = 0; j < 4; ++j){
      int c = col0 + (tx << 2) + j;
      C[crow + c] = acc[i][j] + ldv(bias, bOff + c, f32);
    }
  }
}

// ---------------- conv weight reorder ----------------
__global__ void wc_kernel(const void* __restrict__ w, float* __restrict__ Wc,
                          const u16* __restrict__ det)
{
  bool f32 = is_f32(det);
  int idx = blockIdx.x * 256 + threadIdx.x;
  if (idx >= 3*512*128) return;
  int co = idx & 127;
  int kk = (idx >> 7) & 511;
  int lay = idx >> 16;
  int tt = kk >> 7, ci = kk & 127;
  Wc[idx] = ldv(w, (long long)lay*65536 + co*512 + ci*4 + tt, f32);
}

// ---------------- bottleneck conv as GEMM + BN + ELU ----------------
__global__ __launch_bounds__(256)
void conv_gemm(const float* __restrict__ in, int inStride, int inOff,
               float* __restrict__ out, int outStride, int outOff, int Lout,
               const float* __restrict__ Wc,
               const void* __restrict__ cb, const void* __restrict__ bg,
               const void* __restrict__ bb, const void* __restrict__ bm,
               const void* __restrict__ bv, const u16* __restrict__ det, int lay)
{
  __shared__ float As2[BK][BM+4];
  __shared__ float Bs2[BK][BN+4];
  bool f32 = is_f32(det);
  int tid = threadIdx.x;
  int row0 = blockIdx.y * BM, col0 = blockIdx.x * BN;
  int ty = tid >> 4, tx = tid & 15;
  int lr = tid >> 2, lc4 = (tid & 3) << 2;
  int wr = tid >> 4, wc4 = (tid & 15) << 2;
  int rs = row0 + lr;
  int bs = rs / Lout, js = rs - bs*Lout;
  const float* arow = in + ((size_t)(bs*inStride + inOff + js*4))*128;
  float acc[4][4] = {};
  for (int k0 = 0; k0 < 512; k0 += BK){
    float4 av = *(const float4*)(arow + k0 + lc4);
    As2[lc4+0][lr] = av.x; As2[lc4+1][lr] = av.y;
    As2[lc4+2][lr] = av.z; As2[lc4+3][lr] = av.w;
    float4 wv = *(const float4*)(Wc + (size_t)(k0 + wr)*128 + col0 + wc4);
    *(float4*)&Bs2[wr][wc4] = wv;
    __syncthreads();
    #pragma unroll
    for (int kk = 0; kk < BK; ++kk){
      float4 a  = *(const float4*)&As2[kk][ty << 2];
      float4 bb2 = *(const float4*)&Bs2[kk][tx << 2];
      acc[0][0] += a.x*bb2.x; acc[0][1] += a.x*bb2.y; acc[0][2] += a.x*bb2.z; acc[0][3] += a.x*bb2.w;
      acc[1][0] += a.y*bb2.x; acc[1][1] += a.y*bb2.y; acc[1][2] += a.y*bb2.z; acc[1][3] += a.y*bb2.w;
      acc[2][0] += a.z*bb2.x; acc[2][1] += a.z*bb2.y; acc[2][2] += a.z*bb2.z; acc[2][3] += a.z*bb2.w;
      acc[3][0] += a.w*bb2.x; acc[3][1] += a.w*bb2.y; acc[3][2] += a.w*bb2.z; acc[3][3] += a.w*bb2.w;
    }
    __syncthreads();
  }
  #pragma unroll
  for (int i = 0; i < 4; ++i){
    int r = row0 + (ty << 2) + i;
    int b = r / Lout, j = r - b*Lout;
    float* orow = out + ((size_t)(b*outStride + outOff + j))*128;
    #pragma unroll
    for (int jj = 0; jj < 4; ++jj){
      int co = col0 + (tx << 2) + jj;
      long long po = (long long)lay*128 + co;
      float a = acc[i][jj] + ldv(cb, po, f32);
      a = (a - ldv(bm, po, f32)) * rsqrtf(ldv(bv, po, f32) + 1e-5f) * ldv(bg, po, f32) + ldv(bb, po, f32);
      a = a > 0.f ? a : (__expf(a) - 1.f);
      orow[co] = a;
    }
  }
}

// ---------------- LayerNorm (4 rows/block, optional bf16 shadow) ----------------
__global__ __launch_bounds__(256)
void ln_kernel(const float* __restrict__ X, const void* __restrict__ g, long long gOff,
               const void* __restrict__ bt, long long bOff, float eps,
               float* __restrict__ Out, u16* __restrict__ OutB, const u16* __restrict__ det)
{
  bool f32 = is_f32(det);
  int row = blockIdx.x*4 + (threadIdx.x >> 6);
  int lane = threadIdx.x & 63;
  const float* xr = X + (size_t)row*DM;
  float v[8]; float s = 0.f;
  #pragma unroll
  for (int i = 0; i < 8; ++i){ v[i] = xr[lane + i*64]; s += v[i]; }
  #pragma unroll
  for (int o = 32; o > 0; o >>= 1) s += __shfl_xor(s, o);
  float mean = s * (1.f/512.f);
  float q = 0.f;
  #pragma unroll
  for (int i = 0; i < 8; ++i){ float d = v[i]-mean; q += d*d; }
  #pragma unroll
  for (int o = 32; o > 0; o >>= 1) q += __shfl_xor(q, o);
  float inv = rsqrtf(q*(1.f/512.f) + eps);
  float* orow = Out + (size_t)row*DM;
  #pragma unroll
  for (int i = 0; i < 8; ++i){
    int c = lane + i*64;
    float val = (v[i]-mean)*inv*ldv(g, gOff + c, f32) + ldv(bt, bOff + c, f32);
    orow[c] = val;
    if (OutB) OutB[(size_t)row*DM + c] = f2b(val);
  }
}

// ---------------- concat + LayerNorm(1e-5), 4 rows/block, optional shadow ----------------
__global__ __launch_bounds__(256)
void concat_ln_kernel(const float* __restrict__ emb, const float* __restrict__ up,
                      const void* __restrict__ g, const void* __restrict__ bt,
                      float* __restrict__ Out, u16* __restrict__ OutB, const u16* __restrict__ det)
{
  bool f32 = is_f32(det);
  int row = blockIdx.x*4 + (threadIdx.x >> 6);
  int lane = threadIdx.x & 63;
  int b = row / S1, l = row - b*S1;
  const float* xr = (l < L_IN) ? emb + ((size_t)(b*L_IN + l))*DM
                               : up  + ((size_t)(b*54 + (l - L_IN)))*DM;
  float v[8]; float s = 0.f;
  #pragma unroll
  for (int i = 0; i < 8; ++i){ v[i] = xr[lane + i*64]; s += v[i]; }
  #pragma unroll
  for (int o = 32; o > 0; o >>= 1) s += __shfl_xor(s, o);
  float mean = s * (1.f/512.f);
  float q = 0.f;
  #pragma unroll
  for (int i = 0; i < 8; ++i){ float d = v[i]-mean; q += d*d; }
  #pragma unroll
  for (int o = 32; o > 0; o >>= 1) q += __shfl_xor(q, o);
  float inv = rsqrtf(q*(1.f/512.f) + 1e-5f);
  float* orow = Out + (size_t)row*DM;
  #pragma unroll
  for (int i = 0; i < 8; ++i){
    int c = lane + i*64;
    float val = (v[i]-mean)*inv*ldv(g, c, f32) + ldv(bt, c, f32);
    orow[c] = val;
    if (OutB) OutB[(size_t)row*DM + c] = f2b(val);
  }
}

// ---------------- encoder attention: PAM-sparse, 16-lane unit per (b,q,h) ----------------
__global__ __launch_bounds__(256)
void attn_enc_sparse(u16* __restrict__ q, const u16* __restrict__ k,
                     const u16* __restrict__ v, const int* __restrict__ nbr)
{
  int u = blockIdx.x * 16 + (threadIdx.x >> 4);
  int lane16 = threadIdx.x & 15;
  int h = u % NHD;
  int bq = u / NHD;
  int b = bq / S1, qr = bq - b*S1;
  const float scale = 0.088388347648318447f;
  size_t rowoff = (size_t)bq*HD + h*DK + lane16*8;
  uint4 qw = *(const uint4*)(q + rowoff);
  float qd[8]; unpack8(qw, qd);
  const int* nb = nbr + qr*12;
  size_t base = (size_t)b*S1*HD + h*DK + lane16*8;
  float pj[12];
  #pragma unroll
  for (int j = 0; j < 12; ++j){
    int kg = nb[j];
    int kgc = kg < 0 ? 0 : kg;
    uint4 kw = *(const uint4*)(k + (size_t)kgc*HD + base);
    float kd[8]; unpack8(kw, kd);
    float p = qd[0]*kd[0] + qd[1]*kd[1] + qd[2]*kd[2] + qd[3]*kd[3]
            + qd[4]*kd[4] + qd[5]*kd[5] + qd[6]*kd[6] + qd[7]*kd[7];
    p += __shfl_xor(p, 1); p += __shfl_xor(p, 2);
    p += __shfl_xor(p, 4); p += __shfl_xor(p, 8);
    pj[j] = (kg >= 0) ? p*scale : -1e30f;
  }
  float m = -1e30f;
  #pragma unroll
  for (int j = 0; j < 12; ++j) m = fmaxf(m, pj[j]);
  float s = 0.f;
  #pragma unroll
  for (int j = 0; j < 12; ++j){ pj[j] = __expf(pj[j] - m); s += pj[j]; }
  float inv = 1.f / s;
  float o[8];
  #pragma unroll
  for (int i = 0; i < 8; ++i) o[i] = 0.f;
  #pragma unroll
  for (int j = 0; j < 12; ++j){
    int kg = nb[j];
    int kgc = kg < 0 ? 0 : kg;
    uint4 vw = *(const uint4*)(v + (size_t)kgc*HD + base);
    float vd[8]; unpack8(vw, vd);
    #pragma unroll
    for (int i = 0; i < 8; ++i) o[i] += pj[j]*vd[i];
  }
  uint4 ow;
  ow.x = pk2(o[0]*inv, o[1]*inv);
  ow.y = pk2(o[2]*inv, o[3]*inv);
  ow.z = pk2(o[4]*inv, o[5]*inv);
  ow.w = pk2(o[6]*inv, o[7]*inv);
  *(uint4*)(q + rowoff) = ow;
}

// ---------------- decoder attention: MFMA flash ----------------
#define FQT 64
__global__ __launch_bounds__(256)
void attn_dec_mfma(u16* __restrict__ q, const u16* __restrict__ k,
                   const u16* __restrict__ v)
{
  __shared__ u16 Qs[FQT][136];
  __shared__ u16 Ks[32][136];
  __shared__ u32 Vt[128][20];
  __shared__ u16 Pls[4][16][32];
  int b = blockIdx.z, h = blockIdx.y;
  int qt0 = blockIdx.x * FQT;
  int tid = threadIdx.x;
  int wave = tid >> 6, lane = tid & 63;
  int lm = lane & 15, quad = lane >> 4;
  const float scale = 0.088388347648318447f;
  const size_t qb0 = (size_t)b*L_IN*HD + (size_t)h*DK;
  const size_t kb0 = (size_t)b*SKV*HD + (size_t)h*DK;

  for (int i = tid*4; i < FQT*128; i += 1024){
    int row = i >> 7, d = i & 127;
    int qg = qt0 + row;
    ushort4 w = make_ushort4(0,0,0,0);
    if (qg < L_IN) w = *(const ushort4*)(q + qb0 + (size_t)qg*HD + d);
    *(ushort4*)&Qs[row][d] = w;
  }
  __syncthreads();
  bf16x8 qf[4];
  #pragma unroll
  for (int ks = 0; ks < 4; ++ks)
    qf[ks] = *(const bf16x8*)&Qs[wave*16 + lm][ks*32 + quad*8];

  float mold[4], lsum[4];
  #pragma unroll
  for (int r = 0; r < 4; ++r){ mold[r] = -1e30f; lsum[r] = 0.f; }
  f32x4v oacc[8];
  #pragma unroll
  for (int f = 0; f < 8; ++f) oacc[f] = (f32x4v){0.f,0.f,0.f,0.f};

  int kEnd = S1 + qt0 + FQT; if (kEnd > SKV) kEnd = SKV;
  for (int kt0 = 0; kt0 < kEnd; kt0 += 32){
    __syncthreads();
    for (int i = tid*4; i < 32*128; i += 1024){
      int kk = i >> 7, d = i & 127;
      int kg = kt0 + kk;
      ushort4 w = make_ushort4(0,0,0,0);
      if (kg < SKV) w = *(const ushort4*)(k + kb0 + (size_t)kg*HD + d);
      *(ushort4*)&Ks[kk][d] = w;
    }
    for (int t2 = tid; t2 < 512; t2 += 256){
      int g = t2 & 31, p = t2 >> 5;
      int kg0 = kt0 + 2*p, d0 = g*4;
      ushort4 a = make_ushort4(0,0,0,0), c = make_ushort4(0,0,0,0);
      if (kg0     < SKV) a = *(const ushort4*)(v + kb0 + (size_t)kg0*HD + d0);
      if (kg0 + 1 < SKV) c = *(const ushort4*)(v + kb0 + (size_t)(kg0+1)*HD + d0);
      Vt[d0+0][p] = (u32)a.x | ((u32)c.x << 16);
      Vt[d0+1][p] = (u32)a.y | ((u32)c.y << 16);
      Vt[d0+2][p] = (u32)a.z | ((u32)c.z << 16);
      Vt[d0+3][p] = (u32)a.w | ((u32)c.w << 16);
    }
    __syncthreads();
    f32x4v sacc[2];
    sacc[0] = (f32x4v){0.f,0.f,0.f,0.f};
    sacc[1] = (f32x4v){0.f,0.f,0.f,0.f};
    #pragma unroll
    for (int t = 0; t < 2; ++t)
      #pragma unroll
      for (int ks = 0; ks < 4; ++ks){
        bf16x8 kf = *(const bf16x8*)&Ks[t*16 + lm][ks*32 + quad*8];
        sacc[t] = __builtin_amdgcn_mfma_f32_16x16x32_bf16(qf[ks], kf, sacc[t], 0, 0, 0);
      }
    float p[2][4];
    #pragma unroll
    for (int r = 0; r < 4; ++r){
      int qg = qt0 + wave*16 + quad*4 + r;
      float s0, s1;
      {
        int kg = kt0 + lm;
        bool ok = (kg < SKV) && (qg < L_IN) && (kg <= S1 + qg);
        s0 = ok ? sacc[0][r]*scale : -1e30f;
      }
      {
        int kg = kt0 + 16 + lm;
        bool ok = (kg < SKV) && (qg < L_IN) && (kg <= S1 + qg);
        s1 = ok ? sacc[1][r]*scale : -1e30f;
      }
      float mn = fmaxf(s0, s1);
      #pragma unroll
      for (int o = 8; o > 0; o >>= 1) mn = fmaxf(mn, __shfl_xor(mn, o));
      float mi = fmaxf(mold[r], mn);
      float alpha = __expf(mold[r] - mi);
      mold[r] = mi;
      p[0][r] = __expf(s0 - mi);
      p[1][r] = __expf(s1 - mi);
      float rs = p[0][r] + p[1][r];
      #pragma unroll
      for (int o = 8; o > 0; o >>= 1) rs += __shfl_xor(rs, o);
      lsum[r] = lsum[r]*alpha + rs;
      #pragma unroll
      for (int f = 0; f < 8; ++f) oacc[f][r] *= alpha;
    }
    #pragma unroll
    for (int r = 0; r < 4; ++r){
      Pls[wave][quad*4+r][lm]      = f2b(p[0][r]);
      Pls[wave][quad*4+r][16 + lm] = f2b(p[1][r]);
    }
    bf16x8 pa = *(const bf16x8*)&Pls[wave][lm][quad*8];
    #pragma unroll
    for (int f = 0; f < 8; ++f){
      bf16x8 vf = *(const bf16x8*)&Vt[f*16 + lm][quad*4];
      oacc[f] = __builtin_amdgcn_mfma_f32_16x16x32_bf16(pa, vf, oacc[f], 0, 0, 0);
    }
  }
  #pragma unroll
  for (int r = 0; r < 4; ++r){
    int qg = qt0 + wave*16 + quad*4 + r;
    if (qg < L_IN){
      float inv = 1.f / lsum[r];
      #pragma unroll
      for (int f = 0; f < 8; ++f)
        q[qb0 + (size_t)qg*HD + f*16 + lm] = f2b(oacc[f][r]*inv);
    }
  }
}

// ---------------- prediction head ----------------
__global__ void pred_kernel(const float* __restrict__ X, const void* __restrict__ w,
                            void* __restrict__ out, const u16* __restrict__ det)
{
  bool f32 = is_f32(det);
  int idx = blockIdx.x * 256 + threadIdx.x;
  if (idx >= BSZ*L_IN*7) return;
  int c  = idx % 7;
  int rl = idx / 7;
  const float* xr = X + (size_t)rl*DM;
  float acc = 0.f;
  for (int kk = 0; kk < DM; ++kk) acc += xr[kk] * ldv(w, kk*7 + c, f32);
  if (f32) ((float*)out)[idx] = acc;
  else     ((u16*)out)[idx] = f2b(acc);
}

// ---------------- launch ----------------
extern "C" void kernel_launch(void* const* d_in, const int* in_sizes, int n_in,
                              void* d_out, int out_size, void* d_ws, size_t ws_size,
                              hipStream_t stream)
{
  (void)in_sizes; (void)n_in; (void)out_size;
  #define IN(i) ((const void*)d_in[i])
  const u16* det = (const u16*)d_in[20];
  float* ws   = (float*)d_ws;
  float* encx = ws + OFF_ENCX;
  float* decx = ws + OFF_DECX;
  u16*   qb   = (u16*)(ws + OFF_QB);
  u16*   kb   = (u16*)(ws + OFF_KB);
  u16*   vb   = (u16*)(ws + OFF_VB);
  int*   nbr  = (int*)(ws + OFF_NBR);
  bool haveShadow = ws_size >= WS_NEED;
  bool haveWtAll  = ws_size >= WS_NEED2;
  u16*   encb = haveShadow ? (u16*)(ws + OFF_ENCB) : nullptr;
  u16*   decb = haveShadow ? (u16*)(ws + OFF_DECB) : nullptr;
  u16*   WtAll = (u16*)(ws + OFF_WT);
  // phase-disjoint aliases (fallback path + temporaries)
  float* tmp1  = ws + OFF_VB;
  u16*   WtE3f = (u16*)(ws + OFF_VB + (size_t)BSZ*S1*DM);
  u16*   WtEOf = WtE3f + (size_t)2304*512;
  u16*   WtE1f = WtEOf + (size_t)768*512;
  u16*   WtE2f = WtE1f + (size_t)512*512;
  u16*   WtD3f = (u16*)(ws + OFF_QB + (size_t)BSZ*L_IN*HD/2);
  u16*   WtDOf = WtD3f + (size_t)2304*512;
  u16*   WtD1f = WtDOf + (size_t)768*512;
  u16*   WtD2f = WtD1f + (size_t)512*512;
  u16*   tmph  = (u16*)(ws + OFF_KB);
  float* embE  = ws + OFF_VB;
  float* Wc    = ws + OFF_QB;
  float* bdown = ws + OFF_KB;
  float* bconv = bdown + (size_t)BSZ*L_IN*128;
  float* bup   = bconv + (size_t)BSZ*54*128;

  const int RPe = 111, rpxE = 14;
  const int RPd = 84,  rpxD = 11;

  build_nbr_kernel<<<1, 256, 0, stream>>>(nbr);
  if (haveWtAll)
    wt_all<<<8*2048, 256, 0, stream>>>(IN(22), IN(24), IN(26), IN(28), IN(32), IN(34),
                                       IN(38), IN(40), IN(42), IN(44), IN(48), IN(50),
                                       WtAll, det);

  embed_kernel<<<(BSZ*L_IN*DM)/256, 256, 0, stream>>>(IN(0), IN(1), IN(4), IN(5), IN(6), det, embE, nullptr);
  embed_kernel<<<(BSZ*L_IN*DM)/256, 256, 0, stream>>>(IN(2), IN(3), IN(7), IN(8), IN(9), det, decx, decb);

  // bottleneck
  wc_kernel<<<(3*512*128)/256, 256, 0, stream>>>(IN(12), Wc, det);
  gemm_k<<<dim3(128/BN, (BSZ*L_IN)/BM), 256, 0, stream>>>(
      embE, IN(10), 0, IN(11), 0, bdown, det, 512, 128);
  conv_gemm<<<dim3(2, (BSZ*42)/BM), 256, 0, stream>>>(
      bdown, L_IN, 0, bconv, 54, 0, 42, Wc, IN(13), IN(14), IN(15), IN(16), IN(17), det, 0);
  conv_gemm<<<dim3(2, (BSZ*10)/BM), 256, 0, stream>>>(
      bconv, 54, 0, bconv, 54, 42, 10, Wc + 65536, IN(13), IN(14), IN(15), IN(16), IN(17), det, 1);
  conv_gemm<<<dim3(2, (BSZ*2)/BM), 256, 0, stream>>>(
      bconv, 54, 42, bconv, 54, 52, 2, Wc + 131072, IN(13), IN(14), IN(15), IN(16), IN(17), det, 2);
  gemm_k<<<dim3(512/BN, (BSZ*54)/BM), 256, 0, stream>>>(
      bconv, IN(18), 0, IN(19), 0, bup, det, 128, 512);
  concat_ln_kernel<<<(BSZ*S1)/4, 256, 0, stream>>>(embE, bup, IN(20), IN(21), encx, encb, det);

  // encoder layers
  for (int i = 0; i < 6; ++i){
    long long wO = (long long)i*512*768, oO = (long long)i*768*512;
    long long bO = (long long)i*768, dO = (long long)i*512;
    long long fO = (long long)i*512*512;
    u16 *Wt3, *WtO, *Wt1, *Wt2;
    if (haveWtAll){
      u16* base = WtAll + (size_t)i*WT_SLOT;
      Wt3 = base;
      WtO = base + (size_t)2304*512;
      Wt1 = WtO + (size_t)512*768;
      Wt2 = Wt1 + (size_t)512*512;
    } else {
      wt_batch<<<2048, 256, 0, stream>>>(IN(22), IN(24), IN(26), IN(28), IN(32), IN(34),
                                         wO, oO, fO, WtE3f, WtEOf, WtE1f, WtE2f, det);
      Wt3 = WtE3f; WtO = WtEOf; Wt1 = WtE1f; Wt2 = WtE2f;
    }
    if (haveShadow)
      gemm_qkv<1><<<8*rpxE*18, 256, 0, stream>>>(
          encb, Wt3, IN(23), IN(25), IN(27), bO, qb, kb, vb, det, S1, S1, 0, RPe, 18, rpxE);
    else
      gemm_qkv<0><<<8*rpxE*18, 256, 0, stream>>>(
          encx, Wt3, IN(23), IN(25), IN(27), bO, qb, kb, vb, det, S1, S1, 0, RPe, 18, rpxE);
    attn_enc_sparse<<<(BSZ*S1*NHD)/16, 256, 0, stream>>>(qb, kb, vb, nbr);
    gemm_mfma<2,1,0><<<8*rpxE*4, 256, 0, stream>>>(
        qb, WtO, IN(29), dO, encx, tmp1, det, 768, 512, S1, S1, 0, RPe, 4, rpxE);
    ln_kernel<<<(BSZ*S1)/4, 256, 0, stream>>>(tmp1, IN(30), dO, IN(31), dO, 1e-6f, encx, encb, det);
    if (haveShadow)
      gemm_mfma<1,1,1><<<8*rpxE*4, 256, 0, stream>>>(
          encb, Wt1, IN(33), dO, nullptr, tmph, det, 512, 512, S1, S1, 0, RPe, 4, rpxE);
    else
      gemm_mfma<1,0,1><<<8*rpxE*4, 256, 0, stream>>>(
          encx, Wt1, IN(33), dO, nullptr, tmph, det, 512, 512, S1, S1, 0, RPe, 4, rpxE);
    gemm_mfma<2,1,0><<<8*rpxE*4, 256, 0, stream>>>(
        tmph, Wt2, IN(35), dO, encx, tmp1, det, 512, 512, S1, S1, 0, RPe, 4, rpxE);
    ln_kernel<<<(BSZ*S1)/4, 256, 0, stream>>>(tmp1, IN(36), dO, IN(37), dO, 1e-6f, encx, encb, det);
  }

  // decoder layers
  for (int i = 0; i < 2; ++i){
    long long wO = (long long)i*512*768, oO = (long long)i*768*512;
    long long bO = (long long)i*768, dO = (long long)i*512;
    long long fO = (long long)i*512*512;
    u16 *Wt3, *WtO, *Wt1, *Wt2;
    if (haveWtAll){
      u16* base = WtAll + (size_t)(6+i)*WT_SLOT;
      Wt3 = base;
      WtO = base + (size_t)2304*512;
      Wt1 = WtO + (size_t)512*768;
      Wt2 = Wt1 + (size_t)512*512;
    } else {
      wt_batch<<<2048, 256, 0, stream>>>(IN(38), IN(40), IN(42), IN(44), IN(48), IN(50),
                                         wO, oO, fO, WtD3f, WtDOf, WtD1f, WtD2f, det);
      Wt3 = WtD3f; WtO = WtDOf; Wt1 = WtD1f; Wt2 = WtD2f;
    }
    if (haveShadow){
      gemm_mfma<0,1,1><<<8*rpxD*6, 256, 0, stream>>>(
          decb, Wt3, IN(39), bO, nullptr, qb, det, 512, 768, L_IN, L_IN, 0, RPd, 6, rpxD);
      gemm_qkv<1><<<8*rpxE*12, 256, 0, stream>>>(
          encb, Wt3 + (size_t)768*512, IN(41), IN(43), IN(43), bO, kb, vb, vb, det, S1, SKV, 0, RPe, 12, rpxE);
      gemm_qkv<1><<<8*rpxD*12, 256, 0, stream>>>(
          decb, Wt3 + (size_t)768*512, IN(41), IN(43), IN(43), bO, kb, vb, vb, det, L_IN, SKV, S1, RPd, 12, rpxD);
    } else {
      gemm_mfma<0,0,1><<<8*rpxD*6, 256, 0, stream>>>(
          decx, Wt3, IN(39), bO, nullptr, qb, det, 512, 768, L_IN, L_IN, 0, RPd, 6, rpxD);
      gemm_qkv<0><<<8*rpxE*12, 256, 0, stream>>>(
          encx, Wt3 + (size_t)768*512, IN(41), IN(43), IN(43), bO, kb, vb, vb, det, S1, SKV, 0, RPe, 12, rpxE);
      gemm_qkv<0><<<8*rpxD*12, 256, 0, stream>>>(
          decx, Wt3 + (size_t)768*512, IN(41), IN(43), IN(43), bO, kb, vb, vb, det, L_IN, SKV, S1, RPd, 12, rpxD);
    }
    attn_dec_mfma<<<dim3(3, NHD, BSZ), 256, 0, stream>>>(qb, kb, vb);
    gemm_mfma<2,1,0><<<8*rpxD*4, 256, 0, stream>>>(
        qb, WtO, IN(45), dO, decx, tmp1, det, 768, 512, L_IN, L_IN, 0, RPd, 4, rpxD);
    ln_kernel<<<(BSZ*L_IN)/4, 256, 0, stream>>>(tmp1, IN(46), dO, IN(47), dO, 1e-6f, decx, decb, det);
    if (haveShadow)
      gemm_mfma<1,1,1><<<8*rpxD*4, 256, 0, stream>>>(
          decb, Wt1, IN(49), dO, nullptr, tmph, det, 512, 512, L_IN, L_IN, 0, RPd, 4, rpxD);
    else
      gemm_mfma<1,0,1><<<8*rpxD*4, 256, 0, stream>>>(
          decx, Wt1, IN(49), dO, nullptr, tmph, det, 512, 512, L_IN, L_IN, 0, RPd, 4, rpxD);
    gemm_mfma<2,1,0><<<8*rpxD*4, 256, 0, stream>>>(
        tmph, Wt2, IN(51), dO, decx, tmp1, det, 512, 512, L_IN, L_IN, 0, RPd, 4, rpxD);
    ln_kernel<<<(BSZ*L_IN)/4, 256, 0, stream>>>(tmp1, IN(52), dO, IN(53), dO, 1e-6f, decx, decb, det);
  }

  pred_kernel<<<(BSZ*L_IN*7 + 255)/256, 256, 0, stream>>>(decx, IN(54), d_out, det);
  #undef IN
}